// Round 3
// baseline (1748.406 us; speedup 1.0000x reference)
//
#include <hip/hip_runtime.h>
#include <math.h>

// Fixed problem sizes (from setup_inputs): B=4, N=4096, C=128, DOUT=256,
// H=W=64 (conv out 32x32), M = N/4 = 1024 clusters, K=5 NN.
// Inputs float32; output buffer float32 (concatenated x_down, idx, agg_w).
#define NB 4
#define NT 4096
#define CI 128
#define DOUT 256
#define HWI 4096
#define HWO 1024
#define MC 1024
#define EPS_F 1e-6f

// ---------------- workspace layout (bytes) ----------------
// zero zone (memset each launch):
static const size_t OFF_XMAP  = 0;                          // 4*4096*128*4 = 8388608
static const size_t OFF_CNT   = OFF_XMAP + 8388608;         // 65536
static const size_t OFF_TOT   = OFF_CNT  + 65536;           // 65536
static const size_t OFF_ALLW  = OFF_TOT  + 65536;           // 16384
static const size_t OFF_XDOWN = OFF_ALLW + 16384;           // 4194304
static const size_t OFF_VMAX  = OFF_XDOWN + 4194304;        // 256 (4 ints used)
static const size_t OFF_AWDM  = OFF_VMAX + 256;             // 256 (4 ints used)
static const size_t ZERO_BYTES= OFF_AWDM + 256;
// non-zeroed:
static const size_t OFF_YMAP  = ZERO_BYTES;                 // 4*1024*256*4 = 4194304
static const size_t OFF_XT    = OFF_YMAP + 4194304;         // 4*4096*256*4 = 16777216
static const size_t OFF_SQ    = OFF_XT + 16777216;          // 65536
static const size_t OFF_DEN   = OFF_SQ + 65536;             // 65536
static const size_t OFF_SCORE = OFF_DEN + 65536;            // 65536
static const size_t OFF_WT    = OFF_SCORE + 65536;          // 65536
static const size_t OFF_NW    = OFF_WT + 65536;             // 65536
static const size_t OFF_AWD   = OFF_NW + 65536;             // 65536
static const size_t OFF_IDXD  = OFF_AWD + 65536;            // 16384
static const size_t OFF_IDXC  = OFF_IDXD + 16384;           // 65536
static const size_t OFF_GRAM  = OFF_IDXC + 65536;           // 4096*4096*4 = 67108864

// ---------------- helpers ----------------
__device__ __forceinline__ float waveSum(float v){
#pragma unroll
  for (int m = 1; m < 64; m <<= 1) v += __shfl_xor(v, m, 64);
  return v;
}
__device__ __forceinline__ float blockSum256(float v, float* red){
  v = waveSum(v);
  int lane = threadIdx.x & 63, wid = threadIdx.x >> 6;
  __syncthreads();
  if (lane == 0) red[wid] = v;
  __syncthreads();
  return red[0] + red[1] + red[2] + red[3];
}
// merge two ascending 5-lists, keep 5 smallest (bitonic lower-half network)
__device__ __forceinline__ void merge5(float& a0, float& a1, float& a2, float& a3, float& a4,
                                       float b0, float b1, float b2, float b3, float b4){
  float l0=a0,l1=a1,l2=a2,l3=fminf(a3,b4),l4=fminf(a4,b3),l5=b2,l6=b1,l7=b0;
  float t0=fminf(l0,l4), t4=fmaxf(l0,l4);
  float t1=fminf(l1,l5), t5=fmaxf(l1,l5);
  float t2=fminf(l2,l6), t6=fmaxf(l2,l6);
  float t3=fminf(l3,l7), t7=fmaxf(l3,l7);
  float u0=fminf(t0,t2), u2=fmaxf(t0,t2);
  float u1=fminf(t1,t3), u3=fmaxf(t1,t3);
  float u4=fminf(t4,t6);
  float u5=fminf(t5,t7);
  a0=fminf(u0,u1); a1=fmaxf(u0,u1);
  a2=fminf(u2,u3); a3=fmaxf(u2,u3);
  a4=fminf(u4,u5);
}
__device__ __forceinline__ int grid_cell(float lx, float ly, int dim){
  // matches _grid_idx: clip -> [0,1] -> round half-even -> clamp
  lx = (fminf(fmaxf(lx, -1.f), 1.f) + 1.f) * 0.5f;
  ly = (fminf(fmaxf(ly, -1.f), 1.f) + 1.f) * 0.5f;
  float s = (float)(dim - 1);
  int col = (int)rintf(lx * s); col = min(max(col, 0), dim - 1);
  int row = (int)rintf(ly * s); row = min(max(row, 0), dim - 1);
  return row * dim + col;
}

// ---------------- stage kernels ----------------
// token2map scatter: B*N*C threads
__global__ __launch_bounds__(256) void t2m_scatter(const float* __restrict__ x,
                                                   const float* __restrict__ loc,
                                                   const int* __restrict__ idx_agg,
                                                   float* __restrict__ xmap, float* __restrict__ cnt){
  int lin = blockIdx.x * 256 + threadIdx.x;       // (b*N+n0)*128 + c
  int c  = lin & 127;
  int bn = lin >> 7;
  int b  = bn >> 12;
  float lx = loc[(size_t)bn*2 + 0];
  float ly = loc[(size_t)bn*2 + 1];
  int cell = grid_cell(lx, ly, 64);
  int ia = idx_agg[bn];
  float val = x[((size_t)(b*NT + ia))*CI + c];
  atomicAdd(&xmap[((size_t)(b*HWI + cell))*CI + c], val);
  if (c == 0) atomicAdd(&cnt[b*HWI + cell], 1.0f);
}

__global__ __launch_bounds__(256) void t2m_norm(float* __restrict__ xmap, const float* __restrict__ cnt){
  int lin = blockIdx.x * 256 + threadIdx.x;       // B*HW*C
  xmap[lin] = xmap[lin] / (cnt[lin >> 7] + EPS_F);
}

// 3x3 stride-2 pad-1 conv: block = (b, oh, owq[0..3]) -> 8 ow each; threads = d
__global__ __launch_bounds__(256) void conv_kernel(const float* __restrict__ xmap,
                                                   const float* __restrict__ cw,
                                                   const float* __restrict__ cb,
                                                   float* __restrict__ ymap){
  int blk = blockIdx.x;
  int b = blk >> 7;
  int r = blk & 127;
  int oh = r >> 2;
  int owq = r & 3;
  int d = threadIdx.x;
  __shared__ float patch[3*17*128];
  for (int idx = d; idx < 3*17*128; idx += 256){
    int kh = idx / (17*128);
    int rr = idx % (17*128);
    int il = rr >> 7;
    int c  = rr & 127;
    int ih = oh*2 - 1 + kh;
    int iw = owq*16 - 1 + il;
    float v = 0.f;
    if (ih >= 0 && ih < 64 && iw >= 0 && iw < 64)
      v = xmap[((size_t)(b*HWI + ih*64 + iw))*CI + c];
    patch[idx] = v;
  }
  __syncthreads();
  float acc[8] = {0,0,0,0,0,0,0,0};
  const float* wd = cw + (size_t)d*1152;   // conv_w[d, c, kh, kw]
  for (int c = 0; c < 128; ++c){
#pragma unroll
    for (int kh = 0; kh < 3; ++kh){
#pragma unroll
      for (int kw = 0; kw < 3; ++kw){
        float w = wd[c*9 + kh*3 + kw];
#pragma unroll
        for (int ow = 0; ow < 8; ++ow)
          acc[ow] += w * patch[(kh*17 + 2*ow + kw)*128 + c];
      }
    }
  }
  float bias = cb[d];
  int ow0 = owq * 8;
  for (int ow = 0; ow < 8; ++ow)
    ymap[((size_t)(b*HWO + oh*32 + ow0 + ow))*DOUT + d] = acc[ow] + bias;
}

// segment-sum of agg_weight per target token
__global__ __launch_bounds__(256) void tot_kernel(const int* __restrict__ idx_agg,
                                                  const float* __restrict__ aggw,
                                                  float* __restrict__ tot){
  int lin = blockIdx.x * 256 + threadIdx.x;       // B*N
  int b = lin >> 12;
  atomicAdd(&tot[b*NT + idx_agg[lin]], aggw[lin]);
}

// xt = x @ skip_w.T  (8 rows per block)
__global__ __launch_bounds__(256) void skip_kernel(const float* __restrict__ x,
                                                   const float* __restrict__ sw,
                                                   float* __restrict__ xt){
  int rowbase = blockIdx.x * 8;                   // over B*N
  int d = threadIdx.x;
  __shared__ float xr[8*128];
  ((float4*)xr)[d] = ((const float4*)(x + (size_t)rowbase*CI))[d];
  __syncthreads();
  float acc[8] = {0,0,0,0,0,0,0,0};
  const float* wd = sw + (size_t)d*CI;
  for (int c = 0; c < 128; ++c){
    float w = wd[c];
#pragma unroll
    for (int r = 0; r < 8; ++r) acc[r] += w * xr[r*128 + c];
  }
  for (int r = 0; r < 8; ++r) xt[(size_t)(rowbase + r)*DOUT + d] = acc[r];
}

// map2token weighted scatter-add into xt; one block per (b, n0), threads = d
__global__ __launch_bounds__(256) void m2t_scatter(const float* __restrict__ ymap,
                                                   const float* __restrict__ loc,
                                                   const int* __restrict__ idx_agg,
                                                   const float* __restrict__ aggw,
                                                   const float* __restrict__ tot,
                                                   float* __restrict__ xt){
  int bn = blockIdx.x;
  int d = threadIdx.x;
  int b = bn >> 12;
  float lx = loc[(size_t)bn*2 + 0];
  float ly = loc[(size_t)bn*2 + 1];
  int cell = grid_cell(lx, ly, 32);
  int ia = idx_agg[bn];
  float w = aggw[bn] / (tot[b*NT + ia] + EPS_F);
  float val = ymap[((size_t)(b*HWO + cell))*DOUT + d] * w;
  atomicAdd(&xt[((size_t)(b*NT + ia))*DOUT + d], val);
}

// layernorm + conf/weight + sq; one block per row
__global__ __launch_bounds__(256) void ln_kernel(float* __restrict__ xt,
                                                 const float* __restrict__ g,
                                                 const float* __restrict__ bta,
                                                 const float* __restrict__ cw,
                                                 const float* __restrict__ cb,
                                                 float* __restrict__ sq, float* __restrict__ wt){
  __shared__ float red[4];
  int row = blockIdx.x;
  int d = threadIdx.x;
  float v = xt[(size_t)row*DOUT + d];
  float mu = blockSum256(v, red) * (1.0f/256.0f);
  float xc = v - mu;
  float var = blockSum256(xc*xc, red) * (1.0f/256.0f);
  float rn = 1.0f / sqrtf(var + 1e-5f);
  float y = xc * rn * g[d] + bta[d];
  xt[(size_t)row*DOUT + d] = y;
  float s2 = blockSum256(y*y, red);
  float cf = blockSum256(y*cw[d], red);
  if (d == 0){ sq[row] = s2; wt[row] = expf(cf + cb[0]); }
}

// gram: G[i,j] = dot(xt_i, xt_j), 4096x4096, K=256; 64x64 tile, 4x4 per thread
__global__ __launch_bounds__(256) void gram_kernel(const float* __restrict__ A, float* __restrict__ G){
  __shared__ float As[16][64];
  __shared__ float Bs[16][64];
  int tid = threadIdx.x;
  int tx = tid & 15, ty = tid >> 4;
  int i0 = blockIdx.y * 64, j0 = blockIdx.x * 64;
  int li = tid & 63, kq = tid >> 6;
  float acc[4][4] = {{0}};
  for (int kt = 0; kt < 16; ++kt){
    float4 av = *(const float4*)(A + (size_t)(i0+li)*DOUT + kt*16 + kq*4);
    float4 bv = *(const float4*)(A + (size_t)(j0+li)*DOUT + kt*16 + kq*4);
    __syncthreads();
    As[kq*4+0][li]=av.x; As[kq*4+1][li]=av.y; As[kq*4+2][li]=av.z; As[kq*4+3][li]=av.w;
    Bs[kq*4+0][li]=bv.x; Bs[kq*4+1][li]=bv.y; Bs[kq*4+2][li]=bv.z; Bs[kq*4+3][li]=bv.w;
    __syncthreads();
#pragma unroll
    for (int k = 0; k < 16; ++k){
      float4 a4 = *(const float4*)&As[k][ty*4];
      float4 b4 = *(const float4*)&Bs[k][tx*4];
      float ar[4] = {a4.x, a4.y, a4.z, a4.w};
      float br[4] = {b4.x, b4.y, b4.z, b4.w};
#pragma unroll
      for (int r = 0; r < 4; ++r)
#pragma unroll
        for (int s = 0; s < 4; ++s) acc[r][s] += ar[r]*br[s];
    }
  }
  for (int r = 0; r < 4; ++r){
    float4 o; o.x = acc[r][0]; o.y = acc[r][1]; o.z = acc[r][2]; o.w = acc[r][3];
    *(float4*)(G + (size_t)(i0 + ty*4 + r)*NT + j0 + tx*4) = o;
  }
}

// density + per-batch max(v); one block per row i
__global__ __launch_bounds__(256) void density_kernel(const float* __restrict__ G, const float* __restrict__ sq,
                                                      float* __restrict__ density, int* __restrict__ vmax, int b){
  int i = blockIdx.x;
  int tid = threadIdx.x;
  const float* sqb = sq + b*NT;
  float sqi = sqb[i];
  const float* row = G + (size_t)i*NT;
  float t0=INFINITY,t1=INFINITY,t2=INFINITY,t3=INFINITY,t4=INFINITY;
  float vmx = 0.f;
  for (int j = tid; j < NT; j += 256){
    float v = fmaxf(sqi + sqb[j] - 2.0f*row[j], 0.0f);
    vmx = fmaxf(vmx, v);
    // branchless insert keeping 5 smallest, ascending
    t4 = fminf(t4, v);
    float a;
    a = fminf(t3,t4); t4 = fmaxf(t3,t4); t3 = a;
    a = fminf(t2,t3); t3 = fmaxf(t2,t3); t2 = a;
    a = fminf(t1,t2); t2 = fmaxf(t1,t2); t1 = a;
    a = fminf(t0,t1); t1 = fmaxf(t0,t1); t0 = a;
  }
#pragma unroll
  for (int m = 1; m < 64; m <<= 1){
    float b0=__shfl_xor(t0,m,64), b1=__shfl_xor(t1,m,64), b2=__shfl_xor(t2,m,64),
          b3=__shfl_xor(t3,m,64), b4=__shfl_xor(t4,m,64);
    merge5(t0,t1,t2,t3,t4,b0,b1,b2,b3,b4);
    vmx = fmaxf(vmx, __shfl_xor(vmx,m,64));
  }
  __shared__ float w5[4][5];
  __shared__ float wm[4];
  int lane = tid & 63, wid = tid >> 6;
  if (lane == 0){ w5[wid][0]=t0; w5[wid][1]=t1; w5[wid][2]=t2; w5[wid][3]=t3; w5[wid][4]=t4; wm[wid]=vmx; }
  __syncthreads();
  if (tid == 0){
    float a0=w5[0][0],a1=w5[0][1],a2=w5[0][2],a3=w5[0][3],a4=w5[0][4];
    for (int w = 1; w < 4; ++w) merge5(a0,a1,a2,a3,a4, w5[w][0],w5[w][1],w5[w][2],w5[w][3],w5[w][4]);
    float d0=sqrtf(a0)*0.0625f, d1=sqrtf(a1)*0.0625f, d2=sqrtf(a2)*0.0625f,
          d3=sqrtf(a3)*0.0625f, d4=sqrtf(a4)*0.0625f;
    float s = d0*d0; s += d1*d1; s += d2*d2; s += d3*d3; s += d4*d4;
    density[b*NT + i] = expf(-(s / 5.0f));
    float vm = fmaxf(fmaxf(wm[0],wm[1]), fmaxf(wm[2],wm[3]));
    atomicMax(vmax + b, __float_as_int(vm));   // nonneg floats: int order == float order
  }
}

// d_parent & score; one block per row i
__global__ __launch_bounds__(256) void parent_kernel(const float* __restrict__ G, const float* __restrict__ sq,
                                                     const float* __restrict__ density, const int* __restrict__ vmax,
                                                     float* __restrict__ score, int b){
  int i = blockIdx.x;
  int tid = threadIdx.x;
  const float* sqb = sq + b*NT;
  const float* den = density + b*NT;
  float sqi = sqb[i];
  float di = den[i];
  const float* row = G + (size_t)i*NT;
  float minv = INFINITY;
  for (int j = tid; j < NT; j += 256){
    float v = fmaxf(sqi + sqb[j] - 2.0f*row[j], 0.0f);
    minv = fminf(minv, (den[j] > di) ? v : INFINITY);
  }
#pragma unroll
  for (int m = 1; m < 64; m <<= 1) minv = fminf(minv, __shfl_xor(minv,m,64));
  __shared__ float wmn[4];
  int lane = tid & 63, wid = tid >> 6;
  if (lane == 0) wmn[wid] = minv;
  __syncthreads();
  if (tid == 0){
    float mv = fminf(fminf(wmn[0],wmn[1]), fminf(wmn[2],wmn[3]));
    float dmax = sqrtf(__int_as_float(vmax[b])) * 0.0625f;
    float dp = isinf(mv) ? dmax : sqrtf(mv) * 0.0625f;
    score[b*NT + i] = dp * di;
  }
}

// full bitonic sort of 4096 (score desc, idx asc) -> first M indices
__global__ __launch_bounds__(1024) void topk_sort(const float* __restrict__ score, int* __restrict__ idx_down, int b){
  __shared__ float ss[4096];
  __shared__ int ii[4096];
  int tid = threadIdx.x;
  for (int t = tid; t < 4096; t += 1024){ ss[t] = score[b*NT + t]; ii[t] = t; }
  for (int k = 2; k <= 4096; k <<= 1){
    for (int j = k >> 1; j > 0; j >>= 1){
      __syncthreads();
      for (int t = tid; t < 4096; t += 1024){
        int p = t ^ j;
        if (p > t){
          float s1 = ss[t], s2 = ss[p];
          int i1 = ii[t], i2 = ii[p];
          bool lt = (s1 > s2) || (s1 == s2 && i1 < i2);  // t precedes p in desired order
          bool up = ((t & k) == 0);
          if (up ? !lt : lt){ ss[t]=s2; ss[p]=s1; ii[t]=i2; ii[p]=i1; }
        }
      }
    }
  }
  __syncthreads();
  if (tid < MC) idx_down[b*MC + tid] = ii[tid];
}

// nearest-center assignment; block = 64 j's x 4 m-chunks
__global__ __launch_bounds__(256) void assign_kernel(const float* __restrict__ G, const float* __restrict__ sq,
                                                     const int* __restrict__ idx_down, int* __restrict__ idx_cluster, int b){
  int jl = threadIdx.x & 63, mq = threadIdx.x >> 6;
  int j = blockIdx.x * 64 + jl;
  const float* sqb = sq + b*NT;
  float sqj = sqb[j];
  const int* idb = idx_down + b*MC;
  float bestd = INFINITY; int bestm = 0x7fffffff;
  for (int m = mq*256; m < mq*256 + 256; ++m){
    int im = idb[m];
    float g = G[(size_t)im*NT + j];
    float v = fmaxf(sqb[im] + sqj - 2.0f*g, 0.0f);
    float d = sqrtf(v) * 0.0625f;
    if (d < bestd){ bestd = d; bestm = m; }        // first-min tie rule within chunk
  }
  __shared__ float ld[4][64];
  __shared__ int lm[4][64];
  ld[mq][jl] = bestd; lm[mq][jl] = bestm;
  __syncthreads();
  if (mq == 0){
    for (int q = 1; q < 4; ++q){
      float d2 = ld[q][jl]; int m2 = lm[q][jl];
      if (d2 < bestd || (d2 == bestd && m2 < bestm)){ bestd = d2; bestm = m2; }
    }
    idx_cluster[b*NT + j] = bestm;
  }
}

__global__ __launch_bounds__(256) void override_kernel(const int* __restrict__ idx_down, int* __restrict__ idx_cluster, int b){
  int m = blockIdx.x * 256 + threadIdx.x;
  if (m < MC) idx_cluster[b*NT + idx_down[b*MC + m]] = m;
}

// ---- merge + outputs ----
__global__ __launch_bounds__(256) void allw_kernel(const int* __restrict__ idx_cluster, const float* __restrict__ wt,
                                                   float* __restrict__ allw){
  int lin = blockIdx.x * 256 + threadIdx.x;       // B*N
  int b = lin >> 12;
  atomicAdd(&allw[b*MC + idx_cluster[lin]], wt[lin]);
}
__global__ __launch_bounds__(256) void normw_kernel(const int* __restrict__ idx_cluster, const float* __restrict__ wt,
                                                    const float* __restrict__ allw, float* __restrict__ nw){
  int lin = blockIdx.x * 256 + threadIdx.x;
  int b = lin >> 12;
  nw[lin] = wt[lin] / (allw[b*MC + idx_cluster[lin]] + EPS_F);
}
__global__ __launch_bounds__(256) void xdown_kernel(const int* __restrict__ idx_cluster, const float* __restrict__ nw,
                                                    const float* __restrict__ xt, float* __restrict__ xdown){
  int bn = blockIdx.x;
  int d = threadIdx.x;
  int b = bn >> 12;
  int ic = idx_cluster[bn];
  float v = xt[(size_t)bn*DOUT + d] * nw[bn];
  atomicAdd(&xdown[((size_t)(b*MC + ic))*DOUT + d], v);
}
__global__ __launch_bounds__(256) void out0_kernel(const float* __restrict__ xdown, float* __restrict__ out){
  int lin = blockIdx.x * 256 + threadIdx.x;       // B*M*D
  out[lin] = xdown[lin];
}
__global__ __launch_bounds__(256) void out12a_kernel(const int* __restrict__ idx_agg, const int* __restrict__ idx_cluster,
                                                     const float* __restrict__ aggw, const float* __restrict__ nw,
                                                     float* __restrict__ awd, int* __restrict__ awdmax,
                                                     float* __restrict__ out1){
  int lin = blockIdx.x * 256 + threadIdx.x;       // B*N
  int b = lin >> 12;
  int ia = idx_agg[lin];
  int ic = idx_cluster[b*NT + ia];
  out1[lin] = (float)ic;
  float v = aggw[lin] * nw[b*NT + ia];
  awd[lin] = v;
  atomicMax(&awdmax[b], __float_as_int(v));       // nonneg
}
__global__ __launch_bounds__(256) void out2_kernel(const float* __restrict__ awd, const int* __restrict__ awdmax,
                                                   float* __restrict__ out2){
  int lin = blockIdx.x * 256 + threadIdx.x;
  int b = lin >> 12;
  out2[lin] = awd[lin] / __int_as_float(awdmax[b]);
}

extern "C" void kernel_launch(void* const* d_in, const int* in_sizes, int n_in,
                              void* d_out, int out_size, void* d_ws, size_t ws_size,
                              hipStream_t stream) {
  const float* x      = (const float*)d_in[0];   // f32 (B,N,C)
  const float* loc    = (const float*)d_in[1];   // f32 (B,N,2)
  const int*   idxagg = (const int*)d_in[2];     // (B,N)
  const float* aggw   = (const float*)d_in[3];   // f32 (B,N,1)
  // d_in[4]=H, d_in[5]=W (hard-coded), d_in[6]=idx_k_loc unused
  const float* convw  = (const float*)d_in[7];   // f32 (256,128,3,3)
  const float* convb  = (const float*)d_in[8];
  const float* skipw  = (const float*)d_in[9];   // f32 (256,128)
  const float* lng    = (const float*)d_in[10];
  const float* lnb    = (const float*)d_in[11];
  const float* confw  = (const float*)d_in[12];
  const float* confb  = (const float*)d_in[13];

  char* ws = (char*)d_ws;
  float* w_xmap  = (float*)(ws + OFF_XMAP);
  float* w_cnt   = (float*)(ws + OFF_CNT);
  float* w_tot   = (float*)(ws + OFF_TOT);
  float* w_allw  = (float*)(ws + OFF_ALLW);
  float* w_xdown = (float*)(ws + OFF_XDOWN);
  int*   w_vmax  = (int*)  (ws + OFF_VMAX);
  int*   w_awdm  = (int*)  (ws + OFF_AWDM);
  float* w_ymap  = (float*)(ws + OFF_YMAP);
  float* w_xt    = (float*)(ws + OFF_XT);
  float* w_sq    = (float*)(ws + OFF_SQ);
  float* w_den   = (float*)(ws + OFF_DEN);
  float* w_score = (float*)(ws + OFF_SCORE);
  float* w_wt    = (float*)(ws + OFF_WT);
  float* w_nw    = (float*)(ws + OFF_NW);
  float* w_awd   = (float*)(ws + OFF_AWD);
  int*   w_idxd  = (int*)  (ws + OFF_IDXD);
  int*   w_idxc  = (int*)  (ws + OFF_IDXC);
  float* w_gram  = (float*)(ws + OFF_GRAM);

  float* out0 = (float*)d_out;
  float* out1 = out0 + NB*MC*DOUT;
  float* out2 = out1 + NB*NT;

  hipMemsetAsync(ws, 0, ZERO_BYTES, stream);

  t2m_scatter<<<NB*NT*CI/256, 256, 0, stream>>>(x, loc, idxagg, w_xmap, w_cnt);
  t2m_norm<<<NB*HWI*CI/256, 256, 0, stream>>>(w_xmap, w_cnt);
  conv_kernel<<<NB*32*4, 256, 0, stream>>>(w_xmap, convw, convb, w_ymap);
  tot_kernel<<<NB*NT/256, 256, 0, stream>>>(idxagg, aggw, w_tot);
  skip_kernel<<<NB*NT/8, 256, 0, stream>>>(x, skipw, w_xt);
  m2t_scatter<<<NB*NT, 256, 0, stream>>>(w_ymap, loc, idxagg, aggw, w_tot, w_xt);
  ln_kernel<<<NB*NT, 256, 0, stream>>>(w_xt, lng, lnb, confw, confb, w_sq, w_wt);

  for (int b = 0; b < NB; ++b){
    gram_kernel<<<dim3(64,64), 256, 0, stream>>>(w_xt + (size_t)b*NT*DOUT, w_gram);
    density_kernel<<<NT, 256, 0, stream>>>(w_gram, w_sq, w_den, w_vmax, b);
    parent_kernel<<<NT, 256, 0, stream>>>(w_gram, w_sq, w_den, w_vmax, w_score, b);
    topk_sort<<<1, 1024, 0, stream>>>(w_score, w_idxd, b);
    assign_kernel<<<64, 256, 0, stream>>>(w_gram, w_sq, w_idxd, w_idxc, b);
    override_kernel<<<4, 256, 0, stream>>>(w_idxd, w_idxc, b);
  }

  allw_kernel<<<NB*NT/256, 256, 0, stream>>>(w_idxc, w_wt, w_allw);
  normw_kernel<<<NB*NT/256, 256, 0, stream>>>(w_idxc, w_wt, w_allw, w_nw);
  xdown_kernel<<<NB*NT, 256, 0, stream>>>(w_idxc, w_nw, w_xt, w_xdown);
  out0_kernel<<<NB*MC*DOUT/256, 256, 0, stream>>>(w_xdown, out0);
  out12a_kernel<<<NB*NT/256, 256, 0, stream>>>(idxagg, w_idxc, aggw, w_nw, w_awd, w_awdm, out1);
  out2_kernel<<<NB*NT/256, 256, 0, stream>>>(w_awd, w_awdm, out2);

  (void)in_sizes; (void)n_in; (void)out_size; (void)ws_size;
}

// Round 4
// 1510.394 us; speedup vs baseline: 1.1576x; 1.1576x over previous
//
#include <hip/hip_runtime.h>
#include <math.h>

// Fixed problem sizes (from setup_inputs): B=4, N=4096, C=128, DOUT=256,
// H=W=64 (conv out 32x32), M = N/4 = 1024 clusters, K=5 NN.
// Inputs float32; output buffer float32 (concatenated x_down, idx, agg_w).
#define NB 4
#define NT 4096
#define CI 128
#define DOUT 256
#define HWI 4096
#define HWO 1024
#define MC 1024
#define EPS_F 1e-6f

// ---------------- workspace layout (bytes) ----------------
// zero zone (memset each launch):
static const size_t OFF_XMAP  = 0;                          // 4*4096*128*4 = 8388608
static const size_t OFF_CNT   = OFF_XMAP + 8388608;         // 65536
static const size_t OFF_TOT   = OFF_CNT  + 65536;           // 65536
static const size_t OFF_ALLW  = OFF_TOT  + 65536;           // 16384
static const size_t OFF_XDOWN = OFF_ALLW + 16384;           // 4194304
static const size_t OFF_VMAX  = OFF_XDOWN + 4194304;        // 256 (4 ints used)
static const size_t OFF_AWDM  = OFF_VMAX + 256;             // 256 (4 ints used)
static const size_t ZERO_BYTES= OFF_AWDM + 256;
// non-zeroed:
static const size_t OFF_YMAP  = ZERO_BYTES;                 // 4*1024*256*4 = 4194304
static const size_t OFF_XT    = OFF_YMAP + 4194304;         // 4*4096*256*4 = 16777216
static const size_t OFF_SQ    = OFF_XT + 16777216;          // 65536
static const size_t OFF_DEN   = OFF_SQ + 65536;             // 65536
static const size_t OFF_SCORE = OFF_DEN + 65536;            // 65536
static const size_t OFF_WT    = OFF_SCORE + 65536;          // 65536
static const size_t OFF_NW    = OFF_WT + 65536;             // 65536
static const size_t OFF_AWD   = OFF_NW + 65536;             // 65536
static const size_t OFF_IDXD  = OFF_AWD + 65536;            // 16384
static const size_t OFF_IDXC  = OFF_IDXD + 16384;           // 65536
static const size_t OFF_GRAM  = OFF_IDXC + 65536;           // 4096*4096*4 = 67108864

// ---------------- helpers ----------------
__device__ __forceinline__ float waveSum(float v){
#pragma unroll
  for (int m = 1; m < 64; m <<= 1) v += __shfl_xor(v, m, 64);
  return v;
}
__device__ __forceinline__ float blockSum256(float v, float* red){
  v = waveSum(v);
  int lane = threadIdx.x & 63, wid = threadIdx.x >> 6;
  __syncthreads();
  if (lane == 0) red[wid] = v;
  __syncthreads();
  return red[0] + red[1] + red[2] + red[3];
}
// merge two ascending 5-lists, keep 5 smallest (bitonic lower-half network)
__device__ __forceinline__ void merge5(float& a0, float& a1, float& a2, float& a3, float& a4,
                                       float b0, float b1, float b2, float b3, float b4){
  float l0=a0,l1=a1,l2=a2,l3=fminf(a3,b4),l4=fminf(a4,b3),l5=b2,l6=b1,l7=b0;
  float t0=fminf(l0,l4), t4=fmaxf(l0,l4);
  float t1=fminf(l1,l5), t5=fmaxf(l1,l5);
  float t2=fminf(l2,l6), t6=fmaxf(l2,l6);
  float t3=fminf(l3,l7), t7=fmaxf(l3,l7);
  float u0=fminf(t0,t2), u2=fmaxf(t0,t2);
  float u1=fminf(t1,t3), u3=fmaxf(t1,t3);
  float u4=fminf(t4,t6);
  float u5=fminf(t5,t7);
  a0=fminf(u0,u1); a1=fmaxf(u0,u1);
  a2=fminf(u2,u3); a3=fmaxf(u2,u3);
  a4=fminf(u4,u5);
}
__device__ __forceinline__ int grid_cell(float lx, float ly, int dim){
  // matches _grid_idx: clip -> [0,1] -> round half-even -> clamp
  lx = (fminf(fmaxf(lx, -1.f), 1.f) + 1.f) * 0.5f;
  ly = (fminf(fmaxf(ly, -1.f), 1.f) + 1.f) * 0.5f;
  float s = (float)(dim - 1);
  int col = (int)rintf(lx * s); col = min(max(col, 0), dim - 1);
  int row = (int)rintf(ly * s); row = min(max(row, 0), dim - 1);
  return row * dim + col;
}

// ---------------- stage kernels ----------------
// token2map scatter: B*N*C threads
__global__ __launch_bounds__(256) void t2m_scatter(const float* __restrict__ x,
                                                   const float* __restrict__ loc,
                                                   const int* __restrict__ idx_agg,
                                                   float* __restrict__ xmap, float* __restrict__ cnt){
  int lin = blockIdx.x * 256 + threadIdx.x;       // (b*N+n0)*128 + c
  int c  = lin & 127;
  int bn = lin >> 7;
  int b  = bn >> 12;
  float lx = loc[(size_t)bn*2 + 0];
  float ly = loc[(size_t)bn*2 + 1];
  int cell = grid_cell(lx, ly, 64);
  int ia = idx_agg[bn];
  float val = x[((size_t)(b*NT + ia))*CI + c];
  atomicAdd(&xmap[((size_t)(b*HWI + cell))*CI + c], val);
  if (c == 0) atomicAdd(&cnt[b*HWI + cell], 1.0f);
}

__global__ __launch_bounds__(256) void t2m_norm(float* __restrict__ xmap, const float* __restrict__ cnt){
  int lin = blockIdx.x * 256 + threadIdx.x;       // B*HW*C
  xmap[lin] = xmap[lin] / (cnt[lin >> 7] + EPS_F);
}

// 3x3 stride-2 pad-1 conv: block = (b, oh, owq[0..3]) -> 8 ow each; threads = d
__global__ __launch_bounds__(256) void conv_kernel(const float* __restrict__ xmap,
                                                   const float* __restrict__ cw,
                                                   const float* __restrict__ cb,
                                                   float* __restrict__ ymap){
  int blk = blockIdx.x;
  int b = blk >> 7;
  int r = blk & 127;
  int oh = r >> 2;
  int owq = r & 3;
  int d = threadIdx.x;
  __shared__ float patch[3*17*128];
  for (int idx = d; idx < 3*17*128; idx += 256){
    int kh = idx / (17*128);
    int rr = idx % (17*128);
    int il = rr >> 7;
    int c  = rr & 127;
    int ih = oh*2 - 1 + kh;
    int iw = owq*16 - 1 + il;
    float v = 0.f;
    if (ih >= 0 && ih < 64 && iw >= 0 && iw < 64)
      v = xmap[((size_t)(b*HWI + ih*64 + iw))*CI + c];
    patch[idx] = v;
  }
  __syncthreads();
  float acc[8] = {0,0,0,0,0,0,0,0};
  const float* wd = cw + (size_t)d*1152;   // conv_w[d, c, kh, kw]
  for (int c = 0; c < 128; ++c){
#pragma unroll
    for (int kh = 0; kh < 3; ++kh){
#pragma unroll
      for (int kw = 0; kw < 3; ++kw){
        float w = wd[c*9 + kh*3 + kw];
#pragma unroll
        for (int ow = 0; ow < 8; ++ow)
          acc[ow] += w * patch[(kh*17 + 2*ow + kw)*128 + c];
      }
    }
  }
  float bias = cb[d];
  int ow0 = owq * 8;
  for (int ow = 0; ow < 8; ++ow)
    ymap[((size_t)(b*HWO + oh*32 + ow0 + ow))*DOUT + d] = acc[ow] + bias;
}

// segment-sum of agg_weight per target token
__global__ __launch_bounds__(256) void tot_kernel(const int* __restrict__ idx_agg,
                                                  const float* __restrict__ aggw,
                                                  float* __restrict__ tot){
  int lin = blockIdx.x * 256 + threadIdx.x;       // B*N
  int b = lin >> 12;
  atomicAdd(&tot[b*NT + idx_agg[lin]], aggw[lin]);
}

// xt = x @ skip_w.T  (8 rows per block)
__global__ __launch_bounds__(256) void skip_kernel(const float* __restrict__ x,
                                                   const float* __restrict__ sw,
                                                   float* __restrict__ xt){
  int rowbase = blockIdx.x * 8;                   // over B*N
  int d = threadIdx.x;
  __shared__ float xr[8*128];
  ((float4*)xr)[d] = ((const float4*)(x + (size_t)rowbase*CI))[d];
  __syncthreads();
  float acc[8] = {0,0,0,0,0,0,0,0};
  const float* wd = sw + (size_t)d*CI;
  for (int c = 0; c < 128; ++c){
    float w = wd[c];
#pragma unroll
    for (int r = 0; r < 8; ++r) acc[r] += w * xr[r*128 + c];
  }
  for (int r = 0; r < 8; ++r) xt[(size_t)(rowbase + r)*DOUT + d] = acc[r];
}

// map2token weighted scatter-add into xt; one block per (b, n0), threads = d
__global__ __launch_bounds__(256) void m2t_scatter(const float* __restrict__ ymap,
                                                   const float* __restrict__ loc,
                                                   const int* __restrict__ idx_agg,
                                                   const float* __restrict__ aggw,
                                                   const float* __restrict__ tot,
                                                   float* __restrict__ xt){
  int bn = blockIdx.x;
  int d = threadIdx.x;
  int b = bn >> 12;
  float lx = loc[(size_t)bn*2 + 0];
  float ly = loc[(size_t)bn*2 + 1];
  int cell = grid_cell(lx, ly, 32);
  int ia = idx_agg[bn];
  float w = aggw[bn] / (tot[b*NT + ia] + EPS_F);
  float val = ymap[((size_t)(b*HWO + cell))*DOUT + d] * w;
  atomicAdd(&xt[((size_t)(b*NT + ia))*DOUT + d], val);
}

// layernorm + conf/weight + sq; one block per row
__global__ __launch_bounds__(256) void ln_kernel(float* __restrict__ xt,
                                                 const float* __restrict__ g,
                                                 const float* __restrict__ bta,
                                                 const float* __restrict__ cw,
                                                 const float* __restrict__ cb,
                                                 float* __restrict__ sq, float* __restrict__ wt){
  __shared__ float red[4];
  int row = blockIdx.x;
  int d = threadIdx.x;
  float v = xt[(size_t)row*DOUT + d];
  float mu = blockSum256(v, red) * (1.0f/256.0f);
  float xc = v - mu;
  float var = blockSum256(xc*xc, red) * (1.0f/256.0f);
  float rn = 1.0f / sqrtf(var + 1e-5f);
  float y = xc * rn * g[d] + bta[d];
  xt[(size_t)row*DOUT + d] = y;
  float s2 = blockSum256(y*y, red);
  float cf = blockSum256(y*cw[d], red);
  if (d == 0){ sq[row] = s2; wt[row] = expf(cf + cb[0]); }
}

// gram: G[i,j] = dot(xt_i, xt_j), 4096x4096, K=256.
// 128x128 tile, 256 threads (16x16), 8x8 acc per thread, BK=8.
// k-summation order identical to the previous (passing) version -> bit-identical G.
__global__ __launch_bounds__(256) void gram_kernel(const float* __restrict__ A, float* __restrict__ G){
  __shared__ float As[8][128];
  __shared__ float Bs[8][128];
  int tid = threadIdx.x;
  int i0 = blockIdx.y * 128, j0 = blockIdx.x * 128;
  int lrow = tid >> 1;          // 0..127
  int lc4  = tid & 1;           // 0..1  (float4 within BK=8)
  int ty = tid >> 4, tx = tid & 15;
  int r0 = ty * 8, c0 = tx * 8;
  float acc[8][8] = {{0}};
  for (int kt = 0; kt < 256; kt += 8){
    float4 av = *(const float4*)(A + (size_t)(i0+lrow)*DOUT + kt + lc4*4);
    float4 bv = *(const float4*)(A + (size_t)(j0+lrow)*DOUT + kt + lc4*4);
    __syncthreads();
    As[lc4*4+0][lrow]=av.x; As[lc4*4+1][lrow]=av.y; As[lc4*4+2][lrow]=av.z; As[lc4*4+3][lrow]=av.w;
    Bs[lc4*4+0][lrow]=bv.x; Bs[lc4*4+1][lrow]=bv.y; Bs[lc4*4+2][lrow]=bv.z; Bs[lc4*4+3][lrow]=bv.w;
    __syncthreads();
#pragma unroll
    for (int k = 0; k < 8; ++k){
      float ar[8], br[8];
      *(float4*)&ar[0] = *(const float4*)&As[k][r0];
      *(float4*)&ar[4] = *(const float4*)&As[k][r0+4];
      *(float4*)&br[0] = *(const float4*)&Bs[k][c0];
      *(float4*)&br[4] = *(const float4*)&Bs[k][c0+4];
#pragma unroll
      for (int r = 0; r < 8; ++r)
#pragma unroll
        for (int s = 0; s < 8; ++s) acc[r][s] += ar[r]*br[s];
    }
  }
  for (int r = 0; r < 8; ++r){
    *(float4*)(G + (size_t)(i0 + r0 + r)*NT + j0 + c0)     = *(float4*)&acc[r][0];
    *(float4*)(G + (size_t)(i0 + r0 + r)*NT + j0 + c0 + 4) = *(float4*)&acc[r][4];
  }
}

// density + per-batch max(v); one block per row i
__global__ __launch_bounds__(256) void density_kernel(const float* __restrict__ G, const float* __restrict__ sq,
                                                      float* __restrict__ density, int* __restrict__ vmax, int b){
  int i = blockIdx.x;
  int tid = threadIdx.x;
  const float* sqb = sq + b*NT;
  float sqi = sqb[i];
  const float* row = G + (size_t)i*NT;
  float t0=INFINITY,t1=INFINITY,t2=INFINITY,t3=INFINITY,t4=INFINITY;
  float vmx = 0.f;
  for (int j = tid; j < NT; j += 256){
    float v = fmaxf(sqi + sqb[j] - 2.0f*row[j], 0.0f);
    vmx = fmaxf(vmx, v);
    // branchless insert keeping 5 smallest, ascending
    t4 = fminf(t4, v);
    float a;
    a = fminf(t3,t4); t4 = fmaxf(t3,t4); t3 = a;
    a = fminf(t2,t3); t3 = fmaxf(t2,t3); t2 = a;
    a = fminf(t1,t2); t2 = fmaxf(t1,t2); t1 = a;
    a = fminf(t0,t1); t1 = fmaxf(t0,t1); t0 = a;
  }
#pragma unroll
  for (int m = 1; m < 64; m <<= 1){
    float b0=__shfl_xor(t0,m,64), b1=__shfl_xor(t1,m,64), b2=__shfl_xor(t2,m,64),
          b3=__shfl_xor(t3,m,64), b4=__shfl_xor(t4,m,64);
    merge5(t0,t1,t2,t3,t4,b0,b1,b2,b3,b4);
    vmx = fmaxf(vmx, __shfl_xor(vmx,m,64));
  }
  __shared__ float w5[4][5];
  __shared__ float wm[4];
  int lane = tid & 63, wid = tid >> 6;
  if (lane == 0){ w5[wid][0]=t0; w5[wid][1]=t1; w5[wid][2]=t2; w5[wid][3]=t3; w5[wid][4]=t4; wm[wid]=vmx; }
  __syncthreads();
  if (tid == 0){
    float a0=w5[0][0],a1=w5[0][1],a2=w5[0][2],a3=w5[0][3],a4=w5[0][4];
    for (int w = 1; w < 4; ++w) merge5(a0,a1,a2,a3,a4, w5[w][0],w5[w][1],w5[w][2],w5[w][3],w5[w][4]);
    float d0=sqrtf(a0)*0.0625f, d1=sqrtf(a1)*0.0625f, d2=sqrtf(a2)*0.0625f,
          d3=sqrtf(a3)*0.0625f, d4=sqrtf(a4)*0.0625f;
    float s = d0*d0; s += d1*d1; s += d2*d2; s += d3*d3; s += d4*d4;
    density[b*NT + i] = expf(-(s / 5.0f));
    float vm = fmaxf(fmaxf(wm[0],wm[1]), fmaxf(wm[2],wm[3]));
    atomicMax(vmax + b, __float_as_int(vm));   // nonneg floats: int order == float order
  }
}

// d_parent & score; one block per row i
__global__ __launch_bounds__(256) void parent_kernel(const float* __restrict__ G, const float* __restrict__ sq,
                                                     const float* __restrict__ density, const int* __restrict__ vmax,
                                                     float* __restrict__ score, int b){
  int i = blockIdx.x;
  int tid = threadIdx.x;
  const float* sqb = sq + b*NT;
  const float* den = density + b*NT;
  float sqi = sqb[i];
  float di = den[i];
  const float* row = G + (size_t)i*NT;
  float minv = INFINITY;
  for (int j = tid; j < NT; j += 256){
    float v = fmaxf(sqi + sqb[j] - 2.0f*row[j], 0.0f);
    minv = fminf(minv, (den[j] > di) ? v : INFINITY);
  }
#pragma unroll
  for (int m = 1; m < 64; m <<= 1) minv = fminf(minv, __shfl_xor(minv,m,64));
  __shared__ float wmn[4];
  int lane = tid & 63, wid = tid >> 6;
  if (lane == 0) wmn[wid] = minv;
  __syncthreads();
  if (tid == 0){
    float mv = fminf(fminf(wmn[0],wmn[1]), fminf(wmn[2],wmn[3]));
    float dmax = sqrtf(__int_as_float(vmax[b])) * 0.0625f;
    float dp = isinf(mv) ? dmax : sqrtf(mv) * 0.0625f;
    score[b*NT + i] = dp * di;
  }
}

// full bitonic sort of 4096 (score desc, idx asc) -> first M indices
__global__ __launch_bounds__(1024) void topk_sort(const float* __restrict__ score, int* __restrict__ idx_down, int b){
  __shared__ float ss[4096];
  __shared__ int ii[4096];
  int tid = threadIdx.x;
  for (int t = tid; t < 4096; t += 1024){ ss[t] = score[b*NT + t]; ii[t] = t; }
  for (int k = 2; k <= 4096; k <<= 1){
    for (int j = k >> 1; j > 0; j >>= 1){
      __syncthreads();
      for (int t = tid; t < 4096; t += 1024){
        int p = t ^ j;
        if (p > t){
          float s1 = ss[t], s2 = ss[p];
          int i1 = ii[t], i2 = ii[p];
          bool lt = (s1 > s2) || (s1 == s2 && i1 < i2);  // t precedes p in desired order
          bool up = ((t & k) == 0);
          if (up ? !lt : lt){ ss[t]=s2; ss[p]=s1; ii[t]=i2; ii[p]=i1; }
        }
      }
    }
  }
  __syncthreads();
  if (tid < MC) idx_down[b*MC + tid] = ii[tid];
}

// nearest-center assignment; block = 64 j's x 4 m-chunks
__global__ __launch_bounds__(256) void assign_kernel(const float* __restrict__ G, const float* __restrict__ sq,
                                                     const int* __restrict__ idx_down, int* __restrict__ idx_cluster, int b){
  int jl = threadIdx.x & 63, mq = threadIdx.x >> 6;
  int j = blockIdx.x * 64 + jl;
  const float* sqb = sq + b*NT;
  float sqj = sqb[j];
  const int* idb = idx_down + b*MC;
  float bestd = INFINITY; int bestm = 0x7fffffff;
  for (int m = mq*256; m < mq*256 + 256; ++m){
    int im = idb[m];
    float g = G[(size_t)im*NT + j];
    float v = fmaxf(sqb[im] + sqj - 2.0f*g, 0.0f);
    float d = sqrtf(v) * 0.0625f;
    if (d < bestd){ bestd = d; bestm = m; }        // first-min tie rule within chunk
  }
  __shared__ float ld[4][64];
  __shared__ int lm[4][64];
  ld[mq][jl] = bestd; lm[mq][jl] = bestm;
  __syncthreads();
  if (mq == 0){
    for (int q = 1; q < 4; ++q){
      float d2 = ld[q][jl]; int m2 = lm[q][jl];
      if (d2 < bestd || (d2 == bestd && m2 < bestm)){ bestd = d2; bestm = m2; }
    }
    idx_cluster[b*NT + j] = bestm;
  }
}

__global__ __launch_bounds__(256) void override_kernel(const int* __restrict__ idx_down, int* __restrict__ idx_cluster, int b){
  int m = blockIdx.x * 256 + threadIdx.x;
  if (m < MC) idx_cluster[b*NT + idx_down[b*MC + m]] = m;
}

// ---- merge + outputs ----
__global__ __launch_bounds__(256) void allw_kernel(const int* __restrict__ idx_cluster, const float* __restrict__ wt,
                                                   float* __restrict__ allw){
  int lin = blockIdx.x * 256 + threadIdx.x;       // B*N
  int b = lin >> 12;
  atomicAdd(&allw[b*MC + idx_cluster[lin]], wt[lin]);
}
__global__ __launch_bounds__(256) void normw_kernel(const int* __restrict__ idx_cluster, const float* __restrict__ wt,
                                                    const float* __restrict__ allw, float* __restrict__ nw){
  int lin = blockIdx.x * 256 + threadIdx.x;
  int b = lin >> 12;
  nw[lin] = wt[lin] / (allw[b*MC + idx_cluster[lin]] + EPS_F);
}
__global__ __launch_bounds__(256) void xdown_kernel(const int* __restrict__ idx_cluster, const float* __restrict__ nw,
                                                    const float* __restrict__ xt, float* __restrict__ xdown){
  int bn = blockIdx.x;
  int d = threadIdx.x;
  int b = bn >> 12;
  int ic = idx_cluster[bn];
  float v = xt[(size_t)bn*DOUT + d] * nw[bn];
  atomicAdd(&xdown[((size_t)(b*MC + ic))*DOUT + d], v);
}
__global__ __launch_bounds__(256) void out0_kernel(const float* __restrict__ xdown, float* __restrict__ out){
  int lin = blockIdx.x * 256 + threadIdx.x;       // B*M*D
  out[lin] = xdown[lin];
}
// block-reduced max -> one atomic per block (was: 16384 atomics on 4 addresses = 188 us)
__global__ __launch_bounds__(256) void out12a_kernel(const int* __restrict__ idx_agg, const int* __restrict__ idx_cluster,
                                                     const float* __restrict__ aggw, const float* __restrict__ nw,
                                                     float* __restrict__ awd, int* __restrict__ awdmax,
                                                     float* __restrict__ out1){
  __shared__ float red[4];
  int lin = blockIdx.x * 256 + threadIdx.x;       // B*N ; each block within one batch
  int b = lin >> 12;
  int ia = idx_agg[lin];
  int ic = idx_cluster[b*NT + ia];
  out1[lin] = (float)ic;
  float v = aggw[lin] * nw[b*NT + ia];
  awd[lin] = v;
  float wv = v;
#pragma unroll
  for (int m = 1; m < 64; m <<= 1) wv = fmaxf(wv, __shfl_xor(wv, m, 64));
  int lane = threadIdx.x & 63, wid = threadIdx.x >> 6;
  if (lane == 0) red[wid] = wv;
  __syncthreads();
  if (threadIdx.x == 0){
    float bm = fmaxf(fmaxf(red[0], red[1]), fmaxf(red[2], red[3]));
    atomicMax(&awdmax[b], __float_as_int(bm));    // nonneg
  }
}
__global__ __launch_bounds__(256) void out2_kernel(const float* __restrict__ awd, const int* __restrict__ awdmax,
                                                   float* __restrict__ out2){
  int lin = blockIdx.x * 256 + threadIdx.x;
  int b = lin >> 12;
  out2[lin] = awd[lin] / __int_as_float(awdmax[b]);
}

extern "C" void kernel_launch(void* const* d_in, const int* in_sizes, int n_in,
                              void* d_out, int out_size, void* d_ws, size_t ws_size,
                              hipStream_t stream) {
  const float* x      = (const float*)d_in[0];   // f32 (B,N,C)
  const float* loc    = (const float*)d_in[1];   // f32 (B,N,2)
  const int*   idxagg = (const int*)d_in[2];     // (B,N)
  const float* aggw   = (const float*)d_in[3];   // f32 (B,N,1)
  // d_in[4]=H, d_in[5]=W (hard-coded), d_in[6]=idx_k_loc unused
  const float* convw  = (const float*)d_in[7];   // f32 (256,128,3,3)
  const float* convb  = (const float*)d_in[8];
  const float* skipw  = (const float*)d_in[9];   // f32 (256,128)
  const float* lng    = (const float*)d_in[10];
  const float* lnb    = (const float*)d_in[11];
  const float* confw  = (const float*)d_in[12];
  const float* confb  = (const float*)d_in[13];

  char* ws = (char*)d_ws;
  float* w_xmap  = (float*)(ws + OFF_XMAP);
  float* w_cnt   = (float*)(ws + OFF_CNT);
  float* w_tot   = (float*)(ws + OFF_TOT);
  float* w_allw  = (float*)(ws + OFF_ALLW);
  float* w_xdown = (float*)(ws + OFF_XDOWN);
  int*   w_vmax  = (int*)  (ws + OFF_VMAX);
  int*   w_awdm  = (int*)  (ws + OFF_AWDM);
  float* w_ymap  = (float*)(ws + OFF_YMAP);
  float* w_xt    = (float*)(ws + OFF_XT);
  float* w_sq    = (float*)(ws + OFF_SQ);
  float* w_den   = (float*)(ws + OFF_DEN);
  float* w_score = (float*)(ws + OFF_SCORE);
  float* w_wt    = (float*)(ws + OFF_WT);
  float* w_nw    = (float*)(ws + OFF_NW);
  float* w_awd   = (float*)(ws + OFF_AWD);
  int*   w_idxd  = (int*)  (ws + OFF_IDXD);
  int*   w_idxc  = (int*)  (ws + OFF_IDXC);
  float* w_gram  = (float*)(ws + OFF_GRAM);

  float* out0 = (float*)d_out;
  float* out1 = out0 + NB*MC*DOUT;
  float* out2 = out1 + NB*NT;

  hipMemsetAsync(ws, 0, ZERO_BYTES, stream);

  t2m_scatter<<<NB*NT*CI/256, 256, 0, stream>>>(x, loc, idxagg, w_xmap, w_cnt);
  t2m_norm<<<NB*HWI*CI/256, 256, 0, stream>>>(w_xmap, w_cnt);
  conv_kernel<<<NB*32*4, 256, 0, stream>>>(w_xmap, convw, convb, w_ymap);
  tot_kernel<<<NB*NT/256, 256, 0, stream>>>(idxagg, aggw, w_tot);
  skip_kernel<<<NB*NT/8, 256, 0, stream>>>(x, skipw, w_xt);
  m2t_scatter<<<NB*NT, 256, 0, stream>>>(w_ymap, loc, idxagg, aggw, w_tot, w_xt);
  ln_kernel<<<NB*NT, 256, 0, stream>>>(w_xt, lng, lnb, confw, confb, w_sq, w_wt);

  for (int b = 0; b < NB; ++b){
    gram_kernel<<<dim3(32,32), 256, 0, stream>>>(w_xt + (size_t)b*NT*DOUT, w_gram);
    density_kernel<<<NT, 256, 0, stream>>>(w_gram, w_sq, w_den, w_vmax, b);
    parent_kernel<<<NT, 256, 0, stream>>>(w_gram, w_sq, w_den, w_vmax, w_score, b);
    topk_sort<<<1, 1024, 0, stream>>>(w_score, w_idxd, b);
    assign_kernel<<<64, 256, 0, stream>>>(w_gram, w_sq, w_idxd, w_idxc, b);
    override_kernel<<<4, 256, 0, stream>>>(w_idxd, w_idxc, b);
  }

  allw_kernel<<<NB*NT/256, 256, 0, stream>>>(w_idxc, w_wt, w_allw);
  normw_kernel<<<NB*NT/256, 256, 0, stream>>>(w_idxc, w_wt, w_allw, w_nw);
  xdown_kernel<<<NB*NT, 256, 0, stream>>>(w_idxc, w_nw, w_xt, w_xdown);
  out0_kernel<<<NB*MC*DOUT/256, 256, 0, stream>>>(w_xdown, out0);
  out12a_kernel<<<NB*NT/256, 256, 0, stream>>>(idxagg, w_idxc, aggw, w_nw, w_awd, w_awdm, out1);
  out2_kernel<<<NB*NT/256, 256, 0, stream>>>(w_awd, w_awdm, out2);

  (void)in_sizes; (void)n_in; (void)out_size; (void)ws_size;
}

// Round 5
// 1450.731 us; speedup vs baseline: 1.2052x; 1.0411x over previous
//
#include <hip/hip_runtime.h>
#include <math.h>

// Fixed problem sizes (from setup_inputs): B=4, N=4096, C=128, DOUT=256,
// H=W=64 (conv out 32x32), M = N/4 = 1024 clusters, K=5 NN.
// Inputs float32; output buffer float32 (concatenated x_down, idx, agg_w).
#define NB 4
#define NT 4096
#define CI 128
#define DOUT 256
#define HWI 4096
#define HWO 1024
#define MC 1024
#define EPS_F 1e-6f

// ---------------- workspace layout (bytes) ----------------
// zero zone (memset each launch):
static const size_t OFF_XMAP  = 0;                          // 4*4096*128*4 = 8388608
static const size_t OFF_CNT   = OFF_XMAP + 8388608;         // 65536
static const size_t OFF_TOT   = OFF_CNT  + 65536;           // 65536
static const size_t OFF_ALLW  = OFF_TOT  + 65536;           // 16384
static const size_t OFF_XDOWN = OFF_ALLW + 16384;           // 4194304
static const size_t OFF_VMAX  = OFF_XDOWN + 4194304;        // 256 (4 ints used)
static const size_t OFF_AWDM  = OFF_VMAX + 256;             // 256 (4 ints used)
static const size_t ZERO_BYTES= OFF_AWDM + 256;
// non-zeroed:
static const size_t OFF_YMAP  = ZERO_BYTES;                 // 4*1024*256*4 = 4194304
static const size_t OFF_XT    = OFF_YMAP + 4194304;         // 4*4096*256*4 = 16777216
static const size_t OFF_SQ    = OFF_XT + 16777216;          // 65536
static const size_t OFF_DEN   = OFF_SQ + 65536;             // 65536
static const size_t OFF_SCORE = OFF_DEN + 65536;            // 65536
static const size_t OFF_WT    = OFF_SCORE + 65536;          // 65536
static const size_t OFF_NW    = OFF_WT + 65536;             // 65536
static const size_t OFF_AWD   = OFF_NW + 65536;             // 65536
static const size_t OFF_IDXD  = OFF_AWD + 65536;            // 16384
static const size_t OFF_IDXC  = OFF_IDXD + 16384;           // 65536
static const size_t OFF_GRAM  = OFF_IDXC + 65536;           // 4096*4096*4 = 67108864

// ---------------- helpers ----------------
__device__ __forceinline__ float waveSum(float v){
#pragma unroll
  for (int m = 1; m < 64; m <<= 1) v += __shfl_xor(v, m, 64);
  return v;
}
__device__ __forceinline__ float blockSum256(float v, float* red){
  v = waveSum(v);
  int lane = threadIdx.x & 63, wid = threadIdx.x >> 6;
  __syncthreads();
  if (lane == 0) red[wid] = v;
  __syncthreads();
  return red[0] + red[1] + red[2] + red[3];
}
// merge two ascending 5-lists, keep 5 smallest (bitonic lower-half network)
__device__ __forceinline__ void merge5(float& a0, float& a1, float& a2, float& a3, float& a4,
                                       float b0, float b1, float b2, float b3, float b4){
  float l0=a0,l1=a1,l2=a2,l3=fminf(a3,b4),l4=fminf(a4,b3),l5=b2,l6=b1,l7=b0;
  float t0=fminf(l0,l4), t4=fmaxf(l0,l4);
  float t1=fminf(l1,l5), t5=fmaxf(l1,l5);
  float t2=fminf(l2,l6), t6=fmaxf(l2,l6);
  float t3=fminf(l3,l7), t7=fmaxf(l3,l7);
  float u0=fminf(t0,t2), u2=fmaxf(t0,t2);
  float u1=fminf(t1,t3), u3=fmaxf(t1,t3);
  float u4=fminf(t4,t6);
  float u5=fminf(t5,t7);
  a0=fminf(u0,u1); a1=fmaxf(u0,u1);
  a2=fminf(u2,u3); a3=fmaxf(u2,u3);
  a4=fminf(u4,u5);
}
__device__ __forceinline__ int grid_cell(float lx, float ly, int dim){
  // matches _grid_idx: clip -> [0,1] -> round half-even -> clamp
  lx = (fminf(fmaxf(lx, -1.f), 1.f) + 1.f) * 0.5f;
  ly = (fminf(fmaxf(ly, -1.f), 1.f) + 1.f) * 0.5f;
  float s = (float)(dim - 1);
  int col = (int)rintf(lx * s); col = min(max(col, 0), dim - 1);
  int row = (int)rintf(ly * s); row = min(max(row, 0), dim - 1);
  return row * dim + col;
}

// ---------------- stage kernels ----------------
// token2map scatter: B*N*C threads
__global__ __launch_bounds__(256) void t2m_scatter(const float* __restrict__ x,
                                                   const float* __restrict__ loc,
                                                   const int* __restrict__ idx_agg,
                                                   float* __restrict__ xmap, float* __restrict__ cnt){
  int lin = blockIdx.x * 256 + threadIdx.x;       // (b*N+n0)*128 + c
  int c  = lin & 127;
  int bn = lin >> 7;
  int b  = bn >> 12;
  float lx = loc[(size_t)bn*2 + 0];
  float ly = loc[(size_t)bn*2 + 1];
  int cell = grid_cell(lx, ly, 64);
  int ia = idx_agg[bn];
  float val = x[((size_t)(b*NT + ia))*CI + c];
  atomicAdd(&xmap[((size_t)(b*HWI + cell))*CI + c], val);
  if (c == 0) atomicAdd(&cnt[b*HWI + cell], 1.0f);
}

__global__ __launch_bounds__(256) void t2m_norm(float* __restrict__ xmap, const float* __restrict__ cnt){
  int lin = blockIdx.x * 256 + threadIdx.x;       // B*HW*C
  xmap[lin] = xmap[lin] / (cnt[lin >> 7] + EPS_F);
}

// 3x3 stride-2 pad-1 conv: block = (b, oh, owq[0..3]) -> 8 ow each; threads = d
// weights staged in LDS per c-chunk (removes 1152 uncoalesced global loads/thread)
__global__ __launch_bounds__(256) void conv_kernel(const float* __restrict__ xmap,
                                                   const float* __restrict__ cw,
                                                   const float* __restrict__ cb,
                                                   float* __restrict__ ymap){
  int blk = blockIdx.x;
  int b = blk >> 7;
  int r = blk & 127;
  int oh = r >> 2;
  int owq = r & 3;
  int tid = threadIdx.x;
  __shared__ float patch[3*17*128];     // [kh][il][c], 26.1 KB
  __shared__ float wlds[256*37];        // [d][36+1pad], 37.9 KB
  for (int idx = tid; idx < 3*17*128; idx += 256){
    int kh = idx / (17*128);
    int rr = idx % (17*128);
    int il = rr >> 7;
    int c  = rr & 127;
    int ih = oh*2 - 1 + kh;
    int iw = owq*16 - 1 + il;
    float v = 0.f;
    if (ih >= 0 && ih < 64 && iw >= 0 && iw < 64)
      v = xmap[((size_t)(b*HWI + ih*64 + iw))*CI + c];
    patch[idx] = v;
  }
  float acc[8] = {0,0,0,0,0,0,0,0};
  for (int cc0 = 0; cc0 < 128; cc0 += 4){
    __syncthreads();                     // protect previous chunk reads (and patch load, first iter)
    for (int idx = tid; idx < 256*36; idx += 256){
      int dd = idx / 36;
      int e  = idx - dd*36;
      wlds[dd*37 + e] = cw[(size_t)dd*1152 + cc0*9 + e];
    }
    __syncthreads();
#pragma unroll
    for (int cc = 0; cc < 4; ++cc){
      int c = cc0 + cc;
      const float* wp = &wlds[tid*37 + cc*9];
#pragma unroll
      for (int kh = 0; kh < 3; ++kh){
#pragma unroll
        for (int kw = 0; kw < 3; ++kw){
          float w = wp[kh*3 + kw];
#pragma unroll
          for (int ow = 0; ow < 8; ++ow)
            acc[ow] += w * patch[(kh*17 + 2*ow + kw)*128 + c];
        }
      }
    }
  }
  float bias = cb[tid];
  int ow0 = owq * 8;
  for (int ow = 0; ow < 8; ++ow)
    ymap[((size_t)(b*HWO + oh*32 + ow0 + ow))*DOUT + tid] = acc[ow] + bias;
}

// segment-sum of agg_weight per target token
__global__ __launch_bounds__(256) void tot_kernel(const int* __restrict__ idx_agg,
                                                  const float* __restrict__ aggw,
                                                  float* __restrict__ tot){
  int lin = blockIdx.x * 256 + threadIdx.x;       // B*N
  int b = lin >> 12;
  atomicAdd(&tot[b*NT + idx_agg[lin]], aggw[lin]);
}

// xt = x @ skip_w.T  (8 rows per block)
__global__ __launch_bounds__(256) void skip_kernel(const float* __restrict__ x,
                                                   const float* __restrict__ sw,
                                                   float* __restrict__ xt){
  int rowbase = blockIdx.x * 8;                   // over B*N
  int d = threadIdx.x;
  __shared__ float xr[8*128];
  ((float4*)xr)[d] = ((const float4*)(x + (size_t)rowbase*CI))[d];
  __syncthreads();
  float acc[8] = {0,0,0,0,0,0,0,0};
  const float* wd = sw + (size_t)d*CI;
  for (int c = 0; c < 128; ++c){
    float w = wd[c];
#pragma unroll
    for (int r = 0; r < 8; ++r) acc[r] += w * xr[r*128 + c];
  }
  for (int r = 0; r < 8; ++r) xt[(size_t)(rowbase + r)*DOUT + d] = acc[r];
}

// map2token weighted scatter-add into xt; one block per (b, n0), threads = d
__global__ __launch_bounds__(256) void m2t_scatter(const float* __restrict__ ymap,
                                                   const float* __restrict__ loc,
                                                   const int* __restrict__ idx_agg,
                                                   const float* __restrict__ aggw,
                                                   const float* __restrict__ tot,
                                                   float* __restrict__ xt){
  int bn = blockIdx.x;
  int d = threadIdx.x;
  int b = bn >> 12;
  float lx = loc[(size_t)bn*2 + 0];
  float ly = loc[(size_t)bn*2 + 1];
  int cell = grid_cell(lx, ly, 32);
  int ia = idx_agg[bn];
  float w = aggw[bn] / (tot[b*NT + ia] + EPS_F);
  float val = ymap[((size_t)(b*HWO + cell))*DOUT + d] * w;
  atomicAdd(&xt[((size_t)(b*NT + ia))*DOUT + d], val);
}

// layernorm + conf/weight + sq; one block per row
__global__ __launch_bounds__(256) void ln_kernel(float* __restrict__ xt,
                                                 const float* __restrict__ g,
                                                 const float* __restrict__ bta,
                                                 const float* __restrict__ cw,
                                                 const float* __restrict__ cb,
                                                 float* __restrict__ sq, float* __restrict__ wt){
  __shared__ float red[4];
  int row = blockIdx.x;
  int d = threadIdx.x;
  float v = xt[(size_t)row*DOUT + d];
  float mu = blockSum256(v, red) * (1.0f/256.0f);
  float xc = v - mu;
  float var = blockSum256(xc*xc, red) * (1.0f/256.0f);
  float rn = 1.0f / sqrtf(var + 1e-5f);
  float y = xc * rn * g[d] + bta[d];
  xt[(size_t)row*DOUT + d] = y;
  float s2 = blockSum256(y*y, red);
  float cf = blockSum256(y*cw[d], red);
  if (d == 0){ sq[row] = s2; wt[row] = expf(cf + cb[0]); }
}

// gram: G[i,j] = dot(xt_i, xt_j), symmetric -> compute only lower-triangle
// 128-tiles (528 blocks). 256 threads, 8x8 acc, BK=8. Per-thread cols split
// {tx*4, 64+tx*4} so both b128 B-reads hit the free 2-way bank pattern.
// k-order ascending -> bit-identical output values.
__global__ __launch_bounds__(256) void gram_kernel(const float* __restrict__ A, float* __restrict__ G){
  __shared__ float As[8][128];
  __shared__ float Bs[8][128];
  int t = blockIdx.x;
  int ti = 0, accu = 0;
  while (accu + ti + 1 <= t){ accu += ti + 1; ++ti; }
  int tj = t - accu;                       // tj <= ti
  int i0 = ti * 128, j0 = tj * 128;
  int tid = threadIdx.x;
  int lrow = tid >> 1;          // 0..127
  int lc4  = tid & 1;           // float4 half of BK=8
  int ty = tid >> 4, tx = tid & 15;
  int r0 = ty * 8;
  int cA = tx * 4, cB = 64 + tx * 4;
  float acc[8][8] = {{0}};
  for (int kt = 0; kt < 256; kt += 8){
    float4 av = *(const float4*)(A + (size_t)(i0+lrow)*DOUT + kt + lc4*4);
    float4 bv = *(const float4*)(A + (size_t)(j0+lrow)*DOUT + kt + lc4*4);
    __syncthreads();
    As[lc4*4+0][lrow]=av.x; As[lc4*4+1][lrow]=av.y; As[lc4*4+2][lrow]=av.z; As[lc4*4+3][lrow]=av.w;
    Bs[lc4*4+0][lrow]=bv.x; Bs[lc4*4+1][lrow]=bv.y; Bs[lc4*4+2][lrow]=bv.z; Bs[lc4*4+3][lrow]=bv.w;
    __syncthreads();
#pragma unroll
    for (int k = 0; k < 8; ++k){
      float ar[8], br[8];
      *(float4*)&ar[0] = *(const float4*)&As[k][r0];
      *(float4*)&ar[4] = *(const float4*)&As[k][r0+4];
      *(float4*)&br[0] = *(const float4*)&Bs[k][cA];
      *(float4*)&br[4] = *(const float4*)&Bs[k][cB];
#pragma unroll
      for (int r = 0; r < 8; ++r)
#pragma unroll
        for (int s = 0; s < 8; ++s) acc[r][s] += ar[r]*br[s];
    }
  }
  for (int r = 0; r < 8; ++r){
    size_t row = (size_t)(i0 + r0 + r);
    *(float4*)(G + row*NT + j0 + cA) = *(float4*)&acc[r][0];
    *(float4*)(G + row*NT + j0 + cB) = *(float4*)&acc[r][4];
  }
}

// mirror strict-lower 128-tiles to upper triangle via 64x64 LDS transpose.
// grid = 496*4 blocks; bit-exact copy (G is exactly symmetric by construction).
__global__ __launch_bounds__(256) void mirror_kernel(float* __restrict__ G){
  __shared__ float tile[64*65];
  int blk = blockIdx.x;
  int q = blk & 3; int t = blk >> 2;
  int ti = 1, accu = 0;
  while (accu + ti <= t){ accu += ti; ++ti; }
  int tj = t - accu;                        // tj < ti
  int qa = q >> 1, qb = q & 1;
  int rs = ti*128 + qa*64, cs = tj*128 + qb*64;   // source (lower)
  int rd = tj*128 + qb*64, cd = ti*128 + qa*64;   // dest (upper)
  int lane = threadIdx.x & 63, w = threadIdx.x >> 6;
  for (int i = 0; i < 16; ++i){
    int r = w*16 + i;
    tile[r*65 + lane] = G[(size_t)(rs + r)*NT + cs + lane];
  }
  __syncthreads();
  for (int i = 0; i < 16; ++i){
    int r = w*16 + i;
    G[(size_t)(rd + r)*NT + cd + lane] = tile[lane*65 + r];
  }
}

// density + per-batch max(v); one block per row i
__global__ __launch_bounds__(256) void density_kernel(const float* __restrict__ G, const float* __restrict__ sq,
                                                      float* __restrict__ density, int* __restrict__ vmax, int b){
  int i = blockIdx.x;
  int tid = threadIdx.x;
  const float* sqb = sq + b*NT;
  float sqi = sqb[i];
  const float* row = G + (size_t)i*NT;
  float t0=INFINITY,t1=INFINITY,t2=INFINITY,t3=INFINITY,t4=INFINITY;
  float vmx = 0.f;
  for (int j = tid; j < NT; j += 256){
    float v = fmaxf(sqi + sqb[j] - 2.0f*row[j], 0.0f);
    vmx = fmaxf(vmx, v);
    // branchless insert keeping 5 smallest, ascending
    t4 = fminf(t4, v);
    float a;
    a = fminf(t3,t4); t4 = fmaxf(t3,t4); t3 = a;
    a = fminf(t2,t3); t3 = fmaxf(t2,t3); t2 = a;
    a = fminf(t1,t2); t2 = fmaxf(t1,t2); t1 = a;
    a = fminf(t0,t1); t1 = fmaxf(t0,t1); t0 = a;
  }
#pragma unroll
  for (int m = 1; m < 64; m <<= 1){
    float b0=__shfl_xor(t0,m,64), b1=__shfl_xor(t1,m,64), b2=__shfl_xor(t2,m,64),
          b3=__shfl_xor(t3,m,64), b4=__shfl_xor(t4,m,64);
    merge5(t0,t1,t2,t3,t4,b0,b1,b2,b3,b4);
    vmx = fmaxf(vmx, __shfl_xor(vmx,m,64));
  }
  __shared__ float w5[4][5];
  __shared__ float wm[4];
  int lane = tid & 63, wid = tid >> 6;
  if (lane == 0){ w5[wid][0]=t0; w5[wid][1]=t1; w5[wid][2]=t2; w5[wid][3]=t3; w5[wid][4]=t4; wm[wid]=vmx; }
  __syncthreads();
  if (tid == 0){
    float a0=w5[0][0],a1=w5[0][1],a2=w5[0][2],a3=w5[0][3],a4=w5[0][4];
    for (int w = 1; w < 4; ++w) merge5(a0,a1,a2,a3,a4, w5[w][0],w5[w][1],w5[w][2],w5[w][3],w5[w][4]);
    float d0=sqrtf(a0)*0.0625f, d1=sqrtf(a1)*0.0625f, d2=sqrtf(a2)*0.0625f,
          d3=sqrtf(a3)*0.0625f, d4=sqrtf(a4)*0.0625f;
    float s = d0*d0; s += d1*d1; s += d2*d2; s += d3*d3; s += d4*d4;
    density[b*NT + i] = expf(-(s / 5.0f));
    float vm = fmaxf(fmaxf(wm[0],wm[1]), fmaxf(wm[2],wm[3]));
    atomicMax(vmax + b, __float_as_int(vm));   // nonneg floats: int order == float order
  }
}

// d_parent & score; one block per row i
__global__ __launch_bounds__(256) void parent_kernel(const float* __restrict__ G, const float* __restrict__ sq,
                                                     const float* __restrict__ density, const int* __restrict__ vmax,
                                                     float* __restrict__ score, int b){
  int i = blockIdx.x;
  int tid = threadIdx.x;
  const float* sqb = sq + b*NT;
  const float* den = density + b*NT;
  float sqi = sqb[i];
  float di = den[i];
  const float* row = G + (size_t)i*NT;
  float minv = INFINITY;
  for (int j = tid; j < NT; j += 256){
    float v = fmaxf(sqi + sqb[j] - 2.0f*row[j], 0.0f);
    minv = fminf(minv, (den[j] > di) ? v : INFINITY);
  }
#pragma unroll
  for (int m = 1; m < 64; m <<= 1) minv = fminf(minv, __shfl_xor(minv,m,64));
  __shared__ float wmn[4];
  int lane = tid & 63, wid = tid >> 6;
  if (lane == 0) wmn[wid] = minv;
  __syncthreads();
  if (tid == 0){
    float mv = fminf(fminf(wmn[0],wmn[1]), fminf(wmn[2],wmn[3]));
    float dmax = sqrtf(__int_as_float(vmax[b])) * 0.0625f;
    float dp = isinf(mv) ? dmax : sqrtf(mv) * 0.0625f;
    score[b*NT + i] = dp * di;
  }
}

// full bitonic sort of 4096 (score desc, idx asc) -> first M indices
__global__ __launch_bounds__(1024) void topk_sort(const float* __restrict__ score, int* __restrict__ idx_down, int b){
  __shared__ float ss[4096];
  __shared__ int ii[4096];
  int tid = threadIdx.x;
  for (int t = tid; t < 4096; t += 1024){ ss[t] = score[b*NT + t]; ii[t] = t; }
  for (int k = 2; k <= 4096; k <<= 1){
    for (int j = k >> 1; j > 0; j >>= 1){
      __syncthreads();
      for (int t = tid; t < 4096; t += 1024){
        int p = t ^ j;
        if (p > t){
          float s1 = ss[t], s2 = ss[p];
          int i1 = ii[t], i2 = ii[p];
          bool lt = (s1 > s2) || (s1 == s2 && i1 < i2);  // t precedes p in desired order
          bool up = ((t & k) == 0);
          if (up ? !lt : lt){ ss[t]=s2; ss[p]=s1; ii[t]=i2; ii[p]=i1; }
        }
      }
    }
  }
  __syncthreads();
  if (tid < MC) idx_down[b*MC + tid] = ii[tid];
}

// nearest-center assignment; block = 64 j's x 4 m-chunks
__global__ __launch_bounds__(256) void assign_kernel(const float* __restrict__ G, const float* __restrict__ sq,
                                                     const int* __restrict__ idx_down, int* __restrict__ idx_cluster, int b){
  int jl = threadIdx.x & 63, mq = threadIdx.x >> 6;
  int j = blockIdx.x * 64 + jl;
  const float* sqb = sq + b*NT;
  float sqj = sqb[j];
  const int* idb = idx_down + b*MC;
  float bestd = INFINITY; int bestm = 0x7fffffff;
  for (int m = mq*256; m < mq*256 + 256; ++m){
    int im = idb[m];
    float g = G[(size_t)im*NT + j];
    float v = fmaxf(sqb[im] + sqj - 2.0f*g, 0.0f);
    float d = sqrtf(v) * 0.0625f;
    if (d < bestd){ bestd = d; bestm = m; }        // first-min tie rule within chunk
  }
  __shared__ float ld[4][64];
  __shared__ int lm[4][64];
  ld[mq][jl] = bestd; lm[mq][jl] = bestm;
  __syncthreads();
  if (mq == 0){
    for (int q = 1; q < 4; ++q){
      float d2 = ld[q][jl]; int m2 = lm[q][jl];
      if (d2 < bestd || (d2 == bestd && m2 < bestm)){ bestd = d2; bestm = m2; }
    }
    idx_cluster[b*NT + j] = bestm;
  }
}

__global__ __launch_bounds__(256) void override_kernel(const int* __restrict__ idx_down, int* __restrict__ idx_cluster, int b){
  int m = blockIdx.x * 256 + threadIdx.x;
  if (m < MC) idx_cluster[b*NT + idx_down[b*MC + m]] = m;
}

// ---- merge + outputs ----
__global__ __launch_bounds__(256) void allw_kernel(const int* __restrict__ idx_cluster, const float* __restrict__ wt,
                                                   float* __restrict__ allw){
  int lin = blockIdx.x * 256 + threadIdx.x;       // B*N
  int b = lin >> 12;
  atomicAdd(&allw[b*MC + idx_cluster[lin]], wt[lin]);
}
__global__ __launch_bounds__(256) void normw_kernel(const int* __restrict__ idx_cluster, const float* __restrict__ wt,
                                                    const float* __restrict__ allw, float* __restrict__ nw){
  int lin = blockIdx.x * 256 + threadIdx.x;
  int b = lin >> 12;
  nw[lin] = wt[lin] / (allw[b*MC + idx_cluster[lin]] + EPS_F);
}
__global__ __launch_bounds__(256) void xdown_kernel(const int* __restrict__ idx_cluster, const float* __restrict__ nw,
                                                    const float* __restrict__ xt, float* __restrict__ xdown){
  int bn = blockIdx.x;
  int d = threadIdx.x;
  int b = bn >> 12;
  int ic = idx_cluster[bn];
  float v = xt[(size_t)bn*DOUT + d] * nw[bn];
  atomicAdd(&xdown[((size_t)(b*MC + ic))*DOUT + d], v);
}
__global__ __launch_bounds__(256) void out0_kernel(const float* __restrict__ xdown, float* __restrict__ out){
  int lin = blockIdx.x * 256 + threadIdx.x;       // B*M*D
  out[lin] = xdown[lin];
}
// block-reduced max -> one atomic per block
__global__ __launch_bounds__(256) void out12a_kernel(const int* __restrict__ idx_agg, const int* __restrict__ idx_cluster,
                                                     const float* __restrict__ aggw, const float* __restrict__ nw,
                                                     float* __restrict__ awd, int* __restrict__ awdmax,
                                                     float* __restrict__ out1){
  __shared__ float red[4];
  int lin = blockIdx.x * 256 + threadIdx.x;       // B*N ; each block within one batch
  int b = lin >> 12;
  int ia = idx_agg[lin];
  int ic = idx_cluster[b*NT + ia];
  out1[lin] = (float)ic;
  float v = aggw[lin] * nw[b*NT + ia];
  awd[lin] = v;
  float wv = v;
#pragma unroll
  for (int m = 1; m < 64; m <<= 1) wv = fmaxf(wv, __shfl_xor(wv, m, 64));
  int lane = threadIdx.x & 63, wid = threadIdx.x >> 6;
  if (lane == 0) red[wid] = wv;
  __syncthreads();
  if (threadIdx.x == 0){
    float bm = fmaxf(fmaxf(red[0], red[1]), fmaxf(red[2], red[3]));
    atomicMax(&awdmax[b], __float_as_int(bm));    // nonneg
  }
}
__global__ __launch_bounds__(256) void out2_kernel(const float* __restrict__ awd, const int* __restrict__ awdmax,
                                                   float* __restrict__ out2){
  int lin = blockIdx.x * 256 + threadIdx.x;
  int b = lin >> 12;
  out2[lin] = awd[lin] / __int_as_float(awdmax[b]);
}

extern "C" void kernel_launch(void* const* d_in, const int* in_sizes, int n_in,
                              void* d_out, int out_size, void* d_ws, size_t ws_size,
                              hipStream_t stream) {
  const float* x      = (const float*)d_in[0];   // f32 (B,N,C)
  const float* loc    = (const float*)d_in[1];   // f32 (B,N,2)
  const int*   idxagg = (const int*)d_in[2];     // (B,N)
  const float* aggw   = (const float*)d_in[3];   // f32 (B,N,1)
  // d_in[4]=H, d_in[5]=W (hard-coded), d_in[6]=idx_k_loc unused
  const float* convw  = (const float*)d_in[7];   // f32 (256,128,3,3)
  const float* convb  = (const float*)d_in[8];
  const float* skipw  = (const float*)d_in[9];   // f32 (256,128)
  const float* lng    = (const float*)d_in[10];
  const float* lnb    = (const float*)d_in[11];
  const float* confw  = (const float*)d_in[12];
  const float* confb  = (const float*)d_in[13];

  char* ws = (char*)d_ws;
  float* w_xmap  = (float*)(ws + OFF_XMAP);
  float* w_cnt   = (float*)(ws + OFF_CNT);
  float* w_tot   = (float*)(ws + OFF_TOT);
  float* w_allw  = (float*)(ws + OFF_ALLW);
  float* w_xdown = (float*)(ws + OFF_XDOWN);
  int*   w_vmax  = (int*)  (ws + OFF_VMAX);
  int*   w_awdm  = (int*)  (ws + OFF_AWDM);
  float* w_ymap  = (float*)(ws + OFF_YMAP);
  float* w_xt    = (float*)(ws + OFF_XT);
  float* w_sq    = (float*)(ws + OFF_SQ);
  float* w_den   = (float*)(ws + OFF_DEN);
  float* w_score = (float*)(ws + OFF_SCORE);
  float* w_wt    = (float*)(ws + OFF_WT);
  float* w_nw    = (float*)(ws + OFF_NW);
  float* w_awd   = (float*)(ws + OFF_AWD);
  int*   w_idxd  = (int*)  (ws + OFF_IDXD);
  int*   w_idxc  = (int*)  (ws + OFF_IDXC);
  float* w_gram  = (float*)(ws + OFF_GRAM);

  float* out0 = (float*)d_out;
  float* out1 = out0 + NB*MC*DOUT;
  float* out2 = out1 + NB*NT;

  hipMemsetAsync(ws, 0, ZERO_BYTES, stream);

  t2m_scatter<<<NB*NT*CI/256, 256, 0, stream>>>(x, loc, idxagg, w_xmap, w_cnt);
  t2m_norm<<<NB*HWI*CI/256, 256, 0, stream>>>(w_xmap, w_cnt);
  conv_kernel<<<NB*32*4, 256, 0, stream>>>(w_xmap, convw, convb, w_ymap);
  tot_kernel<<<NB*NT/256, 256, 0, stream>>>(idxagg, aggw, w_tot);
  skip_kernel<<<NB*NT/8, 256, 0, stream>>>(x, skipw, w_xt);
  m2t_scatter<<<NB*NT, 256, 0, stream>>>(w_ymap, loc, idxagg, aggw, w_tot, w_xt);
  ln_kernel<<<NB*NT, 256, 0, stream>>>(w_xt, lng, lnb, confw, confb, w_sq, w_wt);

  for (int b = 0; b < NB; ++b){
    gram_kernel<<<528, 256, 0, stream>>>(w_xt + (size_t)b*NT*DOUT, w_gram);
    mirror_kernel<<<496*4, 256, 0, stream>>>(w_gram);
    density_kernel<<<NT, 256, 0, stream>>>(w_gram, w_sq, w_den, w_vmax, b);
    parent_kernel<<<NT, 256, 0, stream>>>(w_gram, w_sq, w_den, w_vmax, w_score, b);
    topk_sort<<<1, 1024, 0, stream>>>(w_score, w_idxd, b);
    assign_kernel<<<64, 256, 0, stream>>>(w_gram, w_sq, w_idxd, w_idxc, b);
    override_kernel<<<4, 256, 0, stream>>>(w_idxd, w_idxc, b);
  }

  allw_kernel<<<NB*NT/256, 256, 0, stream>>>(w_idxc, w_wt, w_allw);
  normw_kernel<<<NB*NT/256, 256, 0, stream>>>(w_idxc, w_wt, w_allw, w_nw);
  xdown_kernel<<<NB*NT, 256, 0, stream>>>(w_idxc, w_nw, w_xt, w_xdown);
  out0_kernel<<<NB*MC*DOUT/256, 256, 0, stream>>>(w_xdown, out0);
  out12a_kernel<<<NB*NT/256, 256, 0, stream>>>(idxagg, w_idxc, aggw, w_nw, w_awd, w_awdm, out1);
  out2_kernel<<<NB*NT/256, 256, 0, stream>>>(w_awd, w_awdm, out2);

  (void)in_sizes; (void)n_in; (void)out_size; (void)ws_size;
}

// Round 6
// 1372.876 us; speedup vs baseline: 1.2735x; 1.0567x over previous
//
#include <hip/hip_runtime.h>
#include <math.h>

// Fixed problem sizes: B=4, N=4096, C=128, DOUT=256, H=W=64 (conv out 32x32),
// M=1024 clusters, K=5 NN. Inputs f32; output buffer f32.
#define NB 4
#define NT 4096
#define CI 128
#define DOUT 256
#define HWI 4096
#define HWO 1024
#define MC 1024
#define EPS_F 1e-6f

// ---------------- workspace layout (bytes) ----------------
static const size_t OFF_XMAP  = 0;                          // 8388608
static const size_t OFF_CNT   = OFF_XMAP + 8388608;         // 65536
static const size_t OFF_TOT   = OFF_CNT  + 65536;           // 65536
static const size_t OFF_ALLW  = OFF_TOT  + 65536;           // 16384
static const size_t OFF_XDOWN = OFF_ALLW + 16384;           // 4194304
static const size_t OFF_VMAX  = OFF_XDOWN + 4194304;        // 256
static const size_t OFF_AWDM  = OFF_VMAX + 256;             // 256
static const size_t ZERO_BYTES= OFF_AWDM + 256;
// non-zeroed:
static const size_t OFF_YMAP  = ZERO_BYTES;                 // 4194304
static const size_t OFF_XT    = OFF_YMAP + 4194304;         // 16777216
static const size_t OFF_SQ    = OFF_XT + 16777216;          // 65536
static const size_t OFF_DEN   = OFF_SQ + 65536;             // 65536
static const size_t OFF_SCORE = OFF_DEN + 65536;            // 65536
static const size_t OFF_WT    = OFF_SCORE + 65536;          // 65536
static const size_t OFF_NW    = OFF_WT + 65536;             // 65536
static const size_t OFF_AWD   = OFF_NW + 65536;             // 65536
static const size_t OFF_IDXD  = OFF_AWD + 65536;            // 16384
static const size_t OFF_IDXC  = OFF_IDXD + 16384;           // 65536
static const size_t OFF_GRAM  = OFF_IDXC + 65536;           // 67108864
static const size_t OFF_WTR   = OFF_GRAM + 67108864;        // 1179648 (wT[1152][256])

// ---------------- helpers ----------------
__device__ __forceinline__ float waveSum(float v){
#pragma unroll
  for (int m = 1; m < 64; m <<= 1) v += __shfl_xor(v, m, 64);
  return v;
}
__device__ __forceinline__ float blockSum256(float v, float* red){
  v = waveSum(v);
  int lane = threadIdx.x & 63, wid = threadIdx.x >> 6;
  __syncthreads();
  if (lane == 0) red[wid] = v;
  __syncthreads();
  return red[0] + red[1] + red[2] + red[3];
}
__device__ __forceinline__ void merge5(float& a0, float& a1, float& a2, float& a3, float& a4,
                                       float b0, float b1, float b2, float b3, float b4){
  float l0=a0,l1=a1,l2=a2,l3=fminf(a3,b4),l4=fminf(a4,b3),l5=b2,l6=b1,l7=b0;
  float t0=fminf(l0,l4), t4=fmaxf(l0,l4);
  float t1=fminf(l1,l5), t5=fmaxf(l1,l5);
  float t2=fminf(l2,l6), t6=fmaxf(l2,l6);
  float t3=fminf(l3,l7), t7=fmaxf(l3,l7);
  float u0=fminf(t0,t2), u2=fmaxf(t0,t2);
  float u1=fminf(t1,t3), u3=fmaxf(t1,t3);
  float u4=fminf(t4,t6);
  float u5=fminf(t5,t7);
  a0=fminf(u0,u1); a1=fmaxf(u0,u1);
  a2=fminf(u2,u3); a3=fmaxf(u2,u3);
  a4=fminf(u4,u5);
}
__device__ __forceinline__ int grid_cell(float lx, float ly, int dim){
  lx = (fminf(fmaxf(lx, -1.f), 1.f) + 1.f) * 0.5f;
  ly = (fminf(fmaxf(ly, -1.f), 1.f) + 1.f) * 0.5f;
  float s = (float)(dim - 1);
  int col = (int)rintf(lx * s); col = min(max(col, 0), dim - 1);
  int row = (int)rintf(ly * s); row = min(max(row, 0), dim - 1);
  return row * dim + col;
}

// ---------------- stage kernels ----------------
__global__ __launch_bounds__(256) void t2m_scatter(const float* __restrict__ x,
                                                   const float* __restrict__ loc,
                                                   const int* __restrict__ idx_agg,
                                                   float* __restrict__ xmap, float* __restrict__ cnt){
  int lin = blockIdx.x * 256 + threadIdx.x;
  int c  = lin & 127;
  int bn = lin >> 7;
  int b  = bn >> 12;
  float lx = loc[(size_t)bn*2 + 0];
  float ly = loc[(size_t)bn*2 + 1];
  int cell = grid_cell(lx, ly, 64);
  int ia = idx_agg[bn];
  float val = x[((size_t)(b*NT + ia))*CI + c];
  atomicAdd(&xmap[((size_t)(b*HWI + cell))*CI + c], val);
  if (c == 0) atomicAdd(&cnt[b*HWI + cell], 1.0f);
}

__global__ __launch_bounds__(256) void t2m_norm(float* __restrict__ xmap, const float* __restrict__ cnt){
  int lin = blockIdx.x * 256 + threadIdx.x;
  xmap[lin] = xmap[lin] / (cnt[lin >> 7] + EPS_F);
}

// transpose conv weights: wT[k][d], k = c*9 + kh*3 + kw
__global__ __launch_bounds__(256) void wtrans_kernel(const float* __restrict__ cw, float* __restrict__ wT){
  int lin = blockIdx.x * 256 + threadIdx.x;   // 1152*256
  int k = lin >> 8, d = lin & 255;
  wT[lin] = cw[(size_t)d*1152 + k];
}

// conv as implicit GEMM: Y[n,d] = sum_k patch[n,k]*wT[k,d] + bias, n=(b,oh,ow),
// K=1152 ascending (c,kh,kw) -> bit-identical to direct conv's FMA chain.
// 64x64 tile, 256 threads (16x16), 4x4 acc, BK=16, prefetched staging.
__global__ __launch_bounds__(256) void conv_gemm(const float* __restrict__ xmap,
                                                 const float* __restrict__ wT,
                                                 const float* __restrict__ cb,
                                                 float* __restrict__ ymap){
  __shared__ float As[16][64];   // [k][n]
  __shared__ float Bs[16][64];   // [k][d]
  int n0 = blockIdx.y * 64, d0 = blockIdx.x * 64;
  int tid = threadIdx.x;
  int tx = tid & 15, ty = tid >> 4;
  // A-staging: thread owns n = n0 + ln, k-quad kg (4 consecutive k)
  int ln = tid & 63, kg = tid >> 6;          // kg 0..3
  int n = n0 + ln;
  int b = n >> 10, rem = n & 1023;
  int oh = rem >> 5, ow = rem & 31;
  const float* xb = xmap + (size_t)b * HWI * CI;
  // B-staging: thread loads one float4 of row bkr
  int bkr = tid >> 4;                        // 0..15
  int bc4 = (tid & 15) * 4;
  float pa[4]; float4 pbv;
  {
#pragma unroll
    for (int j = 0; j < 4; ++j){
      int k = kg*4 + j;
      int c = k / 9, r9 = k - c*9, kh = r9 / 3, kw = r9 - kh*3;
      int ih = oh*2 - 1 + kh, iw = ow*2 - 1 + kw;
      bool inb = (ih >= 0) && (ih < 64) && (iw >= 0) && (iw < 64);
      pa[j] = inb ? xb[(size_t)(ih*64 + iw)*CI + c] : 0.f;
    }
    pbv = *(const float4*)(wT + (size_t)bkr*256 + d0 + bc4);
  }
  float acc[4][4] = {{0}};
  for (int kt = 0; kt < 72; ++kt){
    __syncthreads();
#pragma unroll
    for (int j = 0; j < 4; ++j) As[kg*4 + j][ln] = pa[j];
    *(float4*)&Bs[bkr][bc4] = pbv;
    __syncthreads();
    if (kt < 71){
      int k2 = (kt + 1) * 16;
#pragma unroll
      for (int j = 0; j < 4; ++j){
        int k = k2 + kg*4 + j;
        int c = k / 9, r9 = k - c*9, kh = r9 / 3, kw = r9 - kh*3;
        int ih = oh*2 - 1 + kh, iw = ow*2 - 1 + kw;
        bool inb = (ih >= 0) && (ih < 64) && (iw >= 0) && (iw < 64);
        pa[j] = inb ? xb[(size_t)(ih*64 + iw)*CI + c] : 0.f;
      }
      pbv = *(const float4*)(wT + (size_t)(k2 + bkr)*256 + d0 + bc4);
    }
#pragma unroll
    for (int k = 0; k < 16; ++k){
      float ar[4], br[4];
      *(float4*)ar = *(const float4*)&As[k][ty*4];
      *(float4*)br = *(const float4*)&Bs[k][tx*4];
#pragma unroll
      for (int r = 0; r < 4; ++r)
#pragma unroll
        for (int s = 0; s < 4; ++s) acc[r][s] += ar[r]*br[s];
    }
  }
  float4 bias = *(const float4*)(cb + d0 + tx*4);
#pragma unroll
  for (int r = 0; r < 4; ++r){
    float4 o;
    o.x = acc[r][0] + bias.x; o.y = acc[r][1] + bias.y;
    o.z = acc[r][2] + bias.z; o.w = acc[r][3] + bias.w;
    *(float4*)(ymap + (size_t)(n0 + ty*4 + r)*DOUT + d0 + tx*4) = o;
  }
}

__global__ __launch_bounds__(256) void tot_kernel(const int* __restrict__ idx_agg,
                                                  const float* __restrict__ aggw,
                                                  float* __restrict__ tot){
  int lin = blockIdx.x * 256 + threadIdx.x;
  int b = lin >> 12;
  atomicAdd(&tot[b*NT + idx_agg[lin]], aggw[lin]);
}

__global__ __launch_bounds__(256) void skip_kernel(const float* __restrict__ x,
                                                   const float* __restrict__ sw,
                                                   float* __restrict__ xt){
  int rowbase = blockIdx.x * 8;
  int d = threadIdx.x;
  __shared__ float xr[8*128];
  ((float4*)xr)[d] = ((const float4*)(x + (size_t)rowbase*CI))[d];
  __syncthreads();
  float acc[8] = {0,0,0,0,0,0,0,0};
  const float* wd = sw + (size_t)d*CI;
  for (int c = 0; c < 128; ++c){
    float w = wd[c];
#pragma unroll
    for (int r = 0; r < 8; ++r) acc[r] += w * xr[r*128 + c];
  }
  for (int r = 0; r < 8; ++r) xt[(size_t)(rowbase + r)*DOUT + d] = acc[r];
}

__global__ __launch_bounds__(256) void m2t_scatter(const float* __restrict__ ymap,
                                                   const float* __restrict__ loc,
                                                   const int* __restrict__ idx_agg,
                                                   const float* __restrict__ aggw,
                                                   const float* __restrict__ tot,
                                                   float* __restrict__ xt){
  int bn = blockIdx.x;
  int d = threadIdx.x;
  int b = bn >> 12;
  float lx = loc[(size_t)bn*2 + 0];
  float ly = loc[(size_t)bn*2 + 1];
  int cell = grid_cell(lx, ly, 32);
  int ia = idx_agg[bn];
  float w = aggw[bn] / (tot[b*NT + ia] + EPS_F);
  float val = ymap[((size_t)(b*HWO + cell))*DOUT + d] * w;
  atomicAdd(&xt[((size_t)(b*NT + ia))*DOUT + d], val);
}

__global__ __launch_bounds__(256) void ln_kernel(float* __restrict__ xt,
                                                 const float* __restrict__ g,
                                                 const float* __restrict__ bta,
                                                 const float* __restrict__ cw,
                                                 const float* __restrict__ cb,
                                                 float* __restrict__ sq, float* __restrict__ wt){
  __shared__ float red[4];
  int row = blockIdx.x;
  int d = threadIdx.x;
  float v = xt[(size_t)row*DOUT + d];
  float mu = blockSum256(v, red) * (1.0f/256.0f);
  float xc = v - mu;
  float var = blockSum256(xc*xc, red) * (1.0f/256.0f);
  float rn = 1.0f / sqrtf(var + 1e-5f);
  float y = xc * rn * g[d] + bta[d];
  xt[(size_t)row*DOUT + d] = y;
  float s2 = blockSum256(y*y, red);
  float cf = blockSum256(y*cw[d], red);
  if (d == 0){ sq[row] = s2; wt[row] = expf(cf + cb[0]); }
}

// gram: lower-triangle 128-tiles only (528 blocks), 8x8 acc, BK=8.
__global__ __launch_bounds__(256) void gram_kernel(const float* __restrict__ A, float* __restrict__ G){
  __shared__ float As[8][128];
  __shared__ float Bs[8][128];
  int t = blockIdx.x;
  int ti = 0, accu = 0;
  while (accu + ti + 1 <= t){ accu += ti + 1; ++ti; }
  int tj = t - accu;
  int i0 = ti * 128, j0 = tj * 128;
  int tid = threadIdx.x;
  int lrow = tid >> 1;
  int lc4  = tid & 1;
  int ty = tid >> 4, tx = tid & 15;
  int r0 = ty * 8;
  int cA = tx * 4, cB = 64 + tx * 4;
  float acc[8][8] = {{0}};
  for (int kt = 0; kt < 256; kt += 8){
    float4 av = *(const float4*)(A + (size_t)(i0+lrow)*DOUT + kt + lc4*4);
    float4 bv = *(const float4*)(A + (size_t)(j0+lrow)*DOUT + kt + lc4*4);
    __syncthreads();
    As[lc4*4+0][lrow]=av.x; As[lc4*4+1][lrow]=av.y; As[lc4*4+2][lrow]=av.z; As[lc4*4+3][lrow]=av.w;
    Bs[lc4*4+0][lrow]=bv.x; Bs[lc4*4+1][lrow]=bv.y; Bs[lc4*4+2][lrow]=bv.z; Bs[lc4*4+3][lrow]=bv.w;
    __syncthreads();
#pragma unroll
    for (int k = 0; k < 8; ++k){
      float ar[8], br[8];
      *(float4*)&ar[0] = *(const float4*)&As[k][r0];
      *(float4*)&ar[4] = *(const float4*)&As[k][r0+4];
      *(float4*)&br[0] = *(const float4*)&Bs[k][cA];
      *(float4*)&br[4] = *(const float4*)&Bs[k][cB];
#pragma unroll
      for (int r = 0; r < 8; ++r)
#pragma unroll
        for (int s = 0; s < 8; ++s) acc[r][s] += ar[r]*br[s];
    }
  }
  for (int r = 0; r < 8; ++r){
    size_t row = (size_t)(i0 + r0 + r);
    *(float4*)(G + row*NT + j0 + cA) = *(float4*)&acc[r][0];
    *(float4*)(G + row*NT + j0 + cB) = *(float4*)&acc[r][4];
  }
}

__global__ __launch_bounds__(256) void mirror_kernel(float* __restrict__ G){
  __shared__ float tile[64*65];
  int blk = blockIdx.x;
  int q = blk & 3; int t = blk >> 2;
  int ti = 1, accu = 0;
  while (accu + ti <= t){ accu += ti; ++ti; }
  int tj = t - accu;
  int qa = q >> 1, qb = q & 1;
  int rs = ti*128 + qa*64, cs = tj*128 + qb*64;
  int rd = tj*128 + qb*64, cd = ti*128 + qa*64;
  int lane = threadIdx.x & 63, w = threadIdx.x >> 6;
  for (int i = 0; i < 16; ++i){
    int r = w*16 + i;
    tile[r*65 + lane] = G[(size_t)(rs + r)*NT + cs + lane];
  }
  __syncthreads();
  for (int i = 0; i < 16; ++i){
    int r = w*16 + i;
    G[(size_t)(rd + r)*NT + cd + lane] = tile[lane*65 + r];
  }
}

__global__ __launch_bounds__(256) void density_kernel(const float* __restrict__ G, const float* __restrict__ sq,
                                                      float* __restrict__ density, int* __restrict__ vmax, int b){
  int i = blockIdx.x;
  int tid = threadIdx.x;
  const float* sqb = sq + b*NT;
  float sqi = sqb[i];
  const float* row = G + (size_t)i*NT;
  float t0=INFINITY,t1=INFINITY,t2=INFINITY,t3=INFINITY,t4=INFINITY;
  float vmx = 0.f;
  for (int j = tid; j < NT; j += 256){
    float v = fmaxf(sqi + sqb[j] - 2.0f*row[j], 0.0f);
    vmx = fmaxf(vmx, v);
    t4 = fminf(t4, v);
    float a;
    a = fminf(t3,t4); t4 = fmaxf(t3,t4); t3 = a;
    a = fminf(t2,t3); t3 = fmaxf(t2,t3); t2 = a;
    a = fminf(t1,t2); t2 = fmaxf(t1,t2); t1 = a;
    a = fminf(t0,t1); t1 = fmaxf(t0,t1); t0 = a;
  }
#pragma unroll
  for (int m = 1; m < 64; m <<= 1){
    float b0=__shfl_xor(t0,m,64), b1=__shfl_xor(t1,m,64), b2=__shfl_xor(t2,m,64),
          b3=__shfl_xor(t3,m,64), b4=__shfl_xor(t4,m,64);
    merge5(t0,t1,t2,t3,t4,b0,b1,b2,b3,b4);
    vmx = fmaxf(vmx, __shfl_xor(vmx,m,64));
  }
  __shared__ float w5[4][5];
  __shared__ float wm[4];
  int lane = tid & 63, wid = tid >> 6;
  if (lane == 0){ w5[wid][0]=t0; w5[wid][1]=t1; w5[wid][2]=t2; w5[wid][3]=t3; w5[wid][4]=t4; wm[wid]=vmx; }
  __syncthreads();
  if (tid == 0){
    float a0=w5[0][0],a1=w5[0][1],a2=w5[0][2],a3=w5[0][3],a4=w5[0][4];
    for (int w = 1; w < 4; ++w) merge5(a0,a1,a2,a3,a4, w5[w][0],w5[w][1],w5[w][2],w5[w][3],w5[w][4]);
    float d0=sqrtf(a0)*0.0625f, d1=sqrtf(a1)*0.0625f, d2=sqrtf(a2)*0.0625f,
          d3=sqrtf(a3)*0.0625f, d4=sqrtf(a4)*0.0625f;
    float s = d0*d0; s += d1*d1; s += d2*d2; s += d3*d3; s += d4*d4;
    density[b*NT + i] = expf(-(s / 5.0f));
    float vm = fmaxf(fmaxf(wm[0],wm[1]), fmaxf(wm[2],wm[3]));
    atomicMax(vmax + b, __float_as_int(vm));
  }
}

__global__ __launch_bounds__(256) void parent_kernel(const float* __restrict__ G, const float* __restrict__ sq,
                                                     const float* __restrict__ density, const int* __restrict__ vmax,
                                                     float* __restrict__ score, int b){
  int i = blockIdx.x;
  int tid = threadIdx.x;
  const float* sqb = sq + b*NT;
  const float* den = density + b*NT;
  float sqi = sqb[i];
  float di = den[i];
  const float* row = G + (size_t)i*NT;
  float minv = INFINITY;
  for (int j = tid; j < NT; j += 256){
    float v = fmaxf(sqi + sqb[j] - 2.0f*row[j], 0.0f);
    minv = fminf(minv, (den[j] > di) ? v : INFINITY);
  }
#pragma unroll
  for (int m = 1; m < 64; m <<= 1) minv = fminf(minv, __shfl_xor(minv,m,64));
  __shared__ float wmn[4];
  int lane = tid & 63, wid = tid >> 6;
  if (lane == 0) wmn[wid] = minv;
  __syncthreads();
  if (tid == 0){
    float mv = fminf(fminf(wmn[0],wmn[1]), fminf(wmn[2],wmn[3]));
    float dmax = sqrtf(__int_as_float(vmax[b])) * 0.0625f;
    float dp = isinf(mv) ? dmax : sqrtf(mv) * 0.0625f;
    score[b*NT + i] = dp * di;
  }
}

__global__ __launch_bounds__(1024) void topk_sort(const float* __restrict__ score, int* __restrict__ idx_down, int b){
  __shared__ float ss[4096];
  __shared__ int ii[4096];
  int tid = threadIdx.x;
  for (int t = tid; t < 4096; t += 1024){ ss[t] = score[b*NT + t]; ii[t] = t; }
  for (int k = 2; k <= 4096; k <<= 1){
    for (int j = k >> 1; j > 0; j >>= 1){
      __syncthreads();
      for (int t = tid; t < 4096; t += 1024){
        int p = t ^ j;
        if (p > t){
          float s1 = ss[t], s2 = ss[p];
          int i1 = ii[t], i2 = ii[p];
          bool lt = (s1 > s2) || (s1 == s2 && i1 < i2);
          bool up = ((t & k) == 0);
          if (up ? !lt : lt){ ss[t]=s2; ss[p]=s1; ii[t]=i2; ii[p]=i1; }
        }
      }
    }
  }
  __syncthreads();
  if (tid < MC) idx_down[b*MC + tid] = ii[tid];
}

__global__ __launch_bounds__(256) void assign_kernel(const float* __restrict__ G, const float* __restrict__ sq,
                                                     const int* __restrict__ idx_down, int* __restrict__ idx_cluster, int b){
  int jl = threadIdx.x & 63, mq = threadIdx.x >> 6;
  int j = blockIdx.x * 64 + jl;
  const float* sqb = sq + b*NT;
  float sqj = sqb[j];
  const int* idb = idx_down + b*MC;
  float bestd = INFINITY; int bestm = 0x7fffffff;
  for (int m = mq*256; m < mq*256 + 256; ++m){
    int im = idb[m];
    float g = G[(size_t)im*NT + j];
    float v = fmaxf(sqb[im] + sqj - 2.0f*g, 0.0f);
    float d = sqrtf(v) * 0.0625f;
    if (d < bestd){ bestd = d; bestm = m; }
  }
  __shared__ float ld[4][64];
  __shared__ int lm[4][64];
  ld[mq][jl] = bestd; lm[mq][jl] = bestm;
  __syncthreads();
  if (mq == 0){
    for (int q = 1; q < 4; ++q){
      float d2 = ld[q][jl]; int m2 = lm[q][jl];
      if (d2 < bestd || (d2 == bestd && m2 < bestm)){ bestd = d2; bestm = m2; }
    }
    idx_cluster[b*NT + j] = bestm;
  }
}

__global__ __launch_bounds__(256) void override_kernel(const int* __restrict__ idx_down, int* __restrict__ idx_cluster, int b){
  int m = blockIdx.x * 256 + threadIdx.x;
  if (m < MC) idx_cluster[b*NT + idx_down[b*MC + m]] = m;
}

__global__ __launch_bounds__(256) void allw_kernel(const int* __restrict__ idx_cluster, const float* __restrict__ wt,
                                                   float* __restrict__ allw){
  int lin = blockIdx.x * 256 + threadIdx.x;
  int b = lin >> 12;
  atomicAdd(&allw[b*MC + idx_cluster[lin]], wt[lin]);
}
__global__ __launch_bounds__(256) void normw_kernel(const int* __restrict__ idx_cluster, const float* __restrict__ wt,
                                                    const float* __restrict__ allw, float* __restrict__ nw){
  int lin = blockIdx.x * 256 + threadIdx.x;
  int b = lin >> 12;
  nw[lin] = wt[lin] / (allw[b*MC + idx_cluster[lin]] + EPS_F);
}
__global__ __launch_bounds__(256) void xdown_kernel(const int* __restrict__ idx_cluster, const float* __restrict__ nw,
                                                    const float* __restrict__ xt, float* __restrict__ xdown){
  int bn = blockIdx.x;
  int d = threadIdx.x;
  int b = bn >> 12;
  int ic = idx_cluster[bn];
  float v = xt[(size_t)bn*DOUT + d] * nw[bn];
  atomicAdd(&xdown[((size_t)(b*MC + ic))*DOUT + d], v);
}
__global__ __launch_bounds__(256) void out0_kernel(const float* __restrict__ xdown, float* __restrict__ out){
  int lin = blockIdx.x * 256 + threadIdx.x;
  out[lin] = xdown[lin];
}
__global__ __launch_bounds__(256) void out12a_kernel(const int* __restrict__ idx_agg, const int* __restrict__ idx_cluster,
                                                     const float* __restrict__ aggw, const float* __restrict__ nw,
                                                     float* __restrict__ awd, int* __restrict__ awdmax,
                                                     float* __restrict__ out1){
  __shared__ float red[4];
  int lin = blockIdx.x * 256 + threadIdx.x;
  int b = lin >> 12;
  int ia = idx_agg[lin];
  int ic = idx_cluster[b*NT + ia];
  out1[lin] = (float)ic;
  float v = aggw[lin] * nw[b*NT + ia];
  awd[lin] = v;
  float wv = v;
#pragma unroll
  for (int m = 1; m < 64; m <<= 1) wv = fmaxf(wv, __shfl_xor(wv, m, 64));
  int lane = threadIdx.x & 63, wid = threadIdx.x >> 6;
  if (lane == 0) red[wid] = wv;
  __syncthreads();
  if (threadIdx.x == 0){
    float bm = fmaxf(fmaxf(red[0], red[1]), fmaxf(red[2], red[3]));
    atomicMax(&awdmax[b], __float_as_int(bm));
  }
}
__global__ __launch_bounds__(256) void out2_kernel(const float* __restrict__ awd, const int* __restrict__ awdmax,
                                                   float* __restrict__ out2){
  int lin = blockIdx.x * 256 + threadIdx.x;
  int b = lin >> 12;
  out2[lin] = awd[lin] / __int_as_float(awdmax[b]);
}

extern "C" void kernel_launch(void* const* d_in, const int* in_sizes, int n_in,
                              void* d_out, int out_size, void* d_ws, size_t ws_size,
                              hipStream_t stream) {
  const float* x      = (const float*)d_in[0];
  const float* loc    = (const float*)d_in[1];
  const int*   idxagg = (const int*)d_in[2];
  const float* aggw   = (const float*)d_in[3];
  const float* convw  = (const float*)d_in[7];
  const float* convb  = (const float*)d_in[8];
  const float* skipw  = (const float*)d_in[9];
  const float* lng    = (const float*)d_in[10];
  const float* lnb    = (const float*)d_in[11];
  const float* confw  = (const float*)d_in[12];
  const float* confb  = (const float*)d_in[13];

  char* ws = (char*)d_ws;
  float* w_xmap  = (float*)(ws + OFF_XMAP);
  float* w_cnt   = (float*)(ws + OFF_CNT);
  float* w_tot   = (float*)(ws + OFF_TOT);
  float* w_allw  = (float*)(ws + OFF_ALLW);
  float* w_xdown = (float*)(ws + OFF_XDOWN);
  int*   w_vmax  = (int*)  (ws + OFF_VMAX);
  int*   w_awdm  = (int*)  (ws + OFF_AWDM);
  float* w_ymap  = (float*)(ws + OFF_YMAP);
  float* w_xt    = (float*)(ws + OFF_XT);
  float* w_sq    = (float*)(ws + OFF_SQ);
  float* w_den   = (float*)(ws + OFF_DEN);
  float* w_score = (float*)(ws + OFF_SCORE);
  float* w_wt    = (float*)(ws + OFF_WT);
  float* w_nw    = (float*)(ws + OFF_NW);
  float* w_awd   = (float*)(ws + OFF_AWD);
  int*   w_idxd  = (int*)  (ws + OFF_IDXD);
  int*   w_idxc  = (int*)  (ws + OFF_IDXC);
  float* w_gram  = (float*)(ws + OFF_GRAM);
  float* w_wtr   = (float*)(ws + OFF_WTR);

  float* out0 = (float*)d_out;
  float* out1 = out0 + NB*MC*DOUT;
  float* out2 = out1 + NB*NT;

  hipMemsetAsync(ws, 0, ZERO_BYTES, stream);

  t2m_scatter<<<NB*NT*CI/256, 256, 0, stream>>>(x, loc, idxagg, w_xmap, w_cnt);
  t2m_norm<<<NB*HWI*CI/256, 256, 0, stream>>>(w_xmap, w_cnt);
  wtrans_kernel<<<1152, 256, 0, stream>>>(convw, w_wtr);
  conv_gemm<<<dim3(4, 64), 256, 0, stream>>>(w_xmap, w_wtr, convb, w_ymap);
  tot_kernel<<<NB*NT/256, 256, 0, stream>>>(idxagg, aggw, w_tot);
  skip_kernel<<<NB*NT/8, 256, 0, stream>>>(x, skipw, w_xt);
  m2t_scatter<<<NB*NT, 256, 0, stream>>>(w_ymap, loc, idxagg, aggw, w_tot, w_xt);
  ln_kernel<<<NB*NT, 256, 0, stream>>>(w_xt, lng, lnb, confw, confb, w_sq, w_wt);

  for (int b = 0; b < NB; ++b){
    gram_kernel<<<528, 256, 0, stream>>>(w_xt + (size_t)b*NT*DOUT, w_gram);
    mirror_kernel<<<496*4, 256, 0, stream>>>(w_gram);
    density_kernel<<<NT, 256, 0, stream>>>(w_gram, w_sq, w_den, w_vmax, b);
    parent_kernel<<<NT, 256, 0, stream>>>(w_gram, w_sq, w_den, w_vmax, w_score, b);
    topk_sort<<<1, 1024, 0, stream>>>(w_score, w_idxd, b);
    assign_kernel<<<64, 256, 0, stream>>>(w_gram, w_sq, w_idxd, w_idxc, b);
    override_kernel<<<4, 256, 0, stream>>>(w_idxd, w_idxc, b);
  }

  allw_kernel<<<NB*NT/256, 256, 0, stream>>>(w_idxc, w_wt, w_allw);
  normw_kernel<<<NB*NT/256, 256, 0, stream>>>(w_idxc, w_wt, w_allw, w_nw);
  xdown_kernel<<<NB*NT, 256, 0, stream>>>(w_idxc, w_nw, w_xt, w_xdown);
  out0_kernel<<<NB*MC*DOUT/256, 256, 0, stream>>>(w_xdown, out0);
  out12a_kernel<<<NB*NT/256, 256, 0, stream>>>(idxagg, w_idxc, aggw, w_nw, w_awd, w_awdm, out1);
  out2_kernel<<<NB*NT/256, 256, 0, stream>>>(w_awd, w_awdm, out2);

  (void)in_sizes; (void)n_in; (void)out_size; (void)ws_size;
}

// Round 7
// 1345.082 us; speedup vs baseline: 1.2999x; 1.0207x over previous
//
#include <hip/hip_runtime.h>
#include <math.h>

// Fixed problem sizes: B=4, N=4096, C=128, DOUT=256, H=W=64 (conv out 32x32),
// M=1024 clusters, K=5 NN. Inputs f32; output buffer f32.
#define NB 4
#define NT 4096
#define CI 128
#define DOUT 256
#define HWI 4096
#define HWO 1024
#define MC 1024
#define EPS_F 1e-6f

// ---------------- workspace layout (bytes) ----------------
static const size_t OFF_XMAP  = 0;                          // 8388608
static const size_t OFF_CNT   = OFF_XMAP + 8388608;         // 65536
static const size_t OFF_TOT   = OFF_CNT  + 65536;           // 65536
static const size_t OFF_ALLW  = OFF_TOT  + 65536;           // 16384
static const size_t OFF_XDOWN = OFF_ALLW + 16384;           // 4194304
static const size_t OFF_VMAX  = OFF_XDOWN + 4194304;        // 256
static const size_t OFF_AWDM  = OFF_VMAX + 256;             // 256
static const size_t ZERO_BYTES= OFF_AWDM + 256;
// non-zeroed:
static const size_t OFF_YMAP  = ZERO_BYTES;                 // 4194304
static const size_t OFF_XT    = OFF_YMAP + 4194304;         // 16777216
static const size_t OFF_SQ    = OFF_XT + 16777216;          // 65536
static const size_t OFF_DEN   = OFF_SQ + 65536;             // 65536
static const size_t OFF_SCORE = OFF_DEN + 65536;            // 65536
static const size_t OFF_WT    = OFF_SCORE + 65536;          // 65536
static const size_t OFF_NW    = OFF_WT + 65536;             // 65536
static const size_t OFF_AWD   = OFF_NW + 65536;             // 65536
static const size_t OFF_IDXD  = OFF_AWD + 65536;            // 16384
static const size_t OFF_IDXC  = OFF_IDXD + 16384;           // 65536
static const size_t OFF_GRAM  = OFF_IDXC + 65536;           // 67108864
static const size_t OFF_WTR   = OFF_GRAM + 67108864;        // 1179648 (wT[1152][256])
static const size_t OFF_P     = OFF_WTR + 1179648;          // 18874368 (P[4096][1152])

// ---------------- helpers ----------------
__device__ __forceinline__ float waveSum(float v){
#pragma unroll
  for (int m = 1; m < 64; m <<= 1) v += __shfl_xor(v, m, 64);
  return v;
}
__device__ __forceinline__ float blockSum256(float v, float* red){
  v = waveSum(v);
  int lane = threadIdx.x & 63, wid = threadIdx.x >> 6;
  __syncthreads();
  if (lane == 0) red[wid] = v;
  __syncthreads();
  return red[0] + red[1] + red[2] + red[3];
}
__device__ __forceinline__ void merge5(float& a0, float& a1, float& a2, float& a3, float& a4,
                                       float b0, float b1, float b2, float b3, float b4){
  float l0=a0,l1=a1,l2=a2,l3=fminf(a3,b4),l4=fminf(a4,b3),l5=b2,l6=b1,l7=b0;
  float t0=fminf(l0,l4), t4=fmaxf(l0,l4);
  float t1=fminf(l1,l5), t5=fmaxf(l1,l5);
  float t2=fminf(l2,l6), t6=fmaxf(l2,l6);
  float t3=fminf(l3,l7), t7=fmaxf(l3,l7);
  float u0=fminf(t0,t2), u2=fmaxf(t0,t2);
  float u1=fminf(t1,t3), u3=fmaxf(t1,t3);
  float u4=fminf(t4,t6);
  float u5=fminf(t5,t7);
  a0=fminf(u0,u1); a1=fmaxf(u0,u1);
  a2=fminf(u2,u3); a3=fmaxf(u2,u3);
  a4=fminf(u4,u5);
}
__device__ __forceinline__ int grid_cell(float lx, float ly, int dim){
  lx = (fminf(fmaxf(lx, -1.f), 1.f) + 1.f) * 0.5f;
  ly = (fminf(fmaxf(ly, -1.f), 1.f) + 1.f) * 0.5f;
  float s = (float)(dim - 1);
  int col = (int)rintf(lx * s); col = min(max(col, 0), dim - 1);
  int row = (int)rintf(ly * s); row = min(max(row, 0), dim - 1);
  return row * dim + col;
}

// ---------------- stage kernels ----------------
__global__ __launch_bounds__(256) void t2m_scatter(const float* __restrict__ x,
                                                   const float* __restrict__ loc,
                                                   const int* __restrict__ idx_agg,
                                                   float* __restrict__ xmap, float* __restrict__ cnt){
  int lin = blockIdx.x * 256 + threadIdx.x;
  int c  = lin & 127;
  int bn = lin >> 7;
  int b  = bn >> 12;
  float lx = loc[(size_t)bn*2 + 0];
  float ly = loc[(size_t)bn*2 + 1];
  int cell = grid_cell(lx, ly, 64);
  int ia = idx_agg[bn];
  float val = x[((size_t)(b*NT + ia))*CI + c];
  atomicAdd(&xmap[((size_t)(b*HWI + cell))*CI + c], val);
  if (c == 0) atomicAdd(&cnt[b*HWI + cell], 1.0f);
}

__global__ __launch_bounds__(256) void t2m_norm(float* __restrict__ xmap, const float* __restrict__ cnt){
  int lin = blockIdx.x * 256 + threadIdx.x;
  xmap[lin] = xmap[lin] / (cnt[lin >> 7] + EPS_F);
}

// transpose conv weights: wT[k][d], k = c*9 + kh*3 + kw
__global__ __launch_bounds__(256) void wtrans_kernel(const float* __restrict__ cw, float* __restrict__ wT){
  int lin = blockIdx.x * 256 + threadIdx.x;   // 1152*256
  int k = lin >> 8, d = lin & 255;
  wT[lin] = cw[(size_t)d*1152 + k];
}

// im2col: P[n][k], n=(b,oh,ow), k=c*9+kh*3+kw. Coalesced xmap reads (lanes on c).
__global__ __launch_bounds__(256) void im2col_kernel(const float* __restrict__ xmap, float* __restrict__ P){
  int tid = threadIdx.x;
  int c = tid & 127, n2 = tid >> 7;
  int n = blockIdx.x * 2 + n2;
  int b = n >> 10, rem = n & 1023;
  int oh = rem >> 5, ow = rem & 31;
  const float* xb = xmap + (size_t)b*HWI*CI;
  float* prow = P + (size_t)n*1152 + c*9;
#pragma unroll
  for (int kh = 0; kh < 3; ++kh){
    int ih = oh*2 - 1 + kh;
#pragma unroll
    for (int kw = 0; kw < 3; ++kw){
      int iw = ow*2 - 1 + kw;
      bool inb = (ih >= 0) && (ih < 64) && (iw >= 0) && (iw < 64);
      prow[kh*3 + kw] = inb ? xb[(size_t)(ih*64 + iw)*CI + c] : 0.f;
    }
  }
}

// conv as pure GEMM on P: Y[n,d] = sum_k P[n,k]*wT[k,d] + bias.
// K ascending -> bit-identical to direct conv. 64x64 tile, BK=16, prefetch.
__global__ __launch_bounds__(256) void conv_gemm(const float* __restrict__ P,
                                                 const float* __restrict__ wT,
                                                 const float* __restrict__ cb,
                                                 float* __restrict__ ymap){
  __shared__ float As[16][64];   // [k][n]
  __shared__ float Bs[16][64];   // [k][d]
  int n0 = blockIdx.y * 64, d0 = blockIdx.x * 64;
  int tid = threadIdx.x;
  int tx = tid & 15, ty = tid >> 4;
  int ln = tid & 63, kq = tid >> 6;          // A: n=ln, float4 at k=kt*16+kq*4
  int bkr = tid >> 4, bc4 = (tid & 15) * 4;  // B: k-row bkr, d-cols bc4
  float4 pav = *(const float4*)(P + (size_t)(n0+ln)*1152 + kq*4);
  float4 pbv = *(const float4*)(wT + (size_t)bkr*256 + d0 + bc4);
  float acc[4][4] = {{0}};
  for (int kt = 0; kt < 72; ++kt){
    __syncthreads();
    As[kq*4+0][ln]=pav.x; As[kq*4+1][ln]=pav.y; As[kq*4+2][ln]=pav.z; As[kq*4+3][ln]=pav.w;
    *(float4*)&Bs[bkr][bc4] = pbv;
    __syncthreads();
    if (kt < 71){
      int k2 = (kt + 1) * 16;
      pav = *(const float4*)(P + (size_t)(n0+ln)*1152 + k2 + kq*4);
      pbv = *(const float4*)(wT + (size_t)(k2 + bkr)*256 + d0 + bc4);
    }
#pragma unroll
    for (int k = 0; k < 16; ++k){
      float ar[4], br[4];
      *(float4*)ar = *(const float4*)&As[k][ty*4];
      *(float4*)br = *(const float4*)&Bs[k][tx*4];
#pragma unroll
      for (int r = 0; r < 4; ++r)
#pragma unroll
        for (int s = 0; s < 4; ++s) acc[r][s] += ar[r]*br[s];
    }
  }
  float4 bias = *(const float4*)(cb + d0 + tx*4);
#pragma unroll
  for (int r = 0; r < 4; ++r){
    float4 o;
    o.x = acc[r][0] + bias.x; o.y = acc[r][1] + bias.y;
    o.z = acc[r][2] + bias.z; o.w = acc[r][3] + bias.w;
    *(float4*)(ymap + (size_t)(n0 + ty*4 + r)*DOUT + d0 + tx*4) = o;
  }
}

__global__ __launch_bounds__(256) void tot_kernel(const int* __restrict__ idx_agg,
                                                  const float* __restrict__ aggw,
                                                  float* __restrict__ tot){
  int lin = blockIdx.x * 256 + threadIdx.x;
  int b = lin >> 12;
  atomicAdd(&tot[b*NT + idx_agg[lin]], aggw[lin]);
}

__global__ __launch_bounds__(256) void skip_kernel(const float* __restrict__ x,
                                                   const float* __restrict__ sw,
                                                   float* __restrict__ xt){
  int rowbase = blockIdx.x * 8;
  int d = threadIdx.x;
  __shared__ float xr[8*128];
  ((float4*)xr)[d] = ((const float4*)(x + (size_t)rowbase*CI))[d];
  __syncthreads();
  float acc[8] = {0,0,0,0,0,0,0,0};
  const float* wd = sw + (size_t)d*CI;
  for (int c = 0; c < 128; ++c){
    float w = wd[c];
#pragma unroll
    for (int r = 0; r < 8; ++r) acc[r] += w * xr[r*128 + c];
  }
  for (int r = 0; r < 8; ++r) xt[(size_t)(rowbase + r)*DOUT + d] = acc[r];
}

__global__ __launch_bounds__(256) void m2t_scatter(const float* __restrict__ ymap,
                                                   const float* __restrict__ loc,
                                                   const int* __restrict__ idx_agg,
                                                   const float* __restrict__ aggw,
                                                   const float* __restrict__ tot,
                                                   float* __restrict__ xt){
  int bn = blockIdx.x;
  int d = threadIdx.x;
  int b = bn >> 12;
  float lx = loc[(size_t)bn*2 + 0];
  float ly = loc[(size_t)bn*2 + 1];
  int cell = grid_cell(lx, ly, 32);
  int ia = idx_agg[bn];
  float w = aggw[bn] / (tot[b*NT + ia] + EPS_F);
  float val = ymap[((size_t)(b*HWO + cell))*DOUT + d] * w;
  atomicAdd(&xt[((size_t)(b*NT + ia))*DOUT + d], val);
}

__global__ __launch_bounds__(256) void ln_kernel(float* __restrict__ xt,
                                                 const float* __restrict__ g,
                                                 const float* __restrict__ bta,
                                                 const float* __restrict__ cw,
                                                 const float* __restrict__ cb,
                                                 float* __restrict__ sq, float* __restrict__ wt){
  __shared__ float red[4];
  int row = blockIdx.x;
  int d = threadIdx.x;
  float v = xt[(size_t)row*DOUT + d];
  float mu = blockSum256(v, red) * (1.0f/256.0f);
  float xc = v - mu;
  float var = blockSum256(xc*xc, red) * (1.0f/256.0f);
  float rn = 1.0f / sqrtf(var + 1e-5f);
  float y = xc * rn * g[d] + bta[d];
  xt[(size_t)row*DOUT + d] = y;
  float s2 = blockSum256(y*y, red);
  float cf = blockSum256(y*cw[d], red);
  if (d == 0){ sq[row] = s2; wt[row] = expf(cf + cb[0]); }
}

// gram: lower-triangle 128-tiles only (528 blocks), 8x8 acc, BK=8, prefetched.
__global__ __launch_bounds__(256) void gram_kernel(const float* __restrict__ A, float* __restrict__ G){
  __shared__ float As[8][128];
  __shared__ float Bs[8][128];
  int t = blockIdx.x;
  int ti = 0, accu = 0;
  while (accu + ti + 1 <= t){ accu += ti + 1; ++ti; }
  int tj = t - accu;
  int i0 = ti * 128, j0 = tj * 128;
  int tid = threadIdx.x;
  int lrow = tid >> 1;
  int lc4  = tid & 1;
  int ty = tid >> 4, tx = tid & 15;
  int r0 = ty * 8;
  int cA = tx * 4, cB = 64 + tx * 4;
  float4 av = *(const float4*)(A + (size_t)(i0+lrow)*DOUT + lc4*4);
  float4 bv = *(const float4*)(A + (size_t)(j0+lrow)*DOUT + lc4*4);
  float acc[8][8] = {{0}};
  for (int kt = 0; kt < 256; kt += 8){
    __syncthreads();
    As[lc4*4+0][lrow]=av.x; As[lc4*4+1][lrow]=av.y; As[lc4*4+2][lrow]=av.z; As[lc4*4+3][lrow]=av.w;
    Bs[lc4*4+0][lrow]=bv.x; Bs[lc4*4+1][lrow]=bv.y; Bs[lc4*4+2][lrow]=bv.z; Bs[lc4*4+3][lrow]=bv.w;
    __syncthreads();
    if (kt < 248){
      av = *(const float4*)(A + (size_t)(i0+lrow)*DOUT + kt + 8 + lc4*4);
      bv = *(const float4*)(A + (size_t)(j0+lrow)*DOUT + kt + 8 + lc4*4);
    }
#pragma unroll
    for (int k = 0; k < 8; ++k){
      float ar[8], br[8];
      *(float4*)&ar[0] = *(const float4*)&As[k][r0];
      *(float4*)&ar[4] = *(const float4*)&As[k][r0+4];
      *(float4*)&br[0] = *(const float4*)&Bs[k][cA];
      *(float4*)&br[4] = *(const float4*)&Bs[k][cB];
#pragma unroll
      for (int r = 0; r < 8; ++r)
#pragma unroll
        for (int s = 0; s < 8; ++s) acc[r][s] += ar[r]*br[s];
    }
  }
  for (int r = 0; r < 8; ++r){
    size_t row = (size_t)(i0 + r0 + r);
    *(float4*)(G + row*NT + j0 + cA) = *(float4*)&acc[r][0];
    *(float4*)(G + row*NT + j0 + cB) = *(float4*)&acc[r][4];
  }
}

__global__ __launch_bounds__(256) void mirror_kernel(float* __restrict__ G){
  __shared__ float tile[64*65];
  int blk = blockIdx.x;
  int q = blk & 3; int t = blk >> 2;
  int ti = 1, accu = 0;
  while (accu + ti <= t){ accu += ti; ++ti; }
  int tj = t - accu;
  int qa = q >> 1, qb = q & 1;
  int rs = ti*128 + qa*64, cs = tj*128 + qb*64;
  int rd = tj*128 + qb*64, cd = ti*128 + qa*64;
  int lane = threadIdx.x & 63, w = threadIdx.x >> 6;
  for (int i = 0; i < 16; ++i){
    int r = w*16 + i;
    tile[r*65 + lane] = G[(size_t)(rs + r)*NT + cs + lane];
  }
  __syncthreads();
  for (int i = 0; i < 16; ++i){
    int r = w*16 + i;
    G[(size_t)(rd + r)*NT + cd + lane] = tile[lane*65 + r];
  }
}

__global__ __launch_bounds__(256) void density_kernel(const float* __restrict__ G, const float* __restrict__ sq,
                                                      float* __restrict__ density, int* __restrict__ vmax, int b){
  int i = blockIdx.x;
  int tid = threadIdx.x;
  const float* sqb = sq + b*NT;
  float sqi = sqb[i];
  const float* row = G + (size_t)i*NT;
  float t0=INFINITY,t1=INFINITY,t2=INFINITY,t3=INFINITY,t4=INFINITY;
  float vmx = 0.f;
  for (int j = tid; j < NT; j += 256){
    float v = fmaxf(sqi + sqb[j] - 2.0f*row[j], 0.0f);
    vmx = fmaxf(vmx, v);
    t4 = fminf(t4, v);
    float a;
    a = fminf(t3,t4); t4 = fmaxf(t3,t4); t3 = a;
    a = fminf(t2,t3); t3 = fmaxf(t2,t3); t2 = a;
    a = fminf(t1,t2); t2 = fmaxf(t1,t2); t1 = a;
    a = fminf(t0,t1); t1 = fmaxf(t0,t1); t0 = a;
  }
#pragma unroll
  for (int m = 1; m < 64; m <<= 1){
    float b0=__shfl_xor(t0,m,64), b1=__shfl_xor(t1,m,64), b2=__shfl_xor(t2,m,64),
          b3=__shfl_xor(t3,m,64), b4=__shfl_xor(t4,m,64);
    merge5(t0,t1,t2,t3,t4,b0,b1,b2,b3,b4);
    vmx = fmaxf(vmx, __shfl_xor(vmx,m,64));
  }
  __shared__ float w5[4][5];
  __shared__ float wm[4];
  int lane = tid & 63, wid = tid >> 6;
  if (lane == 0){ w5[wid][0]=t0; w5[wid][1]=t1; w5[wid][2]=t2; w5[wid][3]=t3; w5[wid][4]=t4; wm[wid]=vmx; }
  __syncthreads();
  if (tid == 0){
    float a0=w5[0][0],a1=w5[0][1],a2=w5[0][2],a3=w5[0][3],a4=w5[0][4];
    for (int w = 1; w < 4; ++w) merge5(a0,a1,a2,a3,a4, w5[w][0],w5[w][1],w5[w][2],w5[w][3],w5[w][4]);
    float d0=sqrtf(a0)*0.0625f, d1=sqrtf(a1)*0.0625f, d2=sqrtf(a2)*0.0625f,
          d3=sqrtf(a3)*0.0625f, d4=sqrtf(a4)*0.0625f;
    float s = d0*d0; s += d1*d1; s += d2*d2; s += d3*d3; s += d4*d4;
    density[b*NT + i] = expf(-(s / 5.0f));
    float vm = fmaxf(fmaxf(wm[0],wm[1]), fmaxf(wm[2],wm[3]));
    atomicMax(vmax + b, __float_as_int(vm));
  }
}

__global__ __launch_bounds__(256) void parent_kernel(const float* __restrict__ G, const float* __restrict__ sq,
                                                     const float* __restrict__ density, const int* __restrict__ vmax,
                                                     float* __restrict__ score, int b){
  int i = blockIdx.x;
  int tid = threadIdx.x;
  const float* sqb = sq + b*NT;
  const float* den = density + b*NT;
  float sqi = sqb[i];
  float di = den[i];
  const float* row = G + (size_t)i*NT;
  float minv = INFINITY;
  for (int j = tid; j < NT; j += 256){
    float v = fmaxf(sqi + sqb[j] - 2.0f*row[j], 0.0f);
    minv = fminf(minv, (den[j] > di) ? v : INFINITY);
  }
#pragma unroll
  for (int m = 1; m < 64; m <<= 1) minv = fminf(minv, __shfl_xor(minv,m,64));
  __shared__ float wmn[4];
  int lane = tid & 63, wid = tid >> 6;
  if (lane == 0) wmn[wid] = minv;
  __syncthreads();
  if (tid == 0){
    float mv = fminf(fminf(wmn[0],wmn[1]), fminf(wmn[2],wmn[3]));
    float dmax = sqrtf(__int_as_float(vmax[b])) * 0.0625f;
    float dp = isinf(mv) ? dmax : sqrtf(mv) * 0.0625f;
    score[b*NT + i] = dp * di;
  }
}

__global__ __launch_bounds__(1024) void topk_sort(const float* __restrict__ score, int* __restrict__ idx_down, int b){
  __shared__ float ss[4096];
  __shared__ int ii[4096];
  int tid = threadIdx.x;
  for (int t = tid; t < 4096; t += 1024){ ss[t] = score[b*NT + t]; ii[t] = t; }
  for (int k = 2; k <= 4096; k <<= 1){
    for (int j = k >> 1; j > 0; j >>= 1){
      __syncthreads();
      for (int t = tid; t < 4096; t += 1024){
        int p = t ^ j;
        if (p > t){
          float s1 = ss[t], s2 = ss[p];
          int i1 = ii[t], i2 = ii[p];
          bool lt = (s1 > s2) || (s1 == s2 && i1 < i2);
          bool up = ((t & k) == 0);
          if (up ? !lt : lt){ ss[t]=s2; ss[p]=s1; ii[t]=i2; ii[p]=i1; }
        }
      }
    }
  }
  __syncthreads();
  if (tid < MC) idx_down[b*MC + tid] = ii[tid];
}

__global__ __launch_bounds__(256) void assign_kernel(const float* __restrict__ G, const float* __restrict__ sq,
                                                     const int* __restrict__ idx_down, int* __restrict__ idx_cluster, int b){
  int jl = threadIdx.x & 63, mq = threadIdx.x >> 6;
  int j = blockIdx.x * 64 + jl;
  const float* sqb = sq + b*NT;
  float sqj = sqb[j];
  const int* idb = idx_down + b*MC;
  float bestd = INFINITY; int bestm = 0x7fffffff;
  for (int m = mq*256; m < mq*256 + 256; ++m){
    int im = idb[m];
    float g = G[(size_t)im*NT + j];
    float v = fmaxf(sqb[im] + sqj - 2.0f*g, 0.0f);
    float d = sqrtf(v) * 0.0625f;
    if (d < bestd){ bestd = d; bestm = m; }
  }
  __shared__ float ld[4][64];
  __shared__ int lm[4][64];
  ld[mq][jl] = bestd; lm[mq][jl] = bestm;
  __syncthreads();
  if (mq == 0){
    for (int q = 1; q < 4; ++q){
      float d2 = ld[q][jl]; int m2 = lm[q][jl];
      if (d2 < bestd || (d2 == bestd && m2 < bestm)){ bestd = d2; bestm = m2; }
    }
    idx_cluster[b*NT + j] = bestm;
  }
}

__global__ __launch_bounds__(256) void override_kernel(const int* __restrict__ idx_down, int* __restrict__ idx_cluster, int b){
  int m = blockIdx.x * 256 + threadIdx.x;
  if (m < MC) idx_cluster[b*NT + idx_down[b*MC + m]] = m;
}

__global__ __launch_bounds__(256) void allw_kernel(const int* __restrict__ idx_cluster, const float* __restrict__ wt,
                                                   float* __restrict__ allw){
  int lin = blockIdx.x * 256 + threadIdx.x;
  int b = lin >> 12;
  atomicAdd(&allw[b*MC + idx_cluster[lin]], wt[lin]);
}
__global__ __launch_bounds__(256) void normw_kernel(const int* __restrict__ idx_cluster, const float* __restrict__ wt,
                                                    const float* __restrict__ allw, float* __restrict__ nw){
  int lin = blockIdx.x * 256 + threadIdx.x;
  int b = lin >> 12;
  nw[lin] = wt[lin] / (allw[b*MC + idx_cluster[lin]] + EPS_F);
}
__global__ __launch_bounds__(256) void xdown_kernel(const int* __restrict__ idx_cluster, const float* __restrict__ nw,
                                                    const float* __restrict__ xt, float* __restrict__ xdown){
  int bn = blockIdx.x;
  int d = threadIdx.x;
  int b = bn >> 12;
  int ic = idx_cluster[bn];
  float v = xt[(size_t)bn*DOUT + d] * nw[bn];
  atomicAdd(&xdown[((size_t)(b*MC + ic))*DOUT + d], v);
}
__global__ __launch_bounds__(256) void out0_kernel(const float* __restrict__ xdown, float* __restrict__ out){
  int lin = blockIdx.x * 256 + threadIdx.x;
  out[lin] = xdown[lin];
}
__global__ __launch_bounds__(256) void out12a_kernel(const int* __restrict__ idx_agg, const int* __restrict__ idx_cluster,
                                                     const float* __restrict__ aggw, const float* __restrict__ nw,
                                                     float* __restrict__ awd, int* __restrict__ awdmax,
                                                     float* __restrict__ out1){
  __shared__ float red[4];
  int lin = blockIdx.x * 256 + threadIdx.x;
  int b = lin >> 12;
  int ia = idx_agg[lin];
  int ic = idx_cluster[b*NT + ia];
  out1[lin] = (float)ic;
  float v = aggw[lin] * nw[b*NT + ia];
  awd[lin] = v;
  float wv = v;
#pragma unroll
  for (int m = 1; m < 64; m <<= 1) wv = fmaxf(wv, __shfl_xor(wv, m, 64));
  int lane = threadIdx.x & 63, wid = threadIdx.x >> 6;
  if (lane == 0) red[wid] = wv;
  __syncthreads();
  if (threadIdx.x == 0){
    float bm = fmaxf(fmaxf(red[0], red[1]), fmaxf(red[2], red[3]));
    atomicMax(&awdmax[b], __float_as_int(bm));
  }
}
__global__ __launch_bounds__(256) void out2_kernel(const float* __restrict__ awd, const int* __restrict__ awdmax,
                                                   float* __restrict__ out2){
  int lin = blockIdx.x * 256 + threadIdx.x;
  int b = lin >> 12;
  out2[lin] = awd[lin] / __int_as_float(awdmax[b]);
}

extern "C" void kernel_launch(void* const* d_in, const int* in_sizes, int n_in,
                              void* d_out, int out_size, void* d_ws, size_t ws_size,
                              hipStream_t stream) {
  const float* x      = (const float*)d_in[0];
  const float* loc    = (const float*)d_in[1];
  const int*   idxagg = (const int*)d_in[2];
  const float* aggw   = (const float*)d_in[3];
  const float* convw  = (const float*)d_in[7];
  const float* convb  = (const float*)d_in[8];
  const float* skipw  = (const float*)d_in[9];
  const float* lng    = (const float*)d_in[10];
  const float* lnb    = (const float*)d_in[11];
  const float* confw  = (const float*)d_in[12];
  const float* confb  = (const float*)d_in[13];

  char* ws = (char*)d_ws;
  float* w_xmap  = (float*)(ws + OFF_XMAP);
  float* w_cnt   = (float*)(ws + OFF_CNT);
  float* w_tot   = (float*)(ws + OFF_TOT);
  float* w_allw  = (float*)(ws + OFF_ALLW);
  float* w_xdown = (float*)(ws + OFF_XDOWN);
  int*   w_vmax  = (int*)  (ws + OFF_VMAX);
  int*   w_awdm  = (int*)  (ws + OFF_AWDM);
  float* w_ymap  = (float*)(ws + OFF_YMAP);
  float* w_xt    = (float*)(ws + OFF_XT);
  float* w_sq    = (float*)(ws + OFF_SQ);
  float* w_den   = (float*)(ws + OFF_DEN);
  float* w_score = (float*)(ws + OFF_SCORE);
  float* w_wt    = (float*)(ws + OFF_WT);
  float* w_nw    = (float*)(ws + OFF_NW);
  float* w_awd   = (float*)(ws + OFF_AWD);
  int*   w_idxd  = (int*)  (ws + OFF_IDXD);
  int*   w_idxc  = (int*)  (ws + OFF_IDXC);
  float* w_gram  = (float*)(ws + OFF_GRAM);
  float* w_wtr   = (float*)(ws + OFF_WTR);
  float* w_p     = (float*)(ws + OFF_P);

  float* out0 = (float*)d_out;
  float* out1 = out0 + NB*MC*DOUT;
  float* out2 = out1 + NB*NT;

  hipMemsetAsync(ws, 0, ZERO_BYTES, stream);

  t2m_scatter<<<NB*NT*CI/256, 256, 0, stream>>>(x, loc, idxagg, w_xmap, w_cnt);
  t2m_norm<<<NB*HWI*CI/256, 256, 0, stream>>>(w_xmap, w_cnt);
  wtrans_kernel<<<1152, 256, 0, stream>>>(convw, w_wtr);
  im2col_kernel<<<2048, 256, 0, stream>>>(w_xmap, w_p);
  conv_gemm<<<dim3(4, 64), 256, 0, stream>>>(w_p, w_wtr, convb, w_ymap);
  tot_kernel<<<NB*NT/256, 256, 0, stream>>>(idxagg, aggw, w_tot);
  skip_kernel<<<NB*NT/8, 256, 0, stream>>>(x, skipw, w_xt);
  m2t_scatter<<<NB*NT, 256, 0, stream>>>(w_ymap, loc, idxagg, aggw, w_tot, w_xt);
  ln_kernel<<<NB*NT, 256, 0, stream>>>(w_xt, lng, lnb, confw, confb, w_sq, w_wt);

  for (int b = 0; b < NB; ++b){
    gram_kernel<<<528, 256, 0, stream>>>(w_xt + (size_t)b*NT*DOUT, w_gram);
    mirror_kernel<<<496*4, 256, 0, stream>>>(w_gram);
    density_kernel<<<NT, 256, 0, stream>>>(w_gram, w_sq, w_den, w_vmax, b);
    parent_kernel<<<NT, 256, 0, stream>>>(w_gram, w_sq, w_den, w_vmax, w_score, b);
    topk_sort<<<1, 1024, 0, stream>>>(w_score, w_idxd, b);
    assign_kernel<<<64, 256, 0, stream>>>(w_gram, w_sq, w_idxd, w_idxc, b);
    override_kernel<<<4, 256, 0, stream>>>(w_idxd, w_idxc, b);
  }

  allw_kernel<<<NB*NT/256, 256, 0, stream>>>(w_idxc, w_wt, w_allw);
  normw_kernel<<<NB*NT/256, 256, 0, stream>>>(w_idxc, w_wt, w_allw, w_nw);
  xdown_kernel<<<NB*NT, 256, 0, stream>>>(w_idxc, w_nw, w_xt, w_xdown);
  out0_kernel<<<NB*MC*DOUT/256, 256, 0, stream>>>(w_xdown, out0);
  out12a_kernel<<<NB*NT/256, 256, 0, stream>>>(idxagg, w_idxc, aggw, w_nw, w_awd, w_awdm, out1);
  out2_kernel<<<NB*NT/256, 256, 0, stream>>>(w_awd, w_awdm, out2);

  (void)in_sizes; (void)n_in; (void)out_size; (void)ws_size;
}

// Round 8
// 1344.024 us; speedup vs baseline: 1.3009x; 1.0008x over previous
//
#include <hip/hip_runtime.h>
#include <math.h>

// B=4, N=4096, C=128, DOUT=256, H=W=64 (conv out 32x32), M=1024, K=5.
// Inputs f32; output buffer f32.
#define NB 4
#define NT 4096
#define CI 128
#define DOUT 256
#define HWI 4096
#define HWO 1024
#define MC 1024
#define EPS_F 1e-6f
#define GSZ 16777216ull          // floats per 4096x4096 G
#define GSZB 67108864ull

// ---------------- workspace layout (bytes) ----------------
static const size_t OFF_XMAP  = 0;                          // 8388608
static const size_t OFF_CNT   = OFF_XMAP + 8388608;         // 65536
static const size_t OFF_TOT   = OFF_CNT  + 65536;
static const size_t OFF_ALLW  = OFF_TOT  + 65536;
static const size_t OFF_XDOWN = OFF_ALLW + 16384;
static const size_t OFF_VMAX  = OFF_XDOWN + 4194304;
static const size_t OFF_AWDM  = OFF_VMAX + 256;
static const size_t ZERO_BYTES= OFF_AWDM + 256;
static const size_t OFF_YMAP  = ZERO_BYTES;                 // 4194304
static const size_t OFF_XT    = OFF_YMAP + 4194304;         // 16777216
static const size_t OFF_SQ    = OFF_XT + 16777216;
static const size_t OFF_DEN   = OFF_SQ + 65536;
static const size_t OFF_SCORE = OFF_DEN + 65536;
static const size_t OFF_WT    = OFF_SCORE + 65536;
static const size_t OFF_NW    = OFF_WT + 65536;
static const size_t OFF_AWD   = OFF_NW + 65536;
static const size_t OFF_IDXD  = OFF_AWD + 65536;
static const size_t OFF_IDXC  = OFF_IDXD + 16384;
static const size_t OFF_GRAM  = OFF_IDXC + 65536;
static const size_t WTRB = 1179648, PB = 18874368;
static const size_t NEED_BIG = OFF_GRAM + 4ull*GSZB + WTRB + PB;

// ---------------- helpers ----------------
__device__ __forceinline__ float waveSum(float v){
#pragma unroll
  for (int m = 1; m < 64; m <<= 1) v += __shfl_xor(v, m, 64);
  return v;
}
__device__ __forceinline__ float blockSum256(float v, float* red){
  v = waveSum(v);
  int lane = threadIdx.x & 63, wid = threadIdx.x >> 6;
  __syncthreads();
  if (lane == 0) red[wid] = v;
  __syncthreads();
  return red[0] + red[1] + red[2] + red[3];
}
__device__ __forceinline__ void merge5(float& a0, float& a1, float& a2, float& a3, float& a4,
                                       float b0, float b1, float b2, float b3, float b4){
  float l0=a0,l1=a1,l2=a2,l3=fminf(a3,b4),l4=fminf(a4,b3),l5=b2,l6=b1,l7=b0;
  float t0=fminf(l0,l4), t4=fmaxf(l0,l4);
  float t1=fminf(l1,l5), t5=fmaxf(l1,l5);
  float t2=fminf(l2,l6), t6=fmaxf(l2,l6);
  float t3=fminf(l3,l7), t7=fmaxf(l3,l7);
  float u0=fminf(t0,t2), u2=fmaxf(t0,t2);
  float u1=fminf(t1,t3), u3=fmaxf(t1,t3);
  float u4=fminf(t4,t6);
  float u5=fminf(t5,t7);
  a0=fminf(u0,u1); a1=fmaxf(u0,u1);
  a2=fminf(u2,u3); a3=fmaxf(u2,u3);
  a4=fminf(u4,u5);
}
__device__ __forceinline__ void ins5(float v, float& t0, float& t1, float& t2, float& t3, float& t4){
  t4 = fminf(t4, v);
  float a;
  a = fminf(t3,t4); t4 = fmaxf(t3,t4); t3 = a;
  a = fminf(t2,t3); t3 = fmaxf(t2,t3); t2 = a;
  a = fminf(t1,t2); t2 = fmaxf(t1,t2); t1 = a;
  a = fminf(t0,t1); t1 = fmaxf(t0,t1); t0 = a;
}
__device__ __forceinline__ int grid_cell(float lx, float ly, int dim){
  lx = (fminf(fmaxf(lx, -1.f), 1.f) + 1.f) * 0.5f;
  ly = (fminf(fmaxf(ly, -1.f), 1.f) + 1.f) * 0.5f;
  float s = (float)(dim - 1);
  int col = (int)rintf(lx * s); col = min(max(col, 0), dim - 1);
  int row = (int)rintf(ly * s); row = min(max(row, 0), dim - 1);
  return row * dim + col;
}

// ---------------- front-end kernels (unchanged) ----------------
__global__ __launch_bounds__(256) void t2m_scatter(const float* __restrict__ x,
                                                   const float* __restrict__ loc,
                                                   const int* __restrict__ idx_agg,
                                                   float* __restrict__ xmap, float* __restrict__ cnt){
  int lin = blockIdx.x * 256 + threadIdx.x;
  int c  = lin & 127;
  int bn = lin >> 7;
  int b  = bn >> 12;
  float lx = loc[(size_t)bn*2 + 0];
  float ly = loc[(size_t)bn*2 + 1];
  int cell = grid_cell(lx, ly, 64);
  int ia = idx_agg[bn];
  float val = x[((size_t)(b*NT + ia))*CI + c];
  atomicAdd(&xmap[((size_t)(b*HWI + cell))*CI + c], val);
  if (c == 0) atomicAdd(&cnt[b*HWI + cell], 1.0f);
}

__global__ __launch_bounds__(256) void t2m_norm(float* __restrict__ xmap, const float* __restrict__ cnt){
  int lin = blockIdx.x * 256 + threadIdx.x;
  xmap[lin] = xmap[lin] / (cnt[lin >> 7] + EPS_F);
}

__global__ __launch_bounds__(256) void wtrans_kernel(const float* __restrict__ cw, float* __restrict__ wT){
  int lin = blockIdx.x * 256 + threadIdx.x;
  int k = lin >> 8, d = lin & 255;
  wT[lin] = cw[(size_t)d*1152 + k];
}

__global__ __launch_bounds__(256) void im2col_kernel(const float* __restrict__ xmap, float* __restrict__ P){
  int tid = threadIdx.x;
  int c = tid & 127, n2 = tid >> 7;
  int n = blockIdx.x * 2 + n2;
  int b = n >> 10, rem = n & 1023;
  int oh = rem >> 5, ow = rem & 31;
  const float* xb = xmap + (size_t)b*HWI*CI;
  float* prow = P + (size_t)n*1152 + c*9;
#pragma unroll
  for (int kh = 0; kh < 3; ++kh){
    int ih = oh*2 - 1 + kh;
#pragma unroll
    for (int kw = 0; kw < 3; ++kw){
      int iw = ow*2 - 1 + kw;
      bool inb = (ih >= 0) && (ih < 64) && (iw >= 0) && (iw < 64);
      prow[kh*3 + kw] = inb ? xb[(size_t)(ih*64 + iw)*CI + c] : 0.f;
    }
  }
}

__global__ __launch_bounds__(256) void conv_gemm(const float* __restrict__ P,
                                                 const float* __restrict__ wT,
                                                 const float* __restrict__ cb,
                                                 float* __restrict__ ymap){
  __shared__ float As[16][64];
  __shared__ float Bs[16][64];
  int n0 = blockIdx.y * 64, d0 = blockIdx.x * 64;
  int tid = threadIdx.x;
  int tx = tid & 15, ty = tid >> 4;
  int ln = tid & 63, kq = tid >> 6;
  int bkr = tid >> 4, bc4 = (tid & 15) * 4;
  float4 pav = *(const float4*)(P + (size_t)(n0+ln)*1152 + kq*4);
  float4 pbv = *(const float4*)(wT + (size_t)bkr*256 + d0 + bc4);
  float acc[4][4] = {{0}};
  for (int kt = 0; kt < 72; ++kt){
    __syncthreads();
    As[kq*4+0][ln]=pav.x; As[kq*4+1][ln]=pav.y; As[kq*4+2][ln]=pav.z; As[kq*4+3][ln]=pav.w;
    *(float4*)&Bs[bkr][bc4] = pbv;
    __syncthreads();
    if (kt < 71){
      int k2 = (kt + 1) * 16;
      pav = *(const float4*)(P + (size_t)(n0+ln)*1152 + k2 + kq*4);
      pbv = *(const float4*)(wT + (size_t)(k2 + bkr)*256 + d0 + bc4);
    }
#pragma unroll
    for (int k = 0; k < 16; ++k){
      float ar[4], br[4];
      *(float4*)ar = *(const float4*)&As[k][ty*4];
      *(float4*)br = *(const float4*)&Bs[k][tx*4];
#pragma unroll
      for (int r = 0; r < 4; ++r)
#pragma unroll
        for (int s = 0; s < 4; ++s) acc[r][s] += ar[r]*br[s];
    }
  }
  float4 bias = *(const float4*)(cb + d0 + tx*4);
#pragma unroll
  for (int r = 0; r < 4; ++r){
    float4 o;
    o.x = acc[r][0] + bias.x; o.y = acc[r][1] + bias.y;
    o.z = acc[r][2] + bias.z; o.w = acc[r][3] + bias.w;
    *(float4*)(ymap + (size_t)(n0 + ty*4 + r)*DOUT + d0 + tx*4) = o;
  }
}

__global__ __launch_bounds__(256) void tot_kernel(const int* __restrict__ idx_agg,
                                                  const float* __restrict__ aggw,
                                                  float* __restrict__ tot){
  int lin = blockIdx.x * 256 + threadIdx.x;
  int b = lin >> 12;
  atomicAdd(&tot[b*NT + idx_agg[lin]], aggw[lin]);
}

__global__ __launch_bounds__(256) void skip_kernel(const float* __restrict__ x,
                                                   const float* __restrict__ sw,
                                                   float* __restrict__ xt){
  int rowbase = blockIdx.x * 8;
  int d = threadIdx.x;
  __shared__ float xr[8*128];
  ((float4*)xr)[d] = ((const float4*)(x + (size_t)rowbase*CI))[d];
  __syncthreads();
  float acc[8] = {0,0,0,0,0,0,0,0};
  const float* wd = sw + (size_t)d*CI;
  for (int c = 0; c < 128; ++c){
    float w = wd[c];
#pragma unroll
    for (int r = 0; r < 8; ++r) acc[r] += w * xr[r*128 + c];
  }
  for (int r = 0; r < 8; ++r) xt[(size_t)(rowbase + r)*DOUT + d] = acc[r];
}

__global__ __launch_bounds__(256) void m2t_scatter(const float* __restrict__ ymap,
                                                   const float* __restrict__ loc,
                                                   const int* __restrict__ idx_agg,
                                                   const float* __restrict__ aggw,
                                                   const float* __restrict__ tot,
                                                   float* __restrict__ xt){
  int bn = blockIdx.x;
  int d = threadIdx.x;
  int b = bn >> 12;
  float lx = loc[(size_t)bn*2 + 0];
  float ly = loc[(size_t)bn*2 + 1];
  int cell = grid_cell(lx, ly, 32);
  int ia = idx_agg[bn];
  float w = aggw[bn] / (tot[b*NT + ia] + EPS_F);
  float val = ymap[((size_t)(b*HWO + cell))*DOUT + d] * w;
  atomicAdd(&xt[((size_t)(b*NT + ia))*DOUT + d], val);
}

__global__ __launch_bounds__(256) void ln_kernel(float* __restrict__ xt,
                                                 const float* __restrict__ g,
                                                 const float* __restrict__ bta,
                                                 const float* __restrict__ cw,
                                                 const float* __restrict__ cb,
                                                 float* __restrict__ sq, float* __restrict__ wt){
  __shared__ float red[4];
  int row = blockIdx.x;
  int d = threadIdx.x;
  float v = xt[(size_t)row*DOUT + d];
  float mu = blockSum256(v, red) * (1.0f/256.0f);
  float xc = v - mu;
  float var = blockSum256(xc*xc, red) * (1.0f/256.0f);
  float rn = 1.0f / sqrtf(var + 1e-5f);
  float y = xc * rn * g[d] + bta[d];
  xt[(size_t)row*DOUT + d] = y;
  float s2 = blockSum256(y*y, red);
  float cf = blockSum256(y*cw[d], red);
  if (d == 0){ sq[row] = s2; wt[row] = expf(cf + cb[0]); }
}

// ---------------- clustering kernels, batch-spanning ----------------
// batch = b_base + blockIdx.y (or .x for topk); Gb = G + blockIdx.y*gstride.
__global__ __launch_bounds__(256) void gram_all(const float* __restrict__ xt, float* __restrict__ G,
                                                int b_base, size_t gstride){
  __shared__ float As[8][128];
  __shared__ float Bs[8][128];
  int b = b_base + blockIdx.y;
  const float* A = xt + (size_t)b*NT*DOUT;
  float* Gb = G + (size_t)blockIdx.y*gstride;
  int t = blockIdx.x;
  int ti = 0, accu = 0;
  while (accu + ti + 1 <= t){ accu += ti + 1; ++ti; }
  int tj = t - accu;
  int i0 = ti * 128, j0 = tj * 128;
  int tid = threadIdx.x;
  int lrow = tid >> 1;
  int lc4  = tid & 1;
  int ty = tid >> 4, tx = tid & 15;
  int r0 = ty * 8;
  int cA = tx * 4, cB = 64 + tx * 4;
  float4 av = *(const float4*)(A + (size_t)(i0+lrow)*DOUT + lc4*4);
  float4 bv = *(const float4*)(A + (size_t)(j0+lrow)*DOUT + lc4*4);
  float acc[8][8] = {{0}};
  for (int kt = 0; kt < 256; kt += 8){
    __syncthreads();
    As[lc4*4+0][lrow]=av.x; As[lc4*4+1][lrow]=av.y; As[lc4*4+2][lrow]=av.z; As[lc4*4+3][lrow]=av.w;
    Bs[lc4*4+0][lrow]=bv.x; Bs[lc4*4+1][lrow]=bv.y; Bs[lc4*4+2][lrow]=bv.z; Bs[lc4*4+3][lrow]=bv.w;
    __syncthreads();
    if (kt < 248){
      av = *(const float4*)(A + (size_t)(i0+lrow)*DOUT + kt + 8 + lc4*4);
      bv = *(const float4*)(A + (size_t)(j0+lrow)*DOUT + kt + 8 + lc4*4);
    }
#pragma unroll
    for (int k = 0; k < 8; ++k){
      float ar[8], br[8];
      *(float4*)&ar[0] = *(const float4*)&As[k][r0];
      *(float4*)&ar[4] = *(const float4*)&As[k][r0+4];
      *(float4*)&br[0] = *(const float4*)&Bs[k][cA];
      *(float4*)&br[4] = *(const float4*)&Bs[k][cB];
#pragma unroll
      for (int r = 0; r < 8; ++r)
#pragma unroll
        for (int s = 0; s < 8; ++s) acc[r][s] += ar[r]*br[s];
    }
  }
  for (int r = 0; r < 8; ++r){
    size_t row = (size_t)(i0 + r0 + r);
    *(float4*)(Gb + row*NT + j0 + cA) = *(float4*)&acc[r][0];
    *(float4*)(Gb + row*NT + j0 + cB) = *(float4*)&acc[r][4];
  }
}

__global__ __launch_bounds__(256) void mirror_all(float* __restrict__ G, size_t gstride){
  __shared__ float tile[64*65];
  float* Gb = G + (size_t)blockIdx.y*gstride;
  int blk = blockIdx.x;
  int q = blk & 3; int t = blk >> 2;
  int ti = 1, accu = 0;
  while (accu + ti <= t){ accu += ti; ++ti; }
  int tj = t - accu;
  int qa = q >> 1, qb = q & 1;
  int rs = ti*128 + qa*64, cs = tj*128 + qb*64;
  int rd = tj*128 + qb*64, cd = ti*128 + qa*64;
  int lane = threadIdx.x & 63, w = threadIdx.x >> 6;
  for (int i = 0; i < 16; ++i){
    int r = w*16 + i;
    tile[r*65 + lane] = Gb[(size_t)(rs + r)*NT + cs + lane];
  }
  __syncthreads();
  for (int i = 0; i < 16; ++i){
    int r = w*16 + i;
    Gb[(size_t)(rd + r)*NT + cd + lane] = tile[lane*65 + r];
  }
}

__global__ __launch_bounds__(256) void density_all(const float* __restrict__ G, size_t gstride,
                                                   const float* __restrict__ sq,
                                                   float* __restrict__ density, int* __restrict__ vmax,
                                                   int b_base){
  int b = b_base + blockIdx.y;
  const float* Gb = G + (size_t)blockIdx.y*gstride;
  int i = blockIdx.x;
  int tid = threadIdx.x;
  const float* sqb = sq + b*NT;
  float sqi = sqb[i];
  const float* row = Gb + (size_t)i*NT;
  float t0=INFINITY,t1=INFINITY,t2=INFINITY,t3=INFINITY,t4=INFINITY;
  float vmx = 0.f;
  for (int j = tid*4; j < NT; j += 1024){
    float4 g4 = *(const float4*)(row + j);
    float4 s4 = *(const float4*)(sqb + j);
    float v0 = fmaxf(sqi + s4.x - 2.0f*g4.x, 0.0f);
    float v1 = fmaxf(sqi + s4.y - 2.0f*g4.y, 0.0f);
    float v2 = fmaxf(sqi + s4.z - 2.0f*g4.z, 0.0f);
    float v3 = fmaxf(sqi + s4.w - 2.0f*g4.w, 0.0f);
    vmx = fmaxf(fmaxf(vmx, fmaxf(v0,v1)), fmaxf(v2,v3));
    ins5(v0,t0,t1,t2,t3,t4); ins5(v1,t0,t1,t2,t3,t4);
    ins5(v2,t0,t1,t2,t3,t4); ins5(v3,t0,t1,t2,t3,t4);
  }
#pragma unroll
  for (int m = 1; m < 64; m <<= 1){
    float b0=__shfl_xor(t0,m,64), b1=__shfl_xor(t1,m,64), b2=__shfl_xor(t2,m,64),
          b3=__shfl_xor(t3,m,64), b4=__shfl_xor(t4,m,64);
    merge5(t0,t1,t2,t3,t4,b0,b1,b2,b3,b4);
    vmx = fmaxf(vmx, __shfl_xor(vmx,m,64));
  }
  __shared__ float w5[4][5];
  __shared__ float wm[4];
  int lane = tid & 63, wid = tid >> 6;
  if (lane == 0){ w5[wid][0]=t0; w5[wid][1]=t1; w5[wid][2]=t2; w5[wid][3]=t3; w5[wid][4]=t4; wm[wid]=vmx; }
  __syncthreads();
  if (tid == 0){
    float a0=w5[0][0],a1=w5[0][1],a2=w5[0][2],a3=w5[0][3],a4=w5[0][4];
    for (int w = 1; w < 4; ++w) merge5(a0,a1,a2,a3,a4, w5[w][0],w5[w][1],w5[w][2],w5[w][3],w5[w][4]);
    float d0=sqrtf(a0)*0.0625f, d1=sqrtf(a1)*0.0625f, d2=sqrtf(a2)*0.0625f,
          d3=sqrtf(a3)*0.0625f, d4=sqrtf(a4)*0.0625f;
    float s = d0*d0; s += d1*d1; s += d2*d2; s += d3*d3; s += d4*d4;
    density[b*NT + i] = expf(-(s / 5.0f));
    float vm = fmaxf(fmaxf(wm[0],wm[1]), fmaxf(wm[2],wm[3]));
    atomicMax(vmax + b, __float_as_int(vm));
  }
}

__global__ __launch_bounds__(256) void parent_all(const float* __restrict__ G, size_t gstride,
                                                  const float* __restrict__ sq,
                                                  const float* __restrict__ density, const int* __restrict__ vmax,
                                                  float* __restrict__ score, int b_base){
  int b = b_base + blockIdx.y;
  const float* Gb = G + (size_t)blockIdx.y*gstride;
  int i = blockIdx.x;
  int tid = threadIdx.x;
  const float* sqb = sq + b*NT;
  const float* den = density + b*NT;
  float sqi = sqb[i];
  float di = den[i];
  const float* row = Gb + (size_t)i*NT;
  float minv = INFINITY;
  for (int j = tid*4; j < NT; j += 1024){
    float4 g4 = *(const float4*)(row + j);
    float4 s4 = *(const float4*)(sqb + j);
    float4 d4 = *(const float4*)(den + j);
    float v0 = fmaxf(sqi + s4.x - 2.0f*g4.x, 0.0f);
    float v1 = fmaxf(sqi + s4.y - 2.0f*g4.y, 0.0f);
    float v2 = fmaxf(sqi + s4.z - 2.0f*g4.z, 0.0f);
    float v3 = fmaxf(sqi + s4.w - 2.0f*g4.w, 0.0f);
    minv = fminf(minv, (d4.x > di) ? v0 : INFINITY);
    minv = fminf(minv, (d4.y > di) ? v1 : INFINITY);
    minv = fminf(minv, (d4.z > di) ? v2 : INFINITY);
    minv = fminf(minv, (d4.w > di) ? v3 : INFINITY);
  }
#pragma unroll
  for (int m = 1; m < 64; m <<= 1) minv = fminf(minv, __shfl_xor(minv,m,64));
  __shared__ float wmn[4];
  int lane = tid & 63, wid = tid >> 6;
  if (lane == 0) wmn[wid] = minv;
  __syncthreads();
  if (tid == 0){
    float mv = fminf(fminf(wmn[0],wmn[1]), fminf(wmn[2],wmn[3]));
    float dmax = sqrtf(__int_as_float(vmax[b])) * 0.0625f;
    float dp = isinf(mv) ? dmax : sqrtf(mv) * 0.0625f;
    score[b*NT + i] = dp * di;
  }
}

__global__ __launch_bounds__(1024) void topk_all(const float* __restrict__ score, int* __restrict__ idx_down, int b_base){
  __shared__ float ss[4096];
  __shared__ int ii[4096];
  int b = b_base + blockIdx.x;
  int tid = threadIdx.x;
  for (int t = tid; t < 4096; t += 1024){ ss[t] = score[b*NT + t]; ii[t] = t; }
  for (int k = 2; k <= 4096; k <<= 1){
    for (int j = k >> 1; j > 0; j >>= 1){
      __syncthreads();
      for (int t = tid; t < 4096; t += 1024){
        int p = t ^ j;
        if (p > t){
          float s1 = ss[t], s2 = ss[p];
          int i1 = ii[t], i2 = ii[p];
          bool lt = (s1 > s2) || (s1 == s2 && i1 < i2);
          bool up = ((t & k) == 0);
          if (up ? !lt : lt){ ss[t]=s2; ss[p]=s1; ii[t]=i2; ii[p]=i1; }
        }
      }
    }
  }
  __syncthreads();
  if (tid < MC) idx_down[b*MC + tid] = ii[tid];
}

__global__ __launch_bounds__(256) void assign_all(const float* __restrict__ G, size_t gstride,
                                                  const float* __restrict__ sq,
                                                  const int* __restrict__ idx_down, int* __restrict__ idx_cluster,
                                                  int b_base){
  int b = b_base + blockIdx.y;
  const float* Gb = G + (size_t)blockIdx.y*gstride;
  int jl = threadIdx.x & 63, mq = threadIdx.x >> 6;
  int j = blockIdx.x * 64 + jl;
  const float* sqb = sq + b*NT;
  float sqj = sqb[j];
  const int* idb = idx_down + b*MC;
  float bestd = INFINITY; int bestm = 0x7fffffff;
  for (int m = mq*256; m < mq*256 + 256; ++m){
    int im = idb[m];
    float g = Gb[(size_t)im*NT + j];
    float v = fmaxf(sqb[im] + sqj - 2.0f*g, 0.0f);
    float d = sqrtf(v) * 0.0625f;
    if (d < bestd){ bestd = d; bestm = m; }
  }
  __shared__ float ld[4][64];
  __shared__ int lm[4][64];
  ld[mq][jl] = bestd; lm[mq][jl] = bestm;
  __syncthreads();
  if (mq == 0){
    for (int q = 1; q < 4; ++q){
      float d2 = ld[q][jl]; int m2 = lm[q][jl];
      if (d2 < bestd || (d2 == bestd && m2 < bestm)){ bestd = d2; bestm = m2; }
    }
    idx_cluster[b*NT + j] = bestm;
  }
}

__global__ __launch_bounds__(256) void override_all(const int* __restrict__ idx_down, int* __restrict__ idx_cluster,
                                                    int b_base){
  int b = b_base + blockIdx.y;
  int m = blockIdx.x * 256 + threadIdx.x;
  if (m < MC) idx_cluster[b*NT + idx_down[b*MC + m]] = m;
}

// ---------------- merge + outputs (unchanged) ----------------
__global__ __launch_bounds__(256) void allw_kernel(const int* __restrict__ idx_cluster, const float* __restrict__ wt,
                                                   float* __restrict__ allw){
  int lin = blockIdx.x * 256 + threadIdx.x;
  int b = lin >> 12;
  atomicAdd(&allw[b*MC + idx_cluster[lin]], wt[lin]);
}
__global__ __launch_bounds__(256) void normw_kernel(const int* __restrict__ idx_cluster, const float* __restrict__ wt,
                                                    const float* __restrict__ allw, float* __restrict__ nw){
  int lin = blockIdx.x * 256 + threadIdx.x;
  int b = lin >> 12;
  nw[lin] = wt[lin] / (allw[b*MC + idx_cluster[lin]] + EPS_F);
}
__global__ __launch_bounds__(256) void xdown_kernel(const int* __restrict__ idx_cluster, const float* __restrict__ nw,
                                                    const float* __restrict__ xt, float* __restrict__ xdown){
  int bn = blockIdx.x;
  int d = threadIdx.x;
  int b = bn >> 12;
  int ic = idx_cluster[bn];
  float v = xt[(size_t)bn*DOUT + d] * nw[bn];
  atomicAdd(&xdown[((size_t)(b*MC + ic))*DOUT + d], v);
}
__global__ __launch_bounds__(256) void out0_kernel(const float* __restrict__ xdown, float* __restrict__ out){
  int lin = blockIdx.x * 256 + threadIdx.x;
  out[lin] = xdown[lin];
}
__global__ __launch_bounds__(256) void out12a_kernel(const int* __restrict__ idx_agg, const int* __restrict__ idx_cluster,
                                                     const float* __restrict__ aggw, const float* __restrict__ nw,
                                                     float* __restrict__ awd, int* __restrict__ awdmax,
                                                     float* __restrict__ out1){
  __shared__ float red[4];
  int lin = blockIdx.x * 256 + threadIdx.x;
  int b = lin >> 12;
  int ia = idx_agg[lin];
  int ic = idx_cluster[b*NT + ia];
  out1[lin] = (float)ic;
  float v = aggw[lin] * nw[b*NT + ia];
  awd[lin] = v;
  float wv = v;
#pragma unroll
  for (int m = 1; m < 64; m <<= 1) wv = fmaxf(wv, __shfl_xor(wv, m, 64));
  int lane = threadIdx.x & 63, wid = threadIdx.x >> 6;
  if (lane == 0) red[wid] = wv;
  __syncthreads();
  if (threadIdx.x == 0){
    float bm = fmaxf(fmaxf(red[0], red[1]), fmaxf(red[2], red[3]));
    atomicMax(&awdmax[b], __float_as_int(bm));
  }
}
__global__ __launch_bounds__(256) void out2_kernel(const float* __restrict__ awd, const int* __restrict__ awdmax,
                                                   float* __restrict__ out2){
  int lin = blockIdx.x * 256 + threadIdx.x;
  int b = lin >> 12;
  out2[lin] = awd[lin] / __int_as_float(awdmax[b]);
}

extern "C" void kernel_launch(void* const* d_in, const int* in_sizes, int n_in,
                              void* d_out, int out_size, void* d_ws, size_t ws_size,
                              hipStream_t stream) {
  const float* x      = (const float*)d_in[0];
  const float* loc    = (const float*)d_in[1];
  const int*   idxagg = (const int*)d_in[2];
  const float* aggw   = (const float*)d_in[3];
  const float* convw  = (const float*)d_in[7];
  const float* convb  = (const float*)d_in[8];
  const float* skipw  = (const float*)d_in[9];
  const float* lng    = (const float*)d_in[10];
  const float* lnb    = (const float*)d_in[11];
  const float* confw  = (const float*)d_in[12];
  const float* confb  = (const float*)d_in[13];

  char* ws = (char*)d_ws;
  float* w_xmap  = (float*)(ws + OFF_XMAP);
  float* w_cnt   = (float*)(ws + OFF_CNT);
  float* w_tot   = (float*)(ws + OFF_TOT);
  float* w_allw  = (float*)(ws + OFF_ALLW);
  float* w_xdown = (float*)(ws + OFF_XDOWN);
  int*   w_vmax  = (int*)  (ws + OFF_VMAX);
  int*   w_awdm  = (int*)  (ws + OFF_AWDM);
  float* w_ymap  = (float*)(ws + OFF_YMAP);
  float* w_xt    = (float*)(ws + OFF_XT);
  float* w_sq    = (float*)(ws + OFF_SQ);
  float* w_den   = (float*)(ws + OFF_DEN);
  float* w_score = (float*)(ws + OFF_SCORE);
  float* w_wt    = (float*)(ws + OFF_WT);
  float* w_nw    = (float*)(ws + OFF_NW);
  float* w_awd   = (float*)(ws + OFF_AWD);
  int*   w_idxd  = (int*)  (ws + OFF_IDXD);
  int*   w_idxc  = (int*)  (ws + OFF_IDXC);
  float* w_gram  = (float*)(ws + OFF_GRAM);

  const int gcount = (ws_size >= NEED_BIG) ? 4 : 1;   // constant per harness -> graph-safe
  size_t offw = OFF_GRAM + (size_t)gcount * GSZB;
  float* w_wtr = (float*)(ws + offw);
  float* w_p   = (float*)(ws + offw + WTRB);

  float* out0 = (float*)d_out;
  float* out1 = out0 + NB*MC*DOUT;
  float* out2 = out1 + NB*NT;

  hipMemsetAsync(ws, 0, ZERO_BYTES, stream);

  t2m_scatter<<<NB*NT*CI/256, 256, 0, stream>>>(x, loc, idxagg, w_xmap, w_cnt);
  t2m_norm<<<NB*HWI*CI/256, 256, 0, stream>>>(w_xmap, w_cnt);
  wtrans_kernel<<<1152, 256, 0, stream>>>(convw, w_wtr);
  im2col_kernel<<<2048, 256, 0, stream>>>(w_xmap, w_p);
  conv_gemm<<<dim3(4, 64), 256, 0, stream>>>(w_p, w_wtr, convb, w_ymap);
  tot_kernel<<<NB*NT/256, 256, 0, stream>>>(idxagg, aggw, w_tot);
  skip_kernel<<<NB*NT/8, 256, 0, stream>>>(x, skipw, w_xt);
  m2t_scatter<<<NB*NT, 256, 0, stream>>>(w_ymap, loc, idxagg, aggw, w_tot, w_xt);
  ln_kernel<<<NB*NT, 256, 0, stream>>>(w_xt, lng, lnb, confw, confb, w_sq, w_wt);

  if (gcount == 4){
    gram_all   <<<dim3(528, 4), 256, 0, stream>>>(w_xt, w_gram, 0, GSZ);
    mirror_all <<<dim3(496*4, 4), 256, 0, stream>>>(w_gram, GSZ);
    density_all<<<dim3(NT, 4), 256, 0, stream>>>(w_gram, GSZ, w_sq, w_den, w_vmax, 0);
    parent_all <<<dim3(NT, 4), 256, 0, stream>>>(w_gram, GSZ, w_sq, w_den, w_vmax, w_score, 0);
    topk_all   <<<4, 1024, 0, stream>>>(w_score, w_idxd, 0);
    assign_all <<<dim3(64, 4), 256, 0, stream>>>(w_gram, GSZ, w_sq, w_idxd, w_idxc, 0);
    override_all<<<dim3(4, 4), 256, 0, stream>>>(w_idxd, w_idxc, 0);
  } else {
    for (int b = 0; b < NB; ++b){
      gram_all   <<<dim3(528, 1), 256, 0, stream>>>(w_xt, w_gram, b, 0);
      mirror_all <<<dim3(496*4, 1), 256, 0, stream>>>(w_gram, 0);
      density_all<<<dim3(NT, 1), 256, 0, stream>>>(w_gram, 0, w_sq, w_den, w_vmax, b);
      parent_all <<<dim3(NT, 1), 256, 0, stream>>>(w_gram, 0, w_sq, w_den, w_vmax, w_score, b);
      topk_all   <<<1, 1024, 0, stream>>>(w_score, w_idxd, b);
      assign_all <<<dim3(64, 1), 256, 0, stream>>>(w_gram, 0, w_sq, w_idxd, w_idxc, b);
      override_all<<<dim3(4, 1), 256, 0, stream>>>(w_idxd, w_idxc, b);
    }
  }

  allw_kernel<<<NB*NT/256, 256, 0, stream>>>(w_idxc, w_wt, w_allw);
  normw_kernel<<<NB*NT/256, 256, 0, stream>>>(w_idxc, w_wt, w_allw, w_nw);
  xdown_kernel<<<NB*NT, 256, 0, stream>>>(w_idxc, w_nw, w_xt, w_xdown);
  out0_kernel<<<NB*MC*DOUT/256, 256, 0, stream>>>(w_xdown, out0);
  out12a_kernel<<<NB*NT/256, 256, 0, stream>>>(idxagg, w_idxc, aggw, w_nw, w_awd, w_awdm, out1);
  out2_kernel<<<NB*NT/256, 256, 0, stream>>>(w_awd, w_awdm, out2);

  (void)in_sizes; (void)n_in; (void)out_size;
}

// Round 9
// 1022.976 us; speedup vs baseline: 1.7091x; 1.3138x over previous
//
#include <hip/hip_runtime.h>
#include <math.h>

// B=4, N=4096, C=128, DOUT=256, H=W=64 (conv out 32x32), M=1024, K=5.
// Inputs f32; output buffer f32.
#define NB 4
#define NT 4096
#define CI 128
#define DOUT 256
#define HWI 4096
#define HWO 1024
#define MC 1024
#define EPS_F 1e-6f
#define GSZ 16777216ull          // floats per 4096x4096 G
#define GSZB 67108864ull

// ---------------- workspace layout (bytes) ----------------
static const size_t OFF_XMAP  = 0;                          // 8388608
static const size_t OFF_CNT   = OFF_XMAP + 8388608;
static const size_t OFF_TOT   = OFF_CNT  + 65536;
static const size_t OFF_ALLW  = OFF_TOT  + 65536;
static const size_t OFF_XDOWN = OFF_ALLW + 16384;
static const size_t OFF_VMAX  = OFF_XDOWN + 4194304;
static const size_t OFF_AWDM  = OFF_VMAX + 256;
static const size_t ZERO_BYTES= OFF_AWDM + 256;
static const size_t OFF_YMAP  = ZERO_BYTES;                 // 4194304
static const size_t OFF_XT    = OFF_YMAP + 4194304;         // 16777216
static const size_t OFF_SQ    = OFF_XT + 16777216;
static const size_t OFF_DEN   = OFF_SQ + 65536;
static const size_t OFF_SCORE = OFF_DEN + 65536;
static const size_t OFF_WT    = OFF_SCORE + 65536;
static const size_t OFF_NW    = OFF_WT + 65536;
static const size_t OFF_AWD   = OFF_NW + 65536;
static const size_t OFF_IDXD  = OFF_AWD + 65536;
static const size_t OFF_IDXC  = OFF_IDXD + 16384;
static const size_t OFF_WTR   = OFF_IDXC + 65536;           // 1179648
static const size_t OFF_P     = OFF_WTR + 1179648;          // 18874368
static const size_t OFF_G     = OFF_P + 18874368;           // G buffers start (~45.8 MB)

// ---------------- helpers ----------------
__device__ __forceinline__ float waveSum(float v){
#pragma unroll
  for (int m = 1; m < 64; m <<= 1) v += __shfl_xor(v, m, 64);
  return v;
}
__device__ __forceinline__ float blockSum256(float v, float* red){
  v = waveSum(v);
  int lane = threadIdx.x & 63, wid = threadIdx.x >> 6;
  __syncthreads();
  if (lane == 0) red[wid] = v;
  __syncthreads();
  return red[0] + red[1] + red[2] + red[3];
}
__device__ __forceinline__ void merge5(float& a0, float& a1, float& a2, float& a3, float& a4,
                                       float b0, float b1, float b2, float b3, float b4){
  float l0=a0,l1=a1,l2=a2,l3=fminf(a3,b4),l4=fminf(a4,b3),l5=b2,l6=b1,l7=b0;
  float t0=fminf(l0,l4), t4=fmaxf(l0,l4);
  float t1=fminf(l1,l5), t5=fmaxf(l1,l5);
  float t2=fminf(l2,l6), t6=fmaxf(l2,l6);
  float t3=fminf(l3,l7), t7=fmaxf(l3,l7);
  float u0=fminf(t0,t2), u2=fmaxf(t0,t2);
  float u1=fminf(t1,t3), u3=fmaxf(t1,t3);
  float u4=fminf(t4,t6);
  float u5=fminf(t5,t7);
  a0=fminf(u0,u1); a1=fmaxf(u0,u1);
  a2=fminf(u2,u3); a3=fmaxf(u2,u3);
  a4=fminf(u4,u5);
}
__device__ __forceinline__ void ins5(float v, float& t0, float& t1, float& t2, float& t3, float& t4){
  t4 = fminf(t4, v);
  float a;
  a = fminf(t3,t4); t4 = fmaxf(t3,t4); t3 = a;
  a = fminf(t2,t3); t3 = fmaxf(t2,t3); t2 = a;
  a = fminf(t1,t2); t2 = fmaxf(t1,t2); t1 = a;
  a = fminf(t0,t1); t1 = fmaxf(t0,t1); t0 = a;
}
__device__ __forceinline__ int grid_cell(float lx, float ly, int dim){
  lx = (fminf(fmaxf(lx, -1.f), 1.f) + 1.f) * 0.5f;
  ly = (fminf(fmaxf(ly, -1.f), 1.f) + 1.f) * 0.5f;
  float s = (float)(dim - 1);
  int col = (int)rintf(lx * s); col = min(max(col, 0), dim - 1);
  int row = (int)rintf(ly * s); row = min(max(row, 0), dim - 1);
  return row * dim + col;
}

// ---------------- front-end kernels ----------------
__global__ __launch_bounds__(256) void t2m_scatter(const float* __restrict__ x,
                                                   const float* __restrict__ loc,
                                                   const int* __restrict__ idx_agg,
                                                   float* __restrict__ xmap, float* __restrict__ cnt){
  int lin = blockIdx.x * 256 + threadIdx.x;
  int c  = lin & 127;
  int bn = lin >> 7;
  int b  = bn >> 12;
  float lx = loc[(size_t)bn*2 + 0];
  float ly = loc[(size_t)bn*2 + 1];
  int cell = grid_cell(lx, ly, 64);
  int ia = idx_agg[bn];
  float val = x[((size_t)(b*NT + ia))*CI + c];
  atomicAdd(&xmap[((size_t)(b*HWI + cell))*CI + c], val);
  if (c == 0) atomicAdd(&cnt[b*HWI + cell], 1.0f);
}

__global__ __launch_bounds__(256) void t2m_norm(float* __restrict__ xmap, const float* __restrict__ cnt){
  int lin = blockIdx.x * 256 + threadIdx.x;
  xmap[lin] = xmap[lin] / (cnt[lin >> 7] + EPS_F);
}

__global__ __launch_bounds__(256) void wtrans_kernel(const float* __restrict__ cw, float* __restrict__ wT){
  int lin = blockIdx.x * 256 + threadIdx.x;
  int k = lin >> 8, d = lin & 255;
  wT[lin] = cw[(size_t)d*1152 + k];
}

__global__ __launch_bounds__(256) void im2col_kernel(const float* __restrict__ xmap, float* __restrict__ P){
  int tid = threadIdx.x;
  int c = tid & 127, n2 = tid >> 7;
  int n = blockIdx.x * 2 + n2;
  int b = n >> 10, rem = n & 1023;
  int oh = rem >> 5, ow = rem & 31;
  const float* xb = xmap + (size_t)b*HWI*CI;
  float* prow = P + (size_t)n*1152 + c*9;
#pragma unroll
  for (int kh = 0; kh < 3; ++kh){
    int ih = oh*2 - 1 + kh;
#pragma unroll
    for (int kw = 0; kw < 3; ++kw){
      int iw = ow*2 - 1 + kw;
      bool inb = (ih >= 0) && (ih < 64) && (iw >= 0) && (iw < 64);
      prow[kh*3 + kw] = inb ? xb[(size_t)(ih*64 + iw)*CI + c] : 0.f;
    }
  }
}

__global__ __launch_bounds__(256) void conv_gemm(const float* __restrict__ P,
                                                 const float* __restrict__ wT,
                                                 const float* __restrict__ cb,
                                                 float* __restrict__ ymap){
  __shared__ float As[16][64];
  __shared__ float Bs[16][64];
  int n0 = blockIdx.y * 64, d0 = blockIdx.x * 64;
  int tid = threadIdx.x;
  int tx = tid & 15, ty = tid >> 4;
  int ln = tid & 63, kq = tid >> 6;
  int bkr = tid >> 4, bc4 = (tid & 15) * 4;
  float4 pav = *(const float4*)(P + (size_t)(n0+ln)*1152 + kq*4);
  float4 pbv = *(const float4*)(wT + (size_t)bkr*256 + d0 + bc4);
  float acc[4][4] = {{0}};
  for (int kt = 0; kt < 72; ++kt){
    __syncthreads();
    As[kq*4+0][ln]=pav.x; As[kq*4+1][ln]=pav.y; As[kq*4+2][ln]=pav.z; As[kq*4+3][ln]=pav.w;
    *(float4*)&Bs[bkr][bc4] = pbv;
    __syncthreads();
    if (kt < 71){
      int k2 = (kt + 1) * 16;
      pav = *(const float4*)(P + (size_t)(n0+ln)*1152 + k2 + kq*4);
      pbv = *(const float4*)(wT + (size_t)(k2 + bkr)*256 + d0 + bc4);
    }
#pragma unroll
    for (int k = 0; k < 16; ++k){
      float ar[4], br[4];
      *(float4*)ar = *(const float4*)&As[k][ty*4];
      *(float4*)br = *(const float4*)&Bs[k][tx*4];
#pragma unroll
      for (int r = 0; r < 4; ++r)
#pragma unroll
        for (int s = 0; s < 4; ++s) acc[r][s] += ar[r]*br[s];
    }
  }
  float4 bias = *(const float4*)(cb + d0 + tx*4);
#pragma unroll
  for (int r = 0; r < 4; ++r){
    float4 o;
    o.x = acc[r][0] + bias.x; o.y = acc[r][1] + bias.y;
    o.z = acc[r][2] + bias.z; o.w = acc[r][3] + bias.w;
    *(float4*)(ymap + (size_t)(n0 + ty*4 + r)*DOUT + d0 + tx*4) = o;
  }
}

__global__ __launch_bounds__(256) void tot_kernel(const int* __restrict__ idx_agg,
                                                  const float* __restrict__ aggw,
                                                  float* __restrict__ tot){
  int lin = blockIdx.x * 256 + threadIdx.x;
  int b = lin >> 12;
  atomicAdd(&tot[b*NT + idx_agg[lin]], aggw[lin]);
}

__global__ __launch_bounds__(256) void skip_kernel(const float* __restrict__ x,
                                                   const float* __restrict__ sw,
                                                   float* __restrict__ xt){
  int rowbase = blockIdx.x * 8;
  int d = threadIdx.x;
  __shared__ float xr[8*128];
  ((float4*)xr)[d] = ((const float4*)(x + (size_t)rowbase*CI))[d];
  __syncthreads();
  float acc[8] = {0,0,0,0,0,0,0,0};
  const float* wd = sw + (size_t)d*CI;
  for (int c = 0; c < 128; ++c){
    float w = wd[c];
#pragma unroll
    for (int r = 0; r < 8; ++r) acc[r] += w * xr[r*128 + c];
  }
  for (int r = 0; r < 8; ++r) xt[(size_t)(rowbase + r)*DOUT + d] = acc[r];
}

__global__ __launch_bounds__(256) void m2t_scatter(const float* __restrict__ ymap,
                                                   const float* __restrict__ loc,
                                                   const int* __restrict__ idx_agg,
                                                   const float* __restrict__ aggw,
                                                   const float* __restrict__ tot,
                                                   float* __restrict__ xt){
  int bn = blockIdx.x;
  int d = threadIdx.x;
  int b = bn >> 12;
  float lx = loc[(size_t)bn*2 + 0];
  float ly = loc[(size_t)bn*2 + 1];
  int cell = grid_cell(lx, ly, 32);
  int ia = idx_agg[bn];
  float w = aggw[bn] / (tot[b*NT + ia] + EPS_F);
  float val = ymap[((size_t)(b*HWO + cell))*DOUT + d] * w;
  atomicAdd(&xt[((size_t)(b*NT + ia))*DOUT + d], val);
}

__global__ __launch_bounds__(256) void ln_kernel(float* __restrict__ xt,
                                                 const float* __restrict__ g,
                                                 const float* __restrict__ bta,
                                                 const float* __restrict__ cw,
                                                 const float* __restrict__ cb,
                                                 float* __restrict__ sq, float* __restrict__ wt){
  __shared__ float red[4];
  int row = blockIdx.x;
  int d = threadIdx.x;
  float v = xt[(size_t)row*DOUT + d];
  float mu = blockSum256(v, red) * (1.0f/256.0f);
  float xc = v - mu;
  float var = blockSum256(xc*xc, red) * (1.0f/256.0f);
  float rn = 1.0f / sqrtf(var + 1e-5f);
  float y = xc * rn * g[d] + bta[d];
  xt[(size_t)row*DOUT + d] = y;
  float s2 = blockSum256(y*y, red);
  float cf = blockSum256(y*cw[d], red);
  if (d == 0){ sq[row] = s2; wt[row] = expf(cf + cb[0]); }
}

// ---------------- clustering kernels ----------------
// gram: 64x64 tiles, lower-triangle only (2080 blocks/batch), BK=16, prefetch.
// Off-diagonal blocks also write the transposed tile (LDS bounce) -> no mirror pass.
// k ascending single FMA chain -> bit-identical G values; G[j,i] exact copy.
__global__ __launch_bounds__(256) void gram64(const float* __restrict__ xt, float* __restrict__ G,
                                              int b_base, size_t gstride){
  __shared__ float As[16][64];
  __shared__ float Bs[16][64];
  __shared__ float T[64][65];
  int b = b_base + blockIdx.y;
  const float* A = xt + (size_t)b*NT*DOUT;
  float* Gb = G + (size_t)blockIdx.y*gstride;
  int t = blockIdx.x;
  int ti = 0, accu = 0;
  while (accu + ti + 1 <= t){ accu += ti + 1; ++ti; }
  int tj = t - accu;                 // tj <= ti, 64 tile-rows
  int i0 = ti * 64, j0 = tj * 64;
  int tid = threadIdx.x;
  int li = tid & 63, kq = tid >> 6;  // staging: row li, float4 k-quad kq
  int tx = tid & 15, ty = tid >> 4;
  float4 av = *(const float4*)(A + (size_t)(i0+li)*DOUT + kq*4);
  float4 bv = *(const float4*)(A + (size_t)(j0+li)*DOUT + kq*4);
  float acc[4][4] = {{0}};
  for (int kt = 0; kt < 256; kt += 16){
    __syncthreads();
    As[kq*4+0][li]=av.x; As[kq*4+1][li]=av.y; As[kq*4+2][li]=av.z; As[kq*4+3][li]=av.w;
    Bs[kq*4+0][li]=bv.x; Bs[kq*4+1][li]=bv.y; Bs[kq*4+2][li]=bv.z; Bs[kq*4+3][li]=bv.w;
    __syncthreads();
    if (kt < 240){
      av = *(const float4*)(A + (size_t)(i0+li)*DOUT + kt + 16 + kq*4);
      bv = *(const float4*)(A + (size_t)(j0+li)*DOUT + kt + 16 + kq*4);
    }
#pragma unroll
    for (int k = 0; k < 16; ++k){
      float ar[4], br[4];
      *(float4*)ar = *(const float4*)&As[k][ty*4];
      *(float4*)br = *(const float4*)&Bs[k][tx*4];
#pragma unroll
      for (int r = 0; r < 4; ++r)
#pragma unroll
        for (int s = 0; s < 4; ++s) acc[r][s] += ar[r]*br[s];
    }
  }
#pragma unroll
  for (int r = 0; r < 4; ++r)
    *(float4*)(Gb + (size_t)(i0 + ty*4 + r)*NT + j0 + tx*4) = *(float4*)&acc[r][0];
  if (ti != tj){
    __syncthreads();
#pragma unroll
    for (int r = 0; r < 4; ++r)
#pragma unroll
      for (int s = 0; s < 4; ++s) T[ty*4+r][tx*4+s] = acc[r][s];
    __syncthreads();
#pragma unroll
    for (int r = 0; r < 4; ++r){
      float4 o;
      o.x = T[tx*4+0][ty*4+r]; o.y = T[tx*4+1][ty*4+r];
      o.z = T[tx*4+2][ty*4+r]; o.w = T[tx*4+3][ty*4+r];
      *(float4*)(Gb + (size_t)(j0 + ty*4 + r)*NT + i0 + tx*4) = o;
    }
  }
}

__global__ __launch_bounds__(256) void density_all(const float* __restrict__ G, size_t gstride,
                                                   const float* __restrict__ sq,
                                                   float* __restrict__ density, int* __restrict__ vmax,
                                                   int b_base){
  int b = b_base + blockIdx.y;
  const float* Gb = G + (size_t)blockIdx.y*gstride;
  int i = blockIdx.x;
  int tid = threadIdx.x;
  const float* sqb = sq + b*NT;
  float sqi = sqb[i];
  const float* row = Gb + (size_t)i*NT;
  float t0=INFINITY,t1=INFINITY,t2=INFINITY,t3=INFINITY,t4=INFINITY;
  float vmx = 0.f;
  for (int j = tid*4; j < NT; j += 1024){
    float4 g4 = *(const float4*)(row + j);
    float4 s4 = *(const float4*)(sqb + j);
    float v0 = fmaxf(sqi + s4.x - 2.0f*g4.x, 0.0f);
    float v1 = fmaxf(sqi + s4.y - 2.0f*g4.y, 0.0f);
    float v2 = fmaxf(sqi + s4.z - 2.0f*g4.z, 0.0f);
    float v3 = fmaxf(sqi + s4.w - 2.0f*g4.w, 0.0f);
    vmx = fmaxf(fmaxf(vmx, fmaxf(v0,v1)), fmaxf(v2,v3));
    ins5(v0,t0,t1,t2,t3,t4); ins5(v1,t0,t1,t2,t3,t4);
    ins5(v2,t0,t1,t2,t3,t4); ins5(v3,t0,t1,t2,t3,t4);
  }
#pragma unroll
  for (int m = 1; m < 64; m <<= 1){
    float b0=__shfl_xor(t0,m,64), b1=__shfl_xor(t1,m,64), b2=__shfl_xor(t2,m,64),
          b3=__shfl_xor(t3,m,64), b4=__shfl_xor(t4,m,64);
    merge5(t0,t1,t2,t3,t4,b0,b1,b2,b3,b4);
    vmx = fmaxf(vmx, __shfl_xor(vmx,m,64));
  }
  __shared__ float w5[4][5];
  __shared__ float wm[4];
  int lane = tid & 63, wid = tid >> 6;
  if (lane == 0){ w5[wid][0]=t0; w5[wid][1]=t1; w5[wid][2]=t2; w5[wid][3]=t3; w5[wid][4]=t4; wm[wid]=vmx; }
  __syncthreads();
  if (tid == 0){
    float a0=w5[0][0],a1=w5[0][1],a2=w5[0][2],a3=w5[0][3],a4=w5[0][4];
    for (int w = 1; w < 4; ++w) merge5(a0,a1,a2,a3,a4, w5[w][0],w5[w][1],w5[w][2],w5[w][3],w5[w][4]);
    float d0=sqrtf(a0)*0.0625f, d1=sqrtf(a1)*0.0625f, d2=sqrtf(a2)*0.0625f,
          d3=sqrtf(a3)*0.0625f, d4=sqrtf(a4)*0.0625f;
    float s = d0*d0; s += d1*d1; s += d2*d2; s += d3*d3; s += d4*d4;
    density[b*NT + i] = expf(-(s / 5.0f));
    float vm = fmaxf(fmaxf(wm[0],wm[1]), fmaxf(wm[2],wm[3]));
    atomicMax(vmax + b, __float_as_int(vm));
  }
}

__global__ __launch_bounds__(256) void parent_all(const float* __restrict__ G, size_t gstride,
                                                  const float* __restrict__ sq,
                                                  const float* __restrict__ density, const int* __restrict__ vmax,
                                                  float* __restrict__ score, int b_base){
  int b = b_base + blockIdx.y;
  const float* Gb = G + (size_t)blockIdx.y*gstride;
  int i = blockIdx.x;
  int tid = threadIdx.x;
  const float* sqb = sq + b*NT;
  const float* den = density + b*NT;
  float sqi = sqb[i];
  float di = den[i];
  const float* row = Gb + (size_t)i*NT;
  float minv = INFINITY;
  for (int j = tid*4; j < NT; j += 1024){
    float4 g4 = *(const float4*)(row + j);
    float4 s4 = *(const float4*)(sqb + j);
    float4 d4 = *(const float4*)(den + j);
    float v0 = fmaxf(sqi + s4.x - 2.0f*g4.x, 0.0f);
    float v1 = fmaxf(sqi + s4.y - 2.0f*g4.y, 0.0f);
    float v2 = fmaxf(sqi + s4.z - 2.0f*g4.z, 0.0f);
    float v3 = fmaxf(sqi + s4.w - 2.0f*g4.w, 0.0f);
    minv = fminf(minv, (d4.x > di) ? v0 : INFINITY);
    minv = fminf(minv, (d4.y > di) ? v1 : INFINITY);
    minv = fminf(minv, (d4.z > di) ? v2 : INFINITY);
    minv = fminf(minv, (d4.w > di) ? v3 : INFINITY);
  }
#pragma unroll
  for (int m = 1; m < 64; m <<= 1) minv = fminf(minv, __shfl_xor(minv,m,64));
  __shared__ float wmn[4];
  int lane = tid & 63, wid = tid >> 6;
  if (lane == 0) wmn[wid] = minv;
  __syncthreads();
  if (tid == 0){
    float mv = fminf(fminf(wmn[0],wmn[1]), fminf(wmn[2],wmn[3]));
    float dmax = sqrtf(__int_as_float(vmax[b])) * 0.0625f;
    float dp = isinf(mv) ? dmax : sqrtf(mv) * 0.0625f;
    score[b*NT + i] = dp * di;
  }
}

__global__ __launch_bounds__(1024) void topk_all(const float* __restrict__ score, int* __restrict__ idx_down, int b_base){
  __shared__ float ss[4096];
  __shared__ int ii[4096];
  int b = b_base + blockIdx.x;
  int tid = threadIdx.x;
  for (int t = tid; t < 4096; t += 1024){ ss[t] = score[b*NT + t]; ii[t] = t; }
  for (int k = 2; k <= 4096; k <<= 1){
    for (int j = k >> 1; j > 0; j >>= 1){
      __syncthreads();
      for (int t = tid; t < 4096; t += 1024){
        int p = t ^ j;
        if (p > t){
          float s1 = ss[t], s2 = ss[p];
          int i1 = ii[t], i2 = ii[p];
          bool lt = (s1 > s2) || (s1 == s2 && i1 < i2);
          bool up = ((t & k) == 0);
          if (up ? !lt : lt){ ss[t]=s2; ss[p]=s1; ii[t]=i2; ii[p]=i1; }
        }
      }
    }
  }
  __syncthreads();
  if (tid < MC) idx_down[b*MC + tid] = ii[tid];
}

__global__ __launch_bounds__(256) void assign_all(const float* __restrict__ G, size_t gstride,
                                                  const float* __restrict__ sq,
                                                  const int* __restrict__ idx_down, int* __restrict__ idx_cluster,
                                                  int b_base){
  int b = b_base + blockIdx.y;
  const float* Gb = G + (size_t)blockIdx.y*gstride;
  int jl = threadIdx.x & 63, mq = threadIdx.x >> 6;
  int j = blockIdx.x * 64 + jl;
  const float* sqb = sq + b*NT;
  float sqj = sqb[j];
  const int* idb = idx_down + b*MC;
  float bestd = INFINITY; int bestm = 0x7fffffff;
  for (int m = mq*256; m < mq*256 + 256; ++m){
    int im = idb[m];
    float g = Gb[(size_t)im*NT + j];
    float v = fmaxf(sqb[im] + sqj - 2.0f*g, 0.0f);
    float d = sqrtf(v) * 0.0625f;
    if (d < bestd){ bestd = d; bestm = m; }
  }
  __shared__ float ld[4][64];
  __shared__ int lm[4][64];
  ld[mq][jl] = bestd; lm[mq][jl] = bestm;
  __syncthreads();
  if (mq == 0){
    for (int q = 1; q < 4; ++q){
      float d2 = ld[q][jl]; int m2 = lm[q][jl];
      if (d2 < bestd || (d2 == bestd && m2 < bestm)){ bestd = d2; bestm = m2; }
    }
    idx_cluster[b*NT + j] = bestm;
  }
}

__global__ __launch_bounds__(256) void override_all(const int* __restrict__ idx_down, int* __restrict__ idx_cluster,
                                                    int b_base){
  int b = b_base + blockIdx.y;
  int m = blockIdx.x * 256 + threadIdx.x;
  if (m < MC) idx_cluster[b*NT + idx_down[b*MC + m]] = m;
}

// ---------------- merge + outputs ----------------
__global__ __launch_bounds__(256) void allw_kernel(const int* __restrict__ idx_cluster, const float* __restrict__ wt,
                                                   float* __restrict__ allw){
  int lin = blockIdx.x * 256 + threadIdx.x;
  int b = lin >> 12;
  atomicAdd(&allw[b*MC + idx_cluster[lin]], wt[lin]);
}
__global__ __launch_bounds__(256) void normw_kernel(const int* __restrict__ idx_cluster, const float* __restrict__ wt,
                                                    const float* __restrict__ allw, float* __restrict__ nw){
  int lin = blockIdx.x * 256 + threadIdx.x;
  int b = lin >> 12;
  nw[lin] = wt[lin] / (allw[b*MC + idx_cluster[lin]] + EPS_F);
}
__global__ __launch_bounds__(256) void xdown_kernel(const int* __restrict__ idx_cluster, const float* __restrict__ nw,
                                                    const float* __restrict__ xt, float* __restrict__ xdown){
  int bn = blockIdx.x;
  int d = threadIdx.x;
  int b = bn >> 12;
  int ic = idx_cluster[bn];
  float v = xt[(size_t)bn*DOUT + d] * nw[bn];
  atomicAdd(&xdown[((size_t)(b*MC + ic))*DOUT + d], v);
}
__global__ __launch_bounds__(256) void out0_kernel(const float* __restrict__ xdown, float* __restrict__ out){
  int lin = blockIdx.x * 256 + threadIdx.x;
  out[lin] = xdown[lin];
}
__global__ __launch_bounds__(256) void out12a_kernel(const int* __restrict__ idx_agg, const int* __restrict__ idx_cluster,
                                                     const float* __restrict__ aggw, const float* __restrict__ nw,
                                                     float* __restrict__ awd, int* __restrict__ awdmax,
                                                     float* __restrict__ out1){
  __shared__ float red[4];
  int lin = blockIdx.x * 256 + threadIdx.x;
  int b = lin >> 12;
  int ia = idx_agg[lin];
  int ic = idx_cluster[b*NT + ia];
  out1[lin] = (float)ic;
  float v = aggw[lin] * nw[b*NT + ia];
  awd[lin] = v;
  float wv = v;
#pragma unroll
  for (int m = 1; m < 64; m <<= 1) wv = fmaxf(wv, __shfl_xor(wv, m, 64));
  int lane = threadIdx.x & 63, wid = threadIdx.x >> 6;
  if (lane == 0) red[wid] = wv;
  __syncthreads();
  if (threadIdx.x == 0){
    float bm = fmaxf(fmaxf(red[0], red[1]), fmaxf(red[2], red[3]));
    atomicMax(&awdmax[b], __float_as_int(bm));
  }
}
__global__ __launch_bounds__(256) void out2_kernel(const float* __restrict__ awd, const int* __restrict__ awdmax,
                                                   float* __restrict__ out2){
  int lin = blockIdx.x * 256 + threadIdx.x;
  int b = lin >> 12;
  out2[lin] = awd[lin] / __int_as_float(awdmax[b]);
}

extern "C" void kernel_launch(void* const* d_in, const int* in_sizes, int n_in,
                              void* d_out, int out_size, void* d_ws, size_t ws_size,
                              hipStream_t stream) {
  const float* x      = (const float*)d_in[0];
  const float* loc    = (const float*)d_in[1];
  const int*   idxagg = (const int*)d_in[2];
  const float* aggw   = (const float*)d_in[3];
  const float* convw  = (const float*)d_in[7];
  const float* convb  = (const float*)d_in[8];
  const float* skipw  = (const float*)d_in[9];
  const float* lng    = (const float*)d_in[10];
  const float* lnb    = (const float*)d_in[11];
  const float* confw  = (const float*)d_in[12];
  const float* confb  = (const float*)d_in[13];

  char* ws = (char*)d_ws;
  float* w_xmap  = (float*)(ws + OFF_XMAP);
  float* w_cnt   = (float*)(ws + OFF_CNT);
  float* w_tot   = (float*)(ws + OFF_TOT);
  float* w_allw  = (float*)(ws + OFF_ALLW);
  float* w_xdown = (float*)(ws + OFF_XDOWN);
  int*   w_vmax  = (int*)  (ws + OFF_VMAX);
  int*   w_awdm  = (int*)  (ws + OFF_AWDM);
  float* w_ymap  = (float*)(ws + OFF_YMAP);
  float* w_xt    = (float*)(ws + OFF_XT);
  float* w_sq    = (float*)(ws + OFF_SQ);
  float* w_den   = (float*)(ws + OFF_DEN);
  float* w_score = (float*)(ws + OFF_SCORE);
  float* w_wt    = (float*)(ws + OFF_WT);
  float* w_nw    = (float*)(ws + OFF_NW);
  float* w_awd   = (float*)(ws + OFF_AWD);
  int*   w_idxd  = (int*)  (ws + OFF_IDXD);
  int*   w_idxc  = (int*)  (ws + OFF_IDXC);
  float* w_wtr   = (float*)(ws + OFF_WTR);
  float* w_p     = (float*)(ws + OFF_P);
  float* w_g     = (float*)(ws + OFF_G);

  // largest batch-group that fits (ws_size constant per harness -> graph-safe)
  int gcount = 1;
  for (int k = 4; k >= 1; --k){
    if (OFF_G + (size_t)k*GSZB <= ws_size){ gcount = k; break; }
  }

  float* out0 = (float*)d_out;
  float* out1 = out0 + NB*MC*DOUT;
  float* out2 = out1 + NB*NT;

  hipMemsetAsync(ws, 0, ZERO_BYTES, stream);

  t2m_scatter<<<NB*NT*CI/256, 256, 0, stream>>>(x, loc, idxagg, w_xmap, w_cnt);
  t2m_norm<<<NB*HWI*CI/256, 256, 0, stream>>>(w_xmap, w_cnt);
  wtrans_kernel<<<1152, 256, 0, stream>>>(convw, w_wtr);
  im2col_kernel<<<2048, 256, 0, stream>>>(w_xmap, w_p);
  conv_gemm<<<dim3(4, 64), 256, 0, stream>>>(w_p, w_wtr, convb, w_ymap);
  tot_kernel<<<NB*NT/256, 256, 0, stream>>>(idxagg, aggw, w_tot);
  skip_kernel<<<NB*NT/8, 256, 0, stream>>>(x, skipw, w_xt);
  m2t_scatter<<<NB*NT, 256, 0, stream>>>(w_ymap, loc, idxagg, aggw, w_tot, w_xt);
  ln_kernel<<<NB*NT, 256, 0, stream>>>(w_xt, lng, lnb, confw, confb, w_sq, w_wt);

  for (int g0 = 0; g0 < NB; g0 += gcount){
    int gy = (NB - g0 < gcount) ? (NB - g0) : gcount;
    gram64     <<<dim3(2080, gy), 256, 0, stream>>>(w_xt, w_g, g0, GSZ);
    density_all<<<dim3(NT, gy), 256, 0, stream>>>(w_g, GSZ, w_sq, w_den, w_vmax, g0);
    parent_all <<<dim3(NT, gy), 256, 0, stream>>>(w_g, GSZ, w_sq, w_den, w_vmax, w_score, g0);
    topk_all   <<<gy, 1024, 0, stream>>>(w_score, w_idxd, g0);
    assign_all <<<dim3(64, gy), 256, 0, stream>>>(w_g, GSZ, w_sq, w_idxd, w_idxc, g0);
    override_all<<<dim3(4, gy), 256, 0, stream>>>(w_idxd, w_idxc, g0);
  }

  allw_kernel<<<NB*NT/256, 256, 0, stream>>>(w_idxc, w_wt, w_allw);
  normw_kernel<<<NB*NT/256, 256, 0, stream>>>(w_idxc, w_wt, w_allw, w_nw);
  xdown_kernel<<<NB*NT, 256, 0, stream>>>(w_idxc, w_nw, w_xt, w_xdown);
  out0_kernel<<<NB*MC*DOUT/256, 256, 0, stream>>>(w_xdown, out0);
  out12a_kernel<<<NB*NT/256, 256, 0, stream>>>(idxagg, w_idxc, aggw, w_nw, w_awd, w_awdm, out1);
  out2_kernel<<<NB*NT/256, 256, 0, stream>>>(w_awd, w_awdm, out2);

  (void)in_sizes; (void)n_in; (void)out_size;
}

// Round 10
// 935.379 us; speedup vs baseline: 1.8692x; 1.0936x over previous
//
#include <hip/hip_runtime.h>
#include <math.h>

// B=4, N=4096, C=128, DOUT=256, H=W=64 (conv out 32x32), M=1024, K=5.
// Inputs f32; output buffer f32.
#define NB 4
#define NT 4096
#define CI 128
#define DOUT 256
#define HWI 4096
#define HWO 1024
#define MC 1024
#define EPS_F 1e-6f
#define GSZ 16777216ull
#define GSZB 67108864ull

// ---------------- workspace layout (bytes) ----------------
// zero zone:
static const size_t OFF_XMAP  = 0;                          // 8388608
static const size_t OFF_CNT   = OFF_XMAP + 8388608;         // 65536
static const size_t OFF_TOT   = OFF_CNT  + 65536;           // 65536
static const size_t OFF_ALLW  = OFF_TOT  + 65536;           // 16384
static const size_t OFF_VMAX  = OFF_ALLW + 16384;           // 256
static const size_t OFF_AWDM  = OFF_VMAX + 256;             // 256
static const size_t ZERO_BYTES= OFF_AWDM + 256;
// non-zeroed:
static const size_t OFF_YMAP  = ZERO_BYTES;                 // 4194304
static const size_t OFF_XT    = OFF_YMAP + 4194304;         // 16777216
static const size_t OFF_SQ    = OFF_XT + 16777216;          // 65536
static const size_t OFF_DEN   = OFF_SQ + 65536;
static const size_t OFF_SCORE = OFF_DEN + 65536;
static const size_t OFF_WT    = OFF_SCORE + 65536;
static const size_t OFF_NW    = OFF_WT + 65536;
static const size_t OFF_AWD   = OFF_NW + 65536;
static const size_t OFF_IDXD  = OFF_AWD + 65536;            // 16384
static const size_t OFF_IDXC  = OFF_IDXD + 16384;           // 65536
static const size_t OFF_INV   = OFF_IDXC + 65536;           // 65536 (init in topk)
static const size_t OFF_WTR   = OFF_INV + 65536;            // 1179648
static const size_t OFF_P     = OFF_WTR + 1179648;          // 18874368
static const size_t OFF_G     = OFF_P + 18874368;           // ~50.1 MB; +3*64MB = 239.8 MiB

// ---------------- helpers ----------------
__device__ __forceinline__ float waveSum(float v){
#pragma unroll
  for (int m = 1; m < 64; m <<= 1) v += __shfl_xor(v, m, 64);
  return v;
}
__device__ __forceinline__ float blockSum256(float v, float* red){
  v = waveSum(v);
  int lane = threadIdx.x & 63, wid = threadIdx.x >> 6;
  __syncthreads();
  if (lane == 0) red[wid] = v;
  __syncthreads();
  return red[0] + red[1] + red[2] + red[3];
}
__device__ __forceinline__ void merge5(float& a0, float& a1, float& a2, float& a3, float& a4,
                                       float b0, float b1, float b2, float b3, float b4){
  float l0=a0,l1=a1,l2=a2,l3=fminf(a3,b4),l4=fminf(a4,b3),l5=b2,l6=b1,l7=b0;
  float t0=fminf(l0,l4), t4=fmaxf(l0,l4);
  float t1=fminf(l1,l5), t5=fmaxf(l1,l5);
  float t2=fminf(l2,l6), t6=fmaxf(l2,l6);
  float t3=fminf(l3,l7), t7=fmaxf(l3,l7);
  float u0=fminf(t0,t2), u2=fmaxf(t0,t2);
  float u1=fminf(t1,t3), u3=fmaxf(t1,t3);
  float u4=fminf(t4,t6);
  float u5=fminf(t5,t7);
  a0=fminf(u0,u1); a1=fmaxf(u0,u1);
  a2=fminf(u2,u3); a3=fmaxf(u2,u3);
  a4=fminf(u4,u5);
}
__device__ __forceinline__ void ins5(float v, float& t0, float& t1, float& t2, float& t3, float& t4){
  t4 = fminf(t4, v);
  float a;
  a = fminf(t3,t4); t4 = fmaxf(t3,t4); t3 = a;
  a = fminf(t2,t3); t3 = fmaxf(t2,t3); t2 = a;
  a = fminf(t1,t2); t2 = fmaxf(t1,t2); t1 = a;
  a = fminf(t0,t1); t1 = fmaxf(t0,t1); t0 = a;
}
__device__ __forceinline__ int grid_cell(float lx, float ly, int dim){
  lx = (fminf(fmaxf(lx, -1.f), 1.f) + 1.f) * 0.5f;
  ly = (fminf(fmaxf(ly, -1.f), 1.f) + 1.f) * 0.5f;
  float s = (float)(dim - 1);
  int col = (int)rintf(lx * s); col = min(max(col, 0), dim - 1);
  int row = (int)rintf(ly * s); row = min(max(row, 0), dim - 1);
  return row * dim + col;
}

// ---------------- front-end kernels ----------------
// token2map scatter + (fused) agg_weight segment-sum
__global__ __launch_bounds__(256) void t2m_scatter(const float* __restrict__ x,
                                                   const float* __restrict__ loc,
                                                   const int* __restrict__ idx_agg,
                                                   const float* __restrict__ aggw,
                                                   float* __restrict__ xmap, float* __restrict__ cnt,
                                                   float* __restrict__ tot){
  int lin = blockIdx.x * 256 + threadIdx.x;
  int c  = lin & 127;
  int bn = lin >> 7;
  int b  = bn >> 12;
  float lx = loc[(size_t)bn*2 + 0];
  float ly = loc[(size_t)bn*2 + 1];
  int cell = grid_cell(lx, ly, 64);
  int ia = idx_agg[bn];
  float val = x[((size_t)(b*NT + ia))*CI + c];
  atomicAdd(&xmap[((size_t)(b*HWI + cell))*CI + c], val);
  if (c == 0) atomicAdd(&cnt[b*HWI + cell], 1.0f);
  if (c == 1) atomicAdd(&tot[b*NT + ia], aggw[bn]);
}

__global__ __launch_bounds__(256) void wtrans_kernel(const float* __restrict__ cw, float* __restrict__ wT){
  int lin = blockIdx.x * 256 + threadIdx.x;
  int k = lin >> 8, d = lin & 255;
  wT[lin] = cw[(size_t)d*1152 + k];
}

// im2col with fused per-cell normalization: P[n][k] = xmap_cell_c / (cnt_cell + eps)
__global__ __launch_bounds__(256) void im2col_kernel(const float* __restrict__ xmap,
                                                     const float* __restrict__ cnt,
                                                     float* __restrict__ P){
  int tid = threadIdx.x;
  int c = tid & 127, n2 = tid >> 7;
  int n = blockIdx.x * 2 + n2;
  int b = n >> 10, rem = n & 1023;
  int oh = rem >> 5, ow = rem & 31;
  const float* xb = xmap + (size_t)b*HWI*CI;
  const float* cb_ = cnt + (size_t)b*HWI;
  float* prow = P + (size_t)n*1152 + c*9;
#pragma unroll
  for (int kh = 0; kh < 3; ++kh){
    int ih = oh*2 - 1 + kh;
#pragma unroll
    for (int kw = 0; kw < 3; ++kw){
      int iw = ow*2 - 1 + kw;
      bool inb = (ih >= 0) && (ih < 64) && (iw >= 0) && (iw < 64);
      float v = 0.f;
      if (inb){
        int cell = ih*64 + iw;
        v = xb[(size_t)cell*CI + c] / (cb_[cell] + EPS_F);
      }
      prow[kh*3 + kw] = v;
    }
  }
}

__global__ __launch_bounds__(256) void conv_gemm(const float* __restrict__ P,
                                                 const float* __restrict__ wT,
                                                 const float* __restrict__ cb,
                                                 float* __restrict__ ymap){
  __shared__ float As[16][64];
  __shared__ float Bs[16][64];
  int n0 = blockIdx.y * 64, d0 = blockIdx.x * 64;
  int tid = threadIdx.x;
  int tx = tid & 15, ty = tid >> 4;
  int ln = tid & 63, kq = tid >> 6;
  int bkr = tid >> 4, bc4 = (tid & 15) * 4;
  float4 pav = *(const float4*)(P + (size_t)(n0+ln)*1152 + kq*4);
  float4 pbv = *(const float4*)(wT + (size_t)bkr*256 + d0 + bc4);
  float acc[4][4] = {{0}};
  for (int kt = 0; kt < 72; ++kt){
    __syncthreads();
    As[kq*4+0][ln]=pav.x; As[kq*4+1][ln]=pav.y; As[kq*4+2][ln]=pav.z; As[kq*4+3][ln]=pav.w;
    *(float4*)&Bs[bkr][bc4] = pbv;
    __syncthreads();
    if (kt < 71){
      int k2 = (kt + 1) * 16;
      pav = *(const float4*)(P + (size_t)(n0+ln)*1152 + k2 + kq*4);
      pbv = *(const float4*)(wT + (size_t)(k2 + bkr)*256 + d0 + bc4);
    }
#pragma unroll
    for (int k = 0; k < 16; ++k){
      float ar[4], br[4];
      *(float4*)ar = *(const float4*)&As[k][ty*4];
      *(float4*)br = *(const float4*)&Bs[k][tx*4];
#pragma unroll
      for (int r = 0; r < 4; ++r)
#pragma unroll
        for (int s = 0; s < 4; ++s) acc[r][s] += ar[r]*br[s];
    }
  }
  float4 bias = *(const float4*)(cb + d0 + tx*4);
#pragma unroll
  for (int r = 0; r < 4; ++r){
    float4 o;
    o.x = acc[r][0] + bias.x; o.y = acc[r][1] + bias.y;
    o.z = acc[r][2] + bias.z; o.w = acc[r][3] + bias.w;
    *(float4*)(ymap + (size_t)(n0 + ty*4 + r)*DOUT + d0 + tx*4) = o;
  }
}

__global__ __launch_bounds__(256) void skip_kernel(const float* __restrict__ x,
                                                   const float* __restrict__ sw,
                                                   float* __restrict__ xt){
  int rowbase = blockIdx.x * 8;
  int d = threadIdx.x;
  __shared__ float xr[8*128];
  ((float4*)xr)[d] = ((const float4*)(x + (size_t)rowbase*CI))[d];
  __syncthreads();
  float acc[8] = {0,0,0,0,0,0,0,0};
  const float* wd = sw + (size_t)d*CI;
  for (int c = 0; c < 128; ++c){
    float w = wd[c];
#pragma unroll
    for (int r = 0; r < 8; ++r) acc[r] += w * xr[r*128 + c];
  }
  for (int r = 0; r < 8; ++r) xt[(size_t)(rowbase + r)*DOUT + d] = acc[r];
}

__global__ __launch_bounds__(256) void m2t_scatter(const float* __restrict__ ymap,
                                                   const float* __restrict__ loc,
                                                   const int* __restrict__ idx_agg,
                                                   const float* __restrict__ aggw,
                                                   const float* __restrict__ tot,
                                                   float* __restrict__ xt){
  int bn = blockIdx.x;
  int d = threadIdx.x;
  int b = bn >> 12;
  float lx = loc[(size_t)bn*2 + 0];
  float ly = loc[(size_t)bn*2 + 1];
  int cell = grid_cell(lx, ly, 32);
  int ia = idx_agg[bn];
  float w = aggw[bn] / (tot[b*NT + ia] + EPS_F);
  float val = ymap[((size_t)(b*HWO + cell))*DOUT + d] * w;
  atomicAdd(&xt[((size_t)(b*NT + ia))*DOUT + d], val);
}

__global__ __launch_bounds__(256) void ln_kernel(float* __restrict__ xt,
                                                 const float* __restrict__ g,
                                                 const float* __restrict__ bta,
                                                 const float* __restrict__ cw,
                                                 const float* __restrict__ cb,
                                                 float* __restrict__ sq, float* __restrict__ wt){
  __shared__ float red[4];
  int row = blockIdx.x;
  int d = threadIdx.x;
  float v = xt[(size_t)row*DOUT + d];
  float mu = blockSum256(v, red) * (1.0f/256.0f);
  float xc = v - mu;
  float var = blockSum256(xc*xc, red) * (1.0f/256.0f);
  float rn = 1.0f / sqrtf(var + 1e-5f);
  float y = xc * rn * g[d] + bta[d];
  xt[(size_t)row*DOUT + d] = y;
  float s2 = blockSum256(y*y, red);
  float cf = blockSum256(y*cw[d], red);
  if (d == 0){ sq[row] = s2; wt[row] = expf(cf + cb[0]); }
}

// ---------------- clustering ----------------
// gram: 64x64 lower-triangle tiles (2080/batch), BK=16, prefetch.
// LDS union: T transpose buffer aliases As/Bs (16.6 KB total -> 8 blocks/CU).
__global__ __launch_bounds__(256) void gram64(const float* __restrict__ xt, float* __restrict__ G,
                                              int b_base, size_t gstride){
  __shared__ float smem[4160];           // As[16][64] @0, Bs[16][64] @1024, T[64][65] aliases all
  int b = b_base + blockIdx.y;
  const float* A = xt + (size_t)b*NT*DOUT;
  float* Gb = G + (size_t)blockIdx.y*gstride;
  int t = blockIdx.x;
  int ti = 0, accu = 0;
  while (accu + ti + 1 <= t){ accu += ti + 1; ++ti; }
  int tj = t - accu;
  int i0 = ti * 64, j0 = tj * 64;
  int tid = threadIdx.x;
  int li = tid & 63, kq = tid >> 6;
  int tx = tid & 15, ty = tid >> 4;
  float4 av = *(const float4*)(A + (size_t)(i0+li)*DOUT + kq*4);
  float4 bv = *(const float4*)(A + (size_t)(j0+li)*DOUT + kq*4);
  float acc[4][4] = {{0}};
  for (int kt = 0; kt < 256; kt += 16){
    __syncthreads();
    smem[(kq*4+0)*64 + li]=av.x; smem[(kq*4+1)*64 + li]=av.y;
    smem[(kq*4+2)*64 + li]=av.z; smem[(kq*4+3)*64 + li]=av.w;
    smem[1024 + (kq*4+0)*64 + li]=bv.x; smem[1024 + (kq*4+1)*64 + li]=bv.y;
    smem[1024 + (kq*4+2)*64 + li]=bv.z; smem[1024 + (kq*4+3)*64 + li]=bv.w;
    __syncthreads();
    if (kt < 240){
      av = *(const float4*)(A + (size_t)(i0+li)*DOUT + kt + 16 + kq*4);
      bv = *(const float4*)(A + (size_t)(j0+li)*DOUT + kt + 16 + kq*4);
    }
#pragma unroll
    for (int k = 0; k < 16; ++k){
      float ar[4], br[4];
      *(float4*)ar = *(const float4*)&smem[k*64 + ty*4];
      *(float4*)br = *(const float4*)&smem[1024 + k*64 + tx*4];
#pragma unroll
      for (int r = 0; r < 4; ++r)
#pragma unroll
        for (int s = 0; s < 4; ++s) acc[r][s] += ar[r]*br[s];
    }
  }
#pragma unroll
  for (int r = 0; r < 4; ++r)
    *(float4*)(Gb + (size_t)(i0 + ty*4 + r)*NT + j0 + tx*4) = *(float4*)&acc[r][0];
  if (ti != tj){
    __syncthreads();
#pragma unroll
    for (int r = 0; r < 4; ++r)
#pragma unroll
      for (int s = 0; s < 4; ++s) smem[(ty*4+r)*65 + tx*4+s] = acc[r][s];
    __syncthreads();
#pragma unroll
    for (int r = 0; r < 4; ++r){
      float4 o;
      o.x = smem[(tx*4+0)*65 + ty*4+r]; o.y = smem[(tx*4+1)*65 + ty*4+r];
      o.z = smem[(tx*4+2)*65 + ty*4+r]; o.w = smem[(tx*4+3)*65 + ty*4+r];
      *(float4*)(Gb + (size_t)(j0 + ty*4 + r)*NT + i0 + tx*4) = o;
    }
  }
}

__global__ __launch_bounds__(256) void density_all(const float* __restrict__ G, size_t gstride,
                                                   const float* __restrict__ sq,
                                                   float* __restrict__ density, int* __restrict__ vmax,
                                                   int b_base){
  int b = b_base + blockIdx.y;
  const float* Gb = G + (size_t)blockIdx.y*gstride;
  int i = blockIdx.x;
  int tid = threadIdx.x;
  const float* sqb = sq + b*NT;
  float sqi = sqb[i];
  const float* row = Gb + (size_t)i*NT;
  float t0=INFINITY,t1=INFINITY,t2=INFINITY,t3=INFINITY,t4=INFINITY;
  float vmx = 0.f;
  for (int j = tid*4; j < NT; j += 1024){
    float4 g4 = *(const float4*)(row + j);
    float4 s4 = *(const float4*)(sqb + j);
    float v0 = fmaxf(sqi + s4.x - 2.0f*g4.x, 0.0f);
    float v1 = fmaxf(sqi + s4.y - 2.0f*g4.y, 0.0f);
    float v2 = fmaxf(sqi + s4.z - 2.0f*g4.z, 0.0f);
    float v3 = fmaxf(sqi + s4.w - 2.0f*g4.w, 0.0f);
    vmx = fmaxf(fmaxf(vmx, fmaxf(v0,v1)), fmaxf(v2,v3));
    ins5(v0,t0,t1,t2,t3,t4); ins5(v1,t0,t1,t2,t3,t4);
    ins5(v2,t0,t1,t2,t3,t4); ins5(v3,t0,t1,t2,t3,t4);
  }
#pragma unroll
  for (int m = 1; m < 64; m <<= 1){
    float b0=__shfl_xor(t0,m,64), b1=__shfl_xor(t1,m,64), b2=__shfl_xor(t2,m,64),
          b3=__shfl_xor(t3,m,64), b4=__shfl_xor(t4,m,64);
    merge5(t0,t1,t2,t3,t4,b0,b1,b2,b3,b4);
    vmx = fmaxf(vmx, __shfl_xor(vmx,m,64));
  }
  __shared__ float w5[4][5];
  __shared__ float wm[4];
  int lane = tid & 63, wid = tid >> 6;
  if (lane == 0){ w5[wid][0]=t0; w5[wid][1]=t1; w5[wid][2]=t2; w5[wid][3]=t3; w5[wid][4]=t4; wm[wid]=vmx; }
  __syncthreads();
  if (tid == 0){
    float a0=w5[0][0],a1=w5[0][1],a2=w5[0][2],a3=w5[0][3],a4=w5[0][4];
    for (int w = 1; w < 4; ++w) merge5(a0,a1,a2,a3,a4, w5[w][0],w5[w][1],w5[w][2],w5[w][3],w5[w][4]);
    float d0=sqrtf(a0)*0.0625f, d1=sqrtf(a1)*0.0625f, d2=sqrtf(a2)*0.0625f,
          d3=sqrtf(a3)*0.0625f, d4=sqrtf(a4)*0.0625f;
    float s = d0*d0; s += d1*d1; s += d2*d2; s += d3*d3; s += d4*d4;
    density[b*NT + i] = expf(-(s / 5.0f));
    float vm = fmaxf(fmaxf(wm[0],wm[1]), fmaxf(wm[2],wm[3]));
    atomicMax(vmax + b, __float_as_int(vm));
  }
}

__global__ __launch_bounds__(256) void parent_all(const float* __restrict__ G, size_t gstride,
                                                  const float* __restrict__ sq,
                                                  const float* __restrict__ density, const int* __restrict__ vmax,
                                                  float* __restrict__ score, int b_base){
  int b = b_base + blockIdx.y;
  const float* Gb = G + (size_t)blockIdx.y*gstride;
  int i = blockIdx.x;
  int tid = threadIdx.x;
  const float* sqb = sq + b*NT;
  const float* den = density + b*NT;
  float sqi = sqb[i];
  float di = den[i];
  const float* row = Gb + (size_t)i*NT;
  float minv = INFINITY;
  for (int j = tid*4; j < NT; j += 1024){
    float4 g4 = *(const float4*)(row + j);
    float4 s4 = *(const float4*)(sqb + j);
    float4 d4 = *(const float4*)(den + j);
    float v0 = fmaxf(sqi + s4.x - 2.0f*g4.x, 0.0f);
    float v1 = fmaxf(sqi + s4.y - 2.0f*g4.y, 0.0f);
    float v2 = fmaxf(sqi + s4.z - 2.0f*g4.z, 0.0f);
    float v3 = fmaxf(sqi + s4.w - 2.0f*g4.w, 0.0f);
    minv = fminf(minv, (d4.x > di) ? v0 : INFINITY);
    minv = fminf(minv, (d4.y > di) ? v1 : INFINITY);
    minv = fminf(minv, (d4.z > di) ? v2 : INFINITY);
    minv = fminf(minv, (d4.w > di) ? v3 : INFINITY);
  }
#pragma unroll
  for (int m = 1; m < 64; m <<= 1) minv = fminf(minv, __shfl_xor(minv,m,64));
  __shared__ float wmn[4];
  int lane = tid & 63, wid = tid >> 6;
  if (lane == 0) wmn[wid] = minv;
  __syncthreads();
  if (tid == 0){
    float mv = fminf(fminf(wmn[0],wmn[1]), fminf(wmn[2],wmn[3]));
    float dmax = sqrtf(__int_as_float(vmax[b])) * 0.0625f;
    float dp = isinf(mv) ? dmax : sqrtf(mv) * 0.0625f;
    score[b*NT + i] = dp * di;
  }
}

// bitonic sort 4096 (score desc, idx asc); 2 pairs/thread/step; also builds inverse map.
__global__ __launch_bounds__(1024) void topk_all(const float* __restrict__ score, int* __restrict__ idx_down,
                                                 int* __restrict__ inv, int b_base){
  __shared__ float ss[4096];
  __shared__ int ii[4096];
  int b = b_base + blockIdx.x;
  int tid = threadIdx.x;
  for (int t = tid; t < 4096; t += 1024){ ss[t] = score[b*NT + t]; ii[t] = t; inv[b*NT + t] = -1; }
  for (int k = 2; k <= 4096; k <<= 1){
    for (int j = k >> 1; j > 0; j >>= 1){
      __syncthreads();
#pragma unroll
      for (int vv = 0; vv < 2; ++vv){
        int v = tid + vv*1024;
        int i1 = 2*v - (v & (j-1));
        int i2 = i1 + j;
        float s1 = ss[i1], s2 = ss[i2];
        int a1 = ii[i1], a2 = ii[i2];
        bool lt = (s1 > s2) || (s1 == s2 && a1 < a2);
        bool up = ((i1 & k) == 0);
        if (up ? !lt : lt){ ss[i1]=s2; ss[i2]=s1; ii[i1]=a2; ii[i2]=a1; }
      }
    }
  }
  __syncthreads();
  if (tid < MC){
    int tok = ii[tid];
    idx_down[b*MC + tid] = tok;
    inv[b*NT + tok] = tid;
  }
}

// nearest-center assign + (fused) override via inv + (fused) allw atomic
__global__ __launch_bounds__(256) void assign_all(const float* __restrict__ G, size_t gstride,
                                                  const float* __restrict__ sq,
                                                  const int* __restrict__ idx_down, const int* __restrict__ inv,
                                                  const float* __restrict__ wt,
                                                  int* __restrict__ idx_cluster, float* __restrict__ allw,
                                                  int b_base){
  int b = b_base + blockIdx.y;
  const float* Gb = G + (size_t)blockIdx.y*gstride;
  int jl = threadIdx.x & 63, mq = threadIdx.x >> 6;
  int j = blockIdx.x * 64 + jl;
  const float* sqb = sq + b*NT;
  float sqj = sqb[j];
  const int* idb = idx_down + b*MC;
  float bestd = INFINITY; int bestm = 0x7fffffff;
  for (int m = mq*256; m < mq*256 + 256; ++m){
    int im = idb[m];
    float g = Gb[(size_t)im*NT + j];
    float v = fmaxf(sqb[im] + sqj - 2.0f*g, 0.0f);
    float d = sqrtf(v) * 0.0625f;
    if (d < bestd){ bestd = d; bestm = m; }
  }
  __shared__ float ld[4][64];
  __shared__ int lm[4][64];
  ld[mq][jl] = bestd; lm[mq][jl] = bestm;
  __syncthreads();
  if (mq == 0){
    for (int q = 1; q < 4; ++q){
      float d2 = ld[q][jl]; int m2 = lm[q][jl];
      if (d2 < bestd || (d2 == bestd && m2 < bestm)){ bestd = d2; bestm = m2; }
    }
    int iv = inv[b*NT + j];
    int final_m = (iv >= 0) ? iv : bestm;
    idx_cluster[b*NT + j] = final_m;
    atomicAdd(&allw[b*MC + final_m], wt[b*NT + j]);
  }
}

// ---------------- merge + outputs ----------------
__global__ __launch_bounds__(256) void normw_kernel(const int* __restrict__ idx_cluster, const float* __restrict__ wt,
                                                    const float* __restrict__ allw, float* __restrict__ nw){
  int lin = blockIdx.x * 256 + threadIdx.x;
  int b = lin >> 12;
  nw[lin] = wt[lin] / (allw[b*MC + idx_cluster[lin]] + EPS_F);
}
// weighted scatter directly into d_out (x_down region, memset to 0 each launch)
__global__ __launch_bounds__(256) void xdown_kernel(const int* __restrict__ idx_cluster, const float* __restrict__ nw,
                                                    const float* __restrict__ xt, float* __restrict__ out0){
  int bn = blockIdx.x;
  int d = threadIdx.x;
  int b = bn >> 12;
  int ic = idx_cluster[bn];
  float v = xt[(size_t)bn*DOUT + d] * nw[bn];
  atomicAdd(&out0[((size_t)(b*MC + ic))*DOUT + d], v);
}
__global__ __launch_bounds__(256) void out12a_kernel(const int* __restrict__ idx_agg, const int* __restrict__ idx_cluster,
                                                     const float* __restrict__ aggw, const float* __restrict__ nw,
                                                     float* __restrict__ awd, int* __restrict__ awdmax,
                                                     float* __restrict__ out1){
  __shared__ float red[4];
  int lin = blockIdx.x * 256 + threadIdx.x;
  int b = lin >> 12;
  int ia = idx_agg[lin];
  int ic = idx_cluster[b*NT + ia];
  out1[lin] = (float)ic;
  float v = aggw[lin] * nw[b*NT + ia];
  awd[lin] = v;
  float wv = v;
#pragma unroll
  for (int m = 1; m < 64; m <<= 1) wv = fmaxf(wv, __shfl_xor(wv, m, 64));
  int lane = threadIdx.x & 63, wid = threadIdx.x >> 6;
  if (lane == 0) red[wid] = wv;
  __syncthreads();
  if (threadIdx.x == 0){
    float bm = fmaxf(fmaxf(red[0], red[1]), fmaxf(red[2], red[3]));
    atomicMax(&awdmax[b], __float_as_int(bm));
  }
}
__global__ __launch_bounds__(256) void out2_kernel(const float* __restrict__ awd, const int* __restrict__ awdmax,
                                                   float* __restrict__ out2){
  int lin = blockIdx.x * 256 + threadIdx.x;
  int b = lin >> 12;
  out2[lin] = awd[lin] / __int_as_float(awdmax[b]);
}

extern "C" void kernel_launch(void* const* d_in, const int* in_sizes, int n_in,
                              void* d_out, int out_size, void* d_ws, size_t ws_size,
                              hipStream_t stream) {
  const float* x      = (const float*)d_in[0];
  const float* loc    = (const float*)d_in[1];
  const int*   idxagg = (const int*)d_in[2];
  const float* aggw   = (const float*)d_in[3];
  const float* convw  = (const float*)d_in[7];
  const float* convb  = (const float*)d_in[8];
  const float* skipw  = (const float*)d_in[9];
  const float* lng    = (const float*)d_in[10];
  const float* lnb    = (const float*)d_in[11];
  const float* confw  = (const float*)d_in[12];
  const float* confb  = (const float*)d_in[13];

  char* ws = (char*)d_ws;
  float* w_xmap  = (float*)(ws + OFF_XMAP);
  float* w_cnt   = (float*)(ws + OFF_CNT);
  float* w_tot   = (float*)(ws + OFF_TOT);
  float* w_allw  = (float*)(ws + OFF_ALLW);
  int*   w_vmax  = (int*)  (ws + OFF_VMAX);
  int*   w_awdm  = (int*)  (ws + OFF_AWDM);
  float* w_ymap  = (float*)(ws + OFF_YMAP);
  float* w_xt    = (float*)(ws + OFF_XT);
  float* w_sq    = (float*)(ws + OFF_SQ);
  float* w_den   = (float*)(ws + OFF_DEN);
  float* w_score = (float*)(ws + OFF_SCORE);
  float* w_wt    = (float*)(ws + OFF_WT);
  float* w_nw    = (float*)(ws + OFF_NW);
  float* w_awd   = (float*)(ws + OFF_AWD);
  int*   w_idxd  = (int*)  (ws + OFF_IDXD);
  int*   w_idxc  = (int*)  (ws + OFF_IDXC);
  int*   w_inv   = (int*)  (ws + OFF_INV);
  float* w_wtr   = (float*)(ws + OFF_WTR);
  float* w_p     = (float*)(ws + OFF_P);
  float* w_g     = (float*)(ws + OFF_G);

  int gcount = 1;
  for (int k = 4; k >= 1; --k){
    if (OFF_G + (size_t)k*GSZB <= ws_size){ gcount = k; break; }
  }

  float* out0 = (float*)d_out;
  float* out1 = out0 + NB*MC*DOUT;
  float* out2 = out1 + NB*NT;

  hipMemsetAsync(ws, 0, ZERO_BYTES, stream);
  hipMemsetAsync(out0, 0, (size_t)NB*MC*DOUT*sizeof(float), stream);

  t2m_scatter<<<NB*NT*CI/256, 256, 0, stream>>>(x, loc, idxagg, aggw, w_xmap, w_cnt, w_tot);
  wtrans_kernel<<<1152, 256, 0, stream>>>(convw, w_wtr);
  im2col_kernel<<<2048, 256, 0, stream>>>(w_xmap, w_cnt, w_p);
  conv_gemm<<<dim3(4, 64), 256, 0, stream>>>(w_p, w_wtr, convb, w_ymap);
  skip_kernel<<<NB*NT/8, 256, 0, stream>>>(x, skipw, w_xt);
  m2t_scatter<<<NB*NT, 256, 0, stream>>>(w_ymap, loc, idxagg, aggw, w_tot, w_xt);
  ln_kernel<<<NB*NT, 256, 0, stream>>>(w_xt, lng, lnb, confw, confb, w_sq, w_wt);

  for (int g0 = 0; g0 < NB; g0 += gcount){
    int gy = (NB - g0 < gcount) ? (NB - g0) : gcount;
    gram64     <<<dim3(2080, gy), 256, 0, stream>>>(w_xt, w_g, g0, GSZ);
    density_all<<<dim3(NT, gy), 256, 0, stream>>>(w_g, GSZ, w_sq, w_den, w_vmax, g0);
    parent_all <<<dim3(NT, gy), 256, 0, stream>>>(w_g, GSZ, w_sq, w_den, w_vmax, w_score, g0);
    topk_all   <<<gy, 1024, 0, stream>>>(w_score, w_idxd, w_inv, g0);
    assign_all <<<dim3(64, gy), 256, 0, stream>>>(w_g, GSZ, w_sq, w_idxd, w_inv, w_wt, w_idxc, w_allw, g0);
  }

  normw_kernel<<<NB*NT/256, 256, 0, stream>>>(w_idxc, w_wt, w_allw, w_nw);
  xdown_kernel<<<NB*NT, 256, 0, stream>>>(w_idxc, w_nw, w_xt, out0);
  out12a_kernel<<<NB*NT/256, 256, 0, stream>>>(idxagg, w_idxc, aggw, w_nw, w_awd, w_awdm, out1);
  out2_kernel<<<NB*NT/256, 256, 0, stream>>>(w_awd, w_awdm, out2);

  (void)in_sizes; (void)n_in; (void)out_size;
}

// Round 11
// 894.310 us; speedup vs baseline: 1.9550x; 1.0459x over previous
//
#include <hip/hip_runtime.h>
#include <math.h>

// B=4, N=4096, C=128, DOUT=256, H=W=64 (conv out 32x32), M=1024, K=5.
// Inputs f32; output buffer f32.
#define NB 4
#define NT 4096
#define CI 128
#define DOUT 256
#define HWI 4096
#define HWO 1024
#define MC 1024
#define EPS_F 1e-6f
#define GSZ 16777216ull
#define GSZB 67108864ull

// ---------------- workspace layout (bytes) ----------------
// zero zone:
static const size_t OFF_XMAP  = 0;                          // 8388608
static const size_t OFF_CNT   = OFF_XMAP + 8388608;         // 65536
static const size_t OFF_TOT   = OFF_CNT  + 65536;           // 65536
static const size_t OFF_ALLW  = OFF_TOT  + 65536;           // 16384
static const size_t OFF_VMAX  = OFF_ALLW + 16384;           // 256
static const size_t OFF_AWDM  = OFF_VMAX + 256;             // 256
static const size_t ZERO_BYTES= OFF_AWDM + 256;
// non-zeroed:
static const size_t OFF_YMAP  = ZERO_BYTES;                 // 4194304
static const size_t OFF_XT    = OFF_YMAP + 4194304;         // 16777216
static const size_t OFF_SQ    = OFF_XT + 16777216;          // 65536
static const size_t OFF_DEN   = OFF_SQ + 65536;
static const size_t OFF_SCORE = OFF_DEN + 65536;
static const size_t OFF_WT    = OFF_SCORE + 65536;
static const size_t OFF_AWD   = OFF_WT + 65536;
static const size_t OFF_IDXD  = OFF_AWD + 65536;            // 16384
static const size_t OFF_IDXC  = OFF_IDXD + 16384;           // 65536
static const size_t OFF_INV   = OFF_IDXC + 65536;           // 65536 (init in topk)
static const size_t OFF_WTR   = OFF_INV + 65536;            // 1179648
static const size_t OFF_P     = OFF_WTR + 1179648;          // 18874368
static const size_t OFF_G     = OFF_P + 18874368;           // ~50 MB; +3*64MB fits 256MiB

// ---------------- helpers ----------------
__device__ __forceinline__ float waveSum(float v){
#pragma unroll
  for (int m = 1; m < 64; m <<= 1) v += __shfl_xor(v, m, 64);
  return v;
}
__device__ __forceinline__ float blockSum256(float v, float* red){
  v = waveSum(v);
  int lane = threadIdx.x & 63, wid = threadIdx.x >> 6;
  __syncthreads();
  if (lane == 0) red[wid] = v;
  __syncthreads();
  return red[0] + red[1] + red[2] + red[3];
}
__device__ __forceinline__ void merge5(float& a0, float& a1, float& a2, float& a3, float& a4,
                                       float b0, float b1, float b2, float b3, float b4){
  float l0=a0,l1=a1,l2=a2,l3=fminf(a3,b4),l4=fminf(a4,b3),l5=b2,l6=b1,l7=b0;
  float t0=fminf(l0,l4), t4=fmaxf(l0,l4);
  float t1=fminf(l1,l5), t5=fmaxf(l1,l5);
  float t2=fminf(l2,l6), t6=fmaxf(l2,l6);
  float t3=fminf(l3,l7), t7=fmaxf(l3,l7);
  float u0=fminf(t0,t2), u2=fmaxf(t0,t2);
  float u1=fminf(t1,t3), u3=fmaxf(t1,t3);
  float u4=fminf(t4,t6);
  float u5=fminf(t5,t7);
  a0=fminf(u0,u1); a1=fmaxf(u0,u1);
  a2=fminf(u2,u3); a3=fmaxf(u2,u3);
  a4=fminf(u4,u5);
}
__device__ __forceinline__ void ins5(float v, float& t0, float& t1, float& t2, float& t3, float& t4){
  t4 = fminf(t4, v);
  float a;
  a = fminf(t3,t4); t4 = fmaxf(t3,t4); t3 = a;
  a = fminf(t2,t3); t3 = fmaxf(t2,t3); t2 = a;
  a = fminf(t1,t2); t2 = fmaxf(t1,t2); t1 = a;
  a = fminf(t0,t1); t1 = fmaxf(t0,t1); t0 = a;
}
__device__ __forceinline__ int grid_cell(float lx, float ly, int dim){
  lx = (fminf(fmaxf(lx, -1.f), 1.f) + 1.f) * 0.5f;
  ly = (fminf(fmaxf(ly, -1.f), 1.f) + 1.f) * 0.5f;
  float s = (float)(dim - 1);
  int col = (int)rintf(lx * s); col = min(max(col, 0), dim - 1);
  int row = (int)rintf(ly * s); row = min(max(row, 0), dim - 1);
  return row * dim + col;
}

// ---------------- front-end kernels ----------------
__global__ __launch_bounds__(256) void t2m_scatter(const float* __restrict__ x,
                                                   const float* __restrict__ loc,
                                                   const int* __restrict__ idx_agg,
                                                   const float* __restrict__ aggw,
                                                   float* __restrict__ xmap, float* __restrict__ cnt,
                                                   float* __restrict__ tot){
  int lin = blockIdx.x * 256 + threadIdx.x;
  int c  = lin & 127;
  int bn = lin >> 7;
  int b  = bn >> 12;
  float lx = loc[(size_t)bn*2 + 0];
  float ly = loc[(size_t)bn*2 + 1];
  int cell = grid_cell(lx, ly, 64);
  int ia = idx_agg[bn];
  float val = x[((size_t)(b*NT + ia))*CI + c];
  atomicAdd(&xmap[((size_t)(b*HWI + cell))*CI + c], val);
  if (c == 0) atomicAdd(&cnt[b*HWI + cell], 1.0f);
  if (c == 1) atomicAdd(&tot[b*NT + ia], aggw[bn]);
}

__global__ __launch_bounds__(256) void wtrans_kernel(const float* __restrict__ cw, float* __restrict__ wT){
  int lin = blockIdx.x * 256 + threadIdx.x;
  int k = lin >> 8, d = lin & 255;
  wT[lin] = cw[(size_t)d*1152 + k];
}

__global__ __launch_bounds__(256) void im2col_kernel(const float* __restrict__ xmap,
                                                     const float* __restrict__ cnt,
                                                     float* __restrict__ P){
  int tid = threadIdx.x;
  int c = tid & 127, n2 = tid >> 7;
  int n = blockIdx.x * 2 + n2;
  int b = n >> 10, rem = n & 1023;
  int oh = rem >> 5, ow = rem & 31;
  const float* xb = xmap + (size_t)b*HWI*CI;
  const float* cb_ = cnt + (size_t)b*HWI;
  float* prow = P + (size_t)n*1152 + c*9;
#pragma unroll
  for (int kh = 0; kh < 3; ++kh){
    int ih = oh*2 - 1 + kh;
#pragma unroll
    for (int kw = 0; kw < 3; ++kw){
      int iw = ow*2 - 1 + kw;
      bool inb = (ih >= 0) && (ih < 64) && (iw >= 0) && (iw < 64);
      float v = 0.f;
      if (inb){
        int cell = ih*64 + iw;
        v = xb[(size_t)cell*CI + c] / (cb_[cell] + EPS_F);
      }
      prow[kh*3 + kw] = v;
    }
  }
}

__global__ __launch_bounds__(256) void conv_gemm(const float* __restrict__ P,
                                                 const float* __restrict__ wT,
                                                 const float* __restrict__ cb,
                                                 float* __restrict__ ymap){
  __shared__ float As[16][64];
  __shared__ float Bs[16][64];
  int n0 = blockIdx.y * 64, d0 = blockIdx.x * 64;
  int tid = threadIdx.x;
  int tx = tid & 15, ty = tid >> 4;
  int ln = tid & 63, kq = tid >> 6;
  int bkr = tid >> 4, bc4 = (tid & 15) * 4;
  float4 pav = *(const float4*)(P + (size_t)(n0+ln)*1152 + kq*4);
  float4 pbv = *(const float4*)(wT + (size_t)bkr*256 + d0 + bc4);
  float acc[4][4] = {{0}};
  for (int kt = 0; kt < 72; ++kt){
    __syncthreads();
    As[kq*4+0][ln]=pav.x; As[kq*4+1][ln]=pav.y; As[kq*4+2][ln]=pav.z; As[kq*4+3][ln]=pav.w;
    *(float4*)&Bs[bkr][bc4] = pbv;
    __syncthreads();
    if (kt < 71){
      int k2 = (kt + 1) * 16;
      pav = *(const float4*)(P + (size_t)(n0+ln)*1152 + k2 + kq*4);
      pbv = *(const float4*)(wT + (size_t)(k2 + bkr)*256 + d0 + bc4);
    }
#pragma unroll
    for (int k = 0; k < 16; ++k){
      float ar[4], br[4];
      *(float4*)ar = *(const float4*)&As[k][ty*4];
      *(float4*)br = *(const float4*)&Bs[k][tx*4];
#pragma unroll
      for (int r = 0; r < 4; ++r)
#pragma unroll
        for (int s = 0; s < 4; ++s) acc[r][s] += ar[r]*br[s];
    }
  }
  float4 bias = *(const float4*)(cb + d0 + tx*4);
#pragma unroll
  for (int r = 0; r < 4; ++r){
    float4 o;
    o.x = acc[r][0] + bias.x; o.y = acc[r][1] + bias.y;
    o.z = acc[r][2] + bias.z; o.w = acc[r][3] + bias.w;
    *(float4*)(ymap + (size_t)(n0 + ty*4 + r)*DOUT + d0 + tx*4) = o;
  }
}

__global__ __launch_bounds__(256) void skip_kernel(const float* __restrict__ x,
                                                   const float* __restrict__ sw,
                                                   float* __restrict__ xt){
  int rowbase = blockIdx.x * 8;
  int d = threadIdx.x;
  __shared__ float xr[8*128];
  ((float4*)xr)[d] = ((const float4*)(x + (size_t)rowbase*CI))[d];
  __syncthreads();
  float acc[8] = {0,0,0,0,0,0,0,0};
  const float* wd = sw + (size_t)d*CI;
  for (int c = 0; c < 128; ++c){
    float w = wd[c];
#pragma unroll
    for (int r = 0; r < 8; ++r) acc[r] += w * xr[r*128 + c];
  }
  for (int r = 0; r < 8; ++r) xt[(size_t)(rowbase + r)*DOUT + d] = acc[r];
}

__global__ __launch_bounds__(256) void m2t_scatter(const float* __restrict__ ymap,
                                                   const float* __restrict__ loc,
                                                   const int* __restrict__ idx_agg,
                                                   const float* __restrict__ aggw,
                                                   const float* __restrict__ tot,
                                                   float* __restrict__ xt){
  int bn = blockIdx.x;
  int d = threadIdx.x;
  int b = bn >> 12;
  float lx = loc[(size_t)bn*2 + 0];
  float ly = loc[(size_t)bn*2 + 1];
  int cell = grid_cell(lx, ly, 32);
  int ia = idx_agg[bn];
  float w = aggw[bn] / (tot[b*NT + ia] + EPS_F);
  float val = ymap[((size_t)(b*HWO + cell))*DOUT + d] * w;
  atomicAdd(&xt[((size_t)(b*NT + ia))*DOUT + d], val);
}

__global__ __launch_bounds__(256) void ln_kernel(float* __restrict__ xt,
                                                 const float* __restrict__ g,
                                                 const float* __restrict__ bta,
                                                 const float* __restrict__ cw,
                                                 const float* __restrict__ cb,
                                                 float* __restrict__ sq, float* __restrict__ wt){
  __shared__ float red[4];
  int row = blockIdx.x;
  int d = threadIdx.x;
  float v = xt[(size_t)row*DOUT + d];
  float mu = blockSum256(v, red) * (1.0f/256.0f);
  float xc = v - mu;
  float var = blockSum256(xc*xc, red) * (1.0f/256.0f);
  float rn = 1.0f / sqrtf(var + 1e-5f);
  float y = xc * rn * g[d] + bta[d];
  xt[(size_t)row*DOUT + d] = y;
  float s2 = blockSum256(y*y, red);
  float cf = blockSum256(y*cw[d], red);
  if (d == 0){ sq[row] = s2; wt[row] = expf(cf + cb[0]); }
}

// ---------------- clustering ----------------
// gram: 64x64 lower-triangle tiles (2080/batch), BK=32 (8 barrier-pairs), prefetch.
// LDS union: As[32][64]@0, Bs[32][64]@2048, T[64][65] aliases (16.6 KB total).
__global__ __launch_bounds__(256) void gram64(const float* __restrict__ xt, float* __restrict__ G,
                                              int b_base, size_t gstride){
  __shared__ float smem[4160];
  int b = b_base + blockIdx.y;
  const float* A = xt + (size_t)b*NT*DOUT;
  float* Gb = G + (size_t)blockIdx.y*gstride;
  int t = blockIdx.x;
  int ti = 0, accu = 0;
  while (accu + ti + 1 <= t){ accu += ti + 1; ++ti; }
  int tj = t - accu;
  int i0 = ti * 64, j0 = tj * 64;
  int tid = threadIdx.x;
  int li = tid & 63, kq = tid >> 6;   // kq 0..3 -> float4 at kq*4 and 16+kq*4
  int tx = tid & 15, ty = tid >> 4;
  const float* Ai = A + (size_t)(i0+li)*DOUT;
  const float* Aj = A + (size_t)(j0+li)*DOUT;
  float4 av0 = *(const float4*)(Ai + kq*4);
  float4 av1 = *(const float4*)(Ai + 16 + kq*4);
  float4 bv0 = *(const float4*)(Aj + kq*4);
  float4 bv1 = *(const float4*)(Aj + 16 + kq*4);
  float acc[4][4] = {{0}};
  for (int kt = 0; kt < 256; kt += 32){
    __syncthreads();
    smem[(kq*4+0)*64 + li]=av0.x; smem[(kq*4+1)*64 + li]=av0.y;
    smem[(kq*4+2)*64 + li]=av0.z; smem[(kq*4+3)*64 + li]=av0.w;
    smem[(16+kq*4+0)*64 + li]=av1.x; smem[(16+kq*4+1)*64 + li]=av1.y;
    smem[(16+kq*4+2)*64 + li]=av1.z; smem[(16+kq*4+3)*64 + li]=av1.w;
    smem[2048 + (kq*4+0)*64 + li]=bv0.x; smem[2048 + (kq*4+1)*64 + li]=bv0.y;
    smem[2048 + (kq*4+2)*64 + li]=bv0.z; smem[2048 + (kq*4+3)*64 + li]=bv0.w;
    smem[2048 + (16+kq*4+0)*64 + li]=bv1.x; smem[2048 + (16+kq*4+1)*64 + li]=bv1.y;
    smem[2048 + (16+kq*4+2)*64 + li]=bv1.z; smem[2048 + (16+kq*4+3)*64 + li]=bv1.w;
    __syncthreads();
    if (kt < 224){
      av0 = *(const float4*)(Ai + kt + 32 + kq*4);
      av1 = *(const float4*)(Ai + kt + 48 + kq*4);
      bv0 = *(const float4*)(Aj + kt + 32 + kq*4);
      bv1 = *(const float4*)(Aj + kt + 48 + kq*4);
    }
#pragma unroll
    for (int k = 0; k < 32; ++k){
      float ar[4], br[4];
      *(float4*)ar = *(const float4*)&smem[k*64 + ty*4];
      *(float4*)br = *(const float4*)&smem[2048 + k*64 + tx*4];
#pragma unroll
      for (int r = 0; r < 4; ++r)
#pragma unroll
        for (int s = 0; s < 4; ++s) acc[r][s] += ar[r]*br[s];
    }
  }
#pragma unroll
  for (int r = 0; r < 4; ++r)
    *(float4*)(Gb + (size_t)(i0 + ty*4 + r)*NT + j0 + tx*4) = *(float4*)&acc[r][0];
  if (ti != tj){
    __syncthreads();
#pragma unroll
    for (int r = 0; r < 4; ++r)
#pragma unroll
      for (int s = 0; s < 4; ++s) smem[(ty*4+r)*65 + tx*4+s] = acc[r][s];
    __syncthreads();
#pragma unroll
    for (int r = 0; r < 4; ++r){
      float4 o;
      o.x = smem[(tx*4+0)*65 + ty*4+r]; o.y = smem[(tx*4+1)*65 + ty*4+r];
      o.z = smem[(tx*4+2)*65 + ty*4+r]; o.w = smem[(tx*4+3)*65 + ty*4+r];
      *(float4*)(Gb + (size_t)(j0 + ty*4 + r)*NT + i0 + tx*4) = o;
    }
  }
}

__global__ __launch_bounds__(256) void density_all(const float* __restrict__ G, size_t gstride,
                                                   const float* __restrict__ sq,
                                                   float* __restrict__ density, int* __restrict__ vmax,
                                                   int b_base){
  int b = b_base + blockIdx.y;
  const float* Gb = G + (size_t)blockIdx.y*gstride;
  int i = blockIdx.x;
  int tid = threadIdx.x;
  const float* sqb = sq + b*NT;
  float sqi = sqb[i];
  const float* row = Gb + (size_t)i*NT;
  float t0=INFINITY,t1=INFINITY,t2=INFINITY,t3=INFINITY,t4=INFINITY;
  float vmx = 0.f;
  for (int j = tid*4; j < NT; j += 1024){
    float4 g4 = *(const float4*)(row + j);
    float4 s4 = *(const float4*)(sqb + j);
    float v0 = fmaxf(sqi + s4.x - 2.0f*g4.x, 0.0f);
    float v1 = fmaxf(sqi + s4.y - 2.0f*g4.y, 0.0f);
    float v2 = fmaxf(sqi + s4.z - 2.0f*g4.z, 0.0f);
    float v3 = fmaxf(sqi + s4.w - 2.0f*g4.w, 0.0f);
    vmx = fmaxf(fmaxf(vmx, fmaxf(v0,v1)), fmaxf(v2,v3));
    ins5(v0,t0,t1,t2,t3,t4); ins5(v1,t0,t1,t2,t3,t4);
    ins5(v2,t0,t1,t2,t3,t4); ins5(v3,t0,t1,t2,t3,t4);
  }
#pragma unroll
  for (int m = 1; m < 64; m <<= 1){
    float b0=__shfl_xor(t0,m,64), b1=__shfl_xor(t1,m,64), b2=__shfl_xor(t2,m,64),
          b3=__shfl_xor(t3,m,64), b4=__shfl_xor(t4,m,64);
    merge5(t0,t1,t2,t3,t4,b0,b1,b2,b3,b4);
    vmx = fmaxf(vmx, __shfl_xor(vmx,m,64));
  }
  __shared__ float w5[4][5];
  __shared__ float wm[4];
  int lane = tid & 63, wid = tid >> 6;
  if (lane == 0){ w5[wid][0]=t0; w5[wid][1]=t1; w5[wid][2]=t2; w5[wid][3]=t3; w5[wid][4]=t4; wm[wid]=vmx; }
  __syncthreads();
  if (tid == 0){
    float a0=w5[0][0],a1=w5[0][1],a2=w5[0][2],a3=w5[0][3],a4=w5[0][4];
    for (int w = 1; w < 4; ++w) merge5(a0,a1,a2,a3,a4, w5[w][0],w5[w][1],w5[w][2],w5[w][3],w5[w][4]);
    float d0=sqrtf(a0)*0.0625f, d1=sqrtf(a1)*0.0625f, d2=sqrtf(a2)*0.0625f,
          d3=sqrtf(a3)*0.0625f, d4=sqrtf(a4)*0.0625f;
    float s = d0*d0; s += d1*d1; s += d2*d2; s += d3*d3; s += d4*d4;
    density[b*NT + i] = expf(-(s / 5.0f));
    float vm = fmaxf(fmaxf(wm[0],wm[1]), fmaxf(wm[2],wm[3]));
    atomicMax(vmax + b, __float_as_int(vm));
  }
}

__global__ __launch_bounds__(256) void parent_all(const float* __restrict__ G, size_t gstride,
                                                  const float* __restrict__ sq,
                                                  const float* __restrict__ density, const int* __restrict__ vmax,
                                                  float* __restrict__ score, int b_base){
  int b = b_base + blockIdx.y;
  const float* Gb = G + (size_t)blockIdx.y*gstride;
  int i = blockIdx.x;
  int tid = threadIdx.x;
  const float* sqb = sq + b*NT;
  const float* den = density + b*NT;
  float sqi = sqb[i];
  float di = den[i];
  const float* row = Gb + (size_t)i*NT;
  float minv = INFINITY;
  for (int j = tid*4; j < NT; j += 1024){
    float4 g4 = *(const float4*)(row + j);
    float4 s4 = *(const float4*)(sqb + j);
    float4 d4 = *(const float4*)(den + j);
    float v0 = fmaxf(sqi + s4.x - 2.0f*g4.x, 0.0f);
    float v1 = fmaxf(sqi + s4.y - 2.0f*g4.y, 0.0f);
    float v2 = fmaxf(sqi + s4.z - 2.0f*g4.z, 0.0f);
    float v3 = fmaxf(sqi + s4.w - 2.0f*g4.w, 0.0f);
    minv = fminf(minv, (d4.x > di) ? v0 : INFINITY);
    minv = fminf(minv, (d4.y > di) ? v1 : INFINITY);
    minv = fminf(minv, (d4.z > di) ? v2 : INFINITY);
    minv = fminf(minv, (d4.w > di) ? v3 : INFINITY);
  }
#pragma unroll
  for (int m = 1; m < 64; m <<= 1) minv = fminf(minv, __shfl_xor(minv,m,64));
  __shared__ float wmn[4];
  int lane = tid & 63, wid = tid >> 6;
  if (lane == 0) wmn[wid] = minv;
  __syncthreads();
  if (tid == 0){
    float mv = fminf(fminf(wmn[0],wmn[1]), fminf(wmn[2],wmn[3]));
    float dmax = sqrtf(__int_as_float(vmax[b])) * 0.0625f;
    float dp = isinf(mv) ? dmax : sqrtf(mv) * 0.0625f;
    score[b*NT + i] = dp * di;
  }
}

__global__ __launch_bounds__(1024) void topk_all(const float* __restrict__ score, int* __restrict__ idx_down,
                                                 int* __restrict__ inv, int b_base){
  __shared__ float ss[4096];
  __shared__ int ii[4096];
  int b = b_base + blockIdx.x;
  int tid = threadIdx.x;
  for (int t = tid; t < 4096; t += 1024){ ss[t] = score[b*NT + t]; ii[t] = t; inv[b*NT + t] = -1; }
  for (int k = 2; k <= 4096; k <<= 1){
    for (int j = k >> 1; j > 0; j >>= 1){
      __syncthreads();
#pragma unroll
      for (int vv = 0; vv < 2; ++vv){
        int v = tid + vv*1024;
        int i1 = 2*v - (v & (j-1));
        int i2 = i1 + j;
        float s1 = ss[i1], s2 = ss[i2];
        int a1 = ii[i1], a2 = ii[i2];
        bool lt = (s1 > s2) || (s1 == s2 && a1 < a2);
        bool up = ((i1 & k) == 0);
        if (up ? !lt : lt){ ss[i1]=s2; ss[i2]=s1; ii[i1]=a2; ii[i2]=a1; }
      }
    }
  }
  __syncthreads();
  if (tid < MC){
    int tok = ii[tid];
    idx_down[b*MC + tid] = tok;
    inv[b*NT + tok] = tid;
  }
}

// assign: block = 16 j x 16 m-chunks (64 m each, ascending); grid 256 x gy.
// chunk-combine ascending preserves first-min (lowest m on tie) exactly.
__global__ __launch_bounds__(256) void assign_all(const float* __restrict__ G, size_t gstride,
                                                  const float* __restrict__ sq,
                                                  const int* __restrict__ idx_down, const int* __restrict__ inv,
                                                  const float* __restrict__ wt,
                                                  int* __restrict__ idx_cluster, float* __restrict__ allw,
                                                  int b_base){
  int b = b_base + blockIdx.y;
  const float* Gb = G + (size_t)blockIdx.y*gstride;
  int jl = threadIdx.x & 15, mq = threadIdx.x >> 4;   // mq 0..15
  int j = blockIdx.x * 16 + jl;
  const float* sqb = sq + b*NT;
  float sqj = sqb[j];
  const int* idb = idx_down + b*MC;
  float bestd = INFINITY; int bestm = 0x7fffffff;
  for (int m = mq*64; m < mq*64 + 64; ++m){
    int im = idb[m];
    float g = Gb[(size_t)im*NT + j];
    float v = fmaxf(sqb[im] + sqj - 2.0f*g, 0.0f);
    float d = sqrtf(v) * 0.0625f;
    if (d < bestd){ bestd = d; bestm = m; }
  }
  __shared__ float ld[16][17];
  __shared__ int lm[16][17];
  ld[mq][jl] = bestd; lm[mq][jl] = bestm;
  __syncthreads();
  if (mq == 0){
    for (int q = 1; q < 16; ++q){
      float d2 = ld[q][jl]; int m2 = lm[q][jl];
      if (d2 < bestd || (d2 == bestd && m2 < bestm)){ bestd = d2; bestm = m2; }
    }
    int iv = inv[b*NT + j];
    int final_m = (iv >= 0) ? iv : bestm;
    idx_cluster[b*NT + j] = final_m;
    atomicAdd(&allw[b*MC + final_m], wt[b*NT + j]);
  }
}

// ---------------- merge + outputs ----------------
// weighted scatter directly into d_out (x_down region, memset to 0 each launch);
// nw recomputed inline (same expression/order as before -> bit-identical).
__global__ __launch_bounds__(256) void xdown_kernel(const int* __restrict__ idx_cluster,
                                                    const float* __restrict__ wt, const float* __restrict__ allw,
                                                    const float* __restrict__ xt, float* __restrict__ out0){
  int bn = blockIdx.x;
  int d = threadIdx.x;
  int b = bn >> 12;
  int ic = idx_cluster[bn];
  float nw = wt[bn] / (allw[b*MC + ic] + EPS_F);
  float v = xt[(size_t)bn*DOUT + d] * nw;
  atomicAdd(&out0[((size_t)(b*MC + ic))*DOUT + d], v);
}
__global__ __launch_bounds__(256) void out12a_kernel(const int* __restrict__ idx_agg, const int* __restrict__ idx_cluster,
                                                     const float* __restrict__ aggw,
                                                     const float* __restrict__ wt, const float* __restrict__ allw,
                                                     float* __restrict__ awd, int* __restrict__ awdmax,
                                                     float* __restrict__ out1){
  __shared__ float red[4];
  int lin = blockIdx.x * 256 + threadIdx.x;
  int b = lin >> 12;
  int ia = idx_agg[lin];
  int ic = idx_cluster[b*NT + ia];
  out1[lin] = (float)ic;
  float nw = wt[b*NT + ia] / (allw[b*MC + ic] + EPS_F);
  float v = aggw[lin] * nw;
  awd[lin] = v;
  float wv = v;
#pragma unroll
  for (int m = 1; m < 64; m <<= 1) wv = fmaxf(wv, __shfl_xor(wv, m, 64));
  int lane = threadIdx.x & 63, wid = threadIdx.x >> 6;
  if (lane == 0) red[wid] = wv;
  __syncthreads();
  if (threadIdx.x == 0){
    float bm = fmaxf(fmaxf(red[0], red[1]), fmaxf(red[2], red[3]));
    atomicMax(&awdmax[b], __float_as_int(bm));
  }
}
__global__ __launch_bounds__(256) void out2_kernel(const float* __restrict__ awd, const int* __restrict__ awdmax,
                                                   float* __restrict__ out2){
  int lin = blockIdx.x * 256 + threadIdx.x;
  int b = lin >> 12;
  out2[lin] = awd[lin] / __int_as_float(awdmax[b]);
}

extern "C" void kernel_launch(void* const* d_in, const int* in_sizes, int n_in,
                              void* d_out, int out_size, void* d_ws, size_t ws_size,
                              hipStream_t stream) {
  const float* x      = (const float*)d_in[0];
  const float* loc    = (const float*)d_in[1];
  const int*   idxagg = (const int*)d_in[2];
  const float* aggw   = (const float*)d_in[3];
  const float* convw  = (const float*)d_in[7];
  const float* convb  = (const float*)d_in[8];
  const float* skipw  = (const float*)d_in[9];
  const float* lng    = (const float*)d_in[10];
  const float* lnb    = (const float*)d_in[11];
  const float* confw  = (const float*)d_in[12];
  const float* confb  = (const float*)d_in[13];

  char* ws = (char*)d_ws;
  float* w_xmap  = (float*)(ws + OFF_XMAP);
  float* w_cnt   = (float*)(ws + OFF_CNT);
  float* w_tot   = (float*)(ws + OFF_TOT);
  float* w_allw  = (float*)(ws + OFF_ALLW);
  int*   w_vmax  = (int*)  (ws + OFF_VMAX);
  int*   w_awdm  = (int*)  (ws + OFF_AWDM);
  float* w_ymap  = (float*)(ws + OFF_YMAP);
  float* w_xt    = (float*)(ws + OFF_XT);
  float* w_sq    = (float*)(ws + OFF_SQ);
  float* w_den   = (float*)(ws + OFF_DEN);
  float* w_score = (float*)(ws + OFF_SCORE);
  float* w_wt    = (float*)(ws + OFF_WT);
  float* w_awd   = (float*)(ws + OFF_AWD);
  int*   w_idxd  = (int*)  (ws + OFF_IDXD);
  int*   w_idxc  = (int*)  (ws + OFF_IDXC);
  int*   w_inv   = (int*)  (ws + OFF_INV);
  float* w_wtr   = (float*)(ws + OFF_WTR);
  float* w_p     = (float*)(ws + OFF_P);
  float* w_g     = (float*)(ws + OFF_G);

  int gcount = 1;
  for (int k = 4; k >= 1; --k){
    if (OFF_G + (size_t)k*GSZB <= ws_size){ gcount = k; break; }
  }

  float* out0 = (float*)d_out;
  float* out1 = out0 + NB*MC*DOUT;
  float* out2 = out1 + NB*NT;

  hipMemsetAsync(ws, 0, ZERO_BYTES, stream);
  hipMemsetAsync(out0, 0, (size_t)NB*MC*DOUT*sizeof(float), stream);

  t2m_scatter<<<NB*NT*CI/256, 256, 0, stream>>>(x, loc, idxagg, aggw, w_xmap, w_cnt, w_tot);
  wtrans_kernel<<<1152, 256, 0, stream>>>(convw, w_wtr);
  im2col_kernel<<<2048, 256, 0, stream>>>(w_xmap, w_cnt, w_p);
  conv_gemm<<<dim3(4, 64), 256, 0, stream>>>(w_p, w_wtr, convb, w_ymap);
  skip_kernel<<<NB*NT/8, 256, 0, stream>>>(x, skipw, w_xt);
  m2t_scatter<<<NB*NT, 256, 0, stream>>>(w_ymap, loc, idxagg, aggw, w_tot, w_xt);
  ln_kernel<<<NB*NT, 256, 0, stream>>>(w_xt, lng, lnb, confw, confb, w_sq, w_wt);

  for (int g0 = 0; g0 < NB; g0 += gcount){
    int gy = (NB - g0 < gcount) ? (NB - g0) : gcount;
    gram64     <<<dim3(2080, gy), 256, 0, stream>>>(w_xt, w_g, g0, GSZ);
    density_all<<<dim3(NT, gy), 256, 0, stream>>>(w_g, GSZ, w_sq, w_den, w_vmax, g0);
    parent_all <<<dim3(NT, gy), 256, 0, stream>>>(w_g, GSZ, w_sq, w_den, w_vmax, w_score, g0);
    topk_all   <<<gy, 1024, 0, stream>>>(w_score, w_idxd, w_inv, g0);
    assign_all <<<dim3(256, gy), 256, 0, stream>>>(w_g, GSZ, w_sq, w_idxd, w_inv, w_wt, w_idxc, w_allw, g0);
  }

  xdown_kernel<<<NB*NT, 256, 0, stream>>>(w_idxc, w_wt, w_allw, w_xt, out0);
  out12a_kernel<<<NB*NT/256, 256, 0, stream>>>(idxagg, w_idxc, aggw, w_wt, w_allw, w_awd, w_awdm, out1);
  out2_kernel<<<NB*NT/256, 256, 0, stream>>>(w_awd, w_awdm, out2);

  (void)in_sizes; (void)n_in; (void)out_size;
}

// Round 12
// 890.127 us; speedup vs baseline: 1.9642x; 1.0047x over previous
//
#include <hip/hip_runtime.h>
#include <math.h>

// B=4, N=4096, C=128, DOUT=256, H=W=64 (conv out 32x32), M=1024, K=5.
// Inputs f32; output buffer f32.
#define NB 4
#define NT 4096
#define CI 128
#define DOUT 256
#define HWI 4096
#define HWO 1024
#define MC 1024
#define EPS_F 1e-6f
#define GSZ 16777216ull
#define GSZB 67108864ull

// ---------------- workspace layout (bytes) ----------------
// zero zone:
static const size_t OFF_XMAP  = 0;                          // 8388608
static const size_t OFF_CNT   = OFF_XMAP + 8388608;         // 65536
static const size_t OFF_TOT   = OFF_CNT  + 65536;           // 65536
static const size_t OFF_ALLW  = OFF_TOT  + 65536;           // 16384
static const size_t OFF_VMAX  = OFF_ALLW + 16384;           // 256
static const size_t OFF_AWDM  = OFF_VMAX + 256;             // 256
static const size_t ZERO_BYTES= OFF_AWDM + 256;
// non-zeroed:
static const size_t OFF_YMAP  = ZERO_BYTES;                 // 4194304
static const size_t OFF_XT    = OFF_YMAP + 4194304;         // 16777216
static const size_t OFF_SQ    = OFF_XT + 16777216;          // 65536
static const size_t OFF_DEN   = OFF_SQ + 65536;
static const size_t OFF_SCORE = OFF_DEN + 65536;
static const size_t OFF_WT    = OFF_SCORE + 65536;
static const size_t OFF_AWD   = OFF_WT + 65536;
static const size_t OFF_IDXD  = OFF_AWD + 65536;            // 16384
static const size_t OFF_IDXC  = OFF_IDXD + 16384;           // 65536
static const size_t OFF_INV   = OFF_IDXC + 65536;           // 65536 (init in topk)
static const size_t OFF_WTR   = OFF_INV + 65536;            // 1179648 (wT[1152][256])
static const size_t OFF_SWT   = OFF_WTR + 1179648;          // 131072 (swT[128][256])
static const size_t OFF_P     = OFF_SWT + 131072;           // 18874368
static const size_t OFF_G     = OFF_P + 18874368;           // ~50.2MB; +3*64MB = 239.9MiB

// ---------------- helpers ----------------
__device__ __forceinline__ float waveSum(float v){
#pragma unroll
  for (int m = 1; m < 64; m <<= 1) v += __shfl_xor(v, m, 64);
  return v;
}
__device__ __forceinline__ float blockSum256(float v, float* red){
  v = waveSum(v);
  int lane = threadIdx.x & 63, wid = threadIdx.x >> 6;
  __syncthreads();
  if (lane == 0) red[wid] = v;
  __syncthreads();
  return red[0] + red[1] + red[2] + red[3];
}
__device__ __forceinline__ void merge5(float& a0, float& a1, float& a2, float& a3, float& a4,
                                       float b0, float b1, float b2, float b3, float b4){
  float l0=a0,l1=a1,l2=a2,l3=fminf(a3,b4),l4=fminf(a4,b3),l5=b2,l6=b1,l7=b0;
  float t0=fminf(l0,l4), t4=fmaxf(l0,l4);
  float t1=fminf(l1,l5), t5=fmaxf(l1,l5);
  float t2=fminf(l2,l6), t6=fmaxf(l2,l6);
  float t3=fminf(l3,l7), t7=fmaxf(l3,l7);
  float u0=fminf(t0,t2), u2=fmaxf(t0,t2);
  float u1=fminf(t1,t3), u3=fmaxf(t1,t3);
  float u4=fminf(t4,t6);
  float u5=fminf(t5,t7);
  a0=fminf(u0,u1); a1=fmaxf(u0,u1);
  a2=fminf(u2,u3); a3=fmaxf(u2,u3);
  a4=fminf(u4,u5);
}
__device__ __forceinline__ void ins5(float v, float& t0, float& t1, float& t2, float& t3, float& t4){
  t4 = fminf(t4, v);
  float a;
  a = fminf(t3,t4); t4 = fmaxf(t3,t4); t3 = a;
  a = fminf(t2,t3); t3 = fmaxf(t2,t3); t2 = a;
  a = fminf(t1,t2); t2 = fmaxf(t1,t2); t1 = a;
  a = fminf(t0,t1); t1 = fmaxf(t0,t1); t0 = a;
}
__device__ __forceinline__ int grid_cell(float lx, float ly, int dim){
  lx = (fminf(fmaxf(lx, -1.f), 1.f) + 1.f) * 0.5f;
  ly = (fminf(fmaxf(ly, -1.f), 1.f) + 1.f) * 0.5f;
  float s = (float)(dim - 1);
  int col = (int)rintf(lx * s); col = min(max(col, 0), dim - 1);
  int row = (int)rintf(ly * s); row = min(max(row, 0), dim - 1);
  return row * dim + col;
}

// ---------------- front-end kernels ----------------
__global__ __launch_bounds__(256) void t2m_scatter(const float* __restrict__ x,
                                                   const float* __restrict__ loc,
                                                   const int* __restrict__ idx_agg,
                                                   const float* __restrict__ aggw,
                                                   float* __restrict__ xmap, float* __restrict__ cnt,
                                                   float* __restrict__ tot){
  int lin = blockIdx.x * 256 + threadIdx.x;
  int c  = lin & 127;
  int bn = lin >> 7;
  int b  = bn >> 12;
  float lx = loc[(size_t)bn*2 + 0];
  float ly = loc[(size_t)bn*2 + 1];
  int cell = grid_cell(lx, ly, 64);
  int ia = idx_agg[bn];
  float val = x[((size_t)(b*NT + ia))*CI + c];
  atomicAdd(&xmap[((size_t)(b*HWI + cell))*CI + c], val);
  if (c == 0) atomicAdd(&cnt[b*HWI + cell], 1.0f);
  if (c == 1) atomicAdd(&tot[b*NT + ia], aggw[bn]);
}

// fused weight prep: wT[k][d] = conv_w[d][k]; swT[c][d] = skip_w[d][c]
__global__ __launch_bounds__(256) void wprep_kernel(const float* __restrict__ cw, const float* __restrict__ sw,
                                                    float* __restrict__ wT, float* __restrict__ swT){
  int lin = blockIdx.x * 256 + threadIdx.x;
  if (lin < 1152*256){
    int k = lin >> 8, d = lin & 255;
    wT[lin] = cw[(size_t)d*1152 + k];
  } else {
    int i = lin - 1152*256;
    int c = i >> 8, d = i & 255;
    swT[i] = sw[d*128 + c];
  }
}

__global__ __launch_bounds__(256) void im2col_kernel(const float* __restrict__ xmap,
                                                     const float* __restrict__ cnt,
                                                     float* __restrict__ P){
  int tid = threadIdx.x;
  int c = tid & 127, n2 = tid >> 7;
  int n = blockIdx.x * 2 + n2;
  int b = n >> 10, rem = n & 1023;
  int oh = rem >> 5, ow = rem & 31;
  const float* xb = xmap + (size_t)b*HWI*CI;
  const float* cb_ = cnt + (size_t)b*HWI;
  float* prow = P + (size_t)n*1152 + c*9;
#pragma unroll
  for (int kh = 0; kh < 3; ++kh){
    int ih = oh*2 - 1 + kh;
#pragma unroll
    for (int kw = 0; kw < 3; ++kw){
      int iw = ow*2 - 1 + kw;
      bool inb = (ih >= 0) && (ih < 64) && (iw >= 0) && (iw < 64);
      float v = 0.f;
      if (inb){
        int cell = ih*64 + iw;
        v = xb[(size_t)cell*CI + c] / (cb_[cell] + EPS_F);
      }
      prow[kh*3 + kw] = v;
    }
  }
}

// conv GEMM: 64(n) x 32(d) tiles -> grid (8,64)=512 blocks (2/CU). K ascending,
// full chain per output -> bit-identical to prior conv.
__global__ __launch_bounds__(256) void conv_gemm(const float* __restrict__ P,
                                                 const float* __restrict__ wT,
                                                 const float* __restrict__ cb,
                                                 float* __restrict__ ymap){
  __shared__ float As[16][64];
  __shared__ float Bs[16][32];
  int n0 = blockIdx.y * 64, d0 = blockIdx.x * 32;
  int tid = threadIdx.x;
  int tx = tid & 15, ty = tid >> 4;          // cols tx*2..+1, rows ty*4..+3
  int ln = tid & 63, kq = tid >> 6;          // A staging: row ln, k-quad kq
  int bkr = tid >> 3, bc4 = (tid & 7) * 4;   // B staging (tid<128): k-row bkr, cols bc4
  float4 pav = *(const float4*)(P + (size_t)(n0+ln)*1152 + kq*4);
  float4 pbv;
  if (tid < 128) pbv = *(const float4*)(wT + (size_t)bkr*256 + d0 + bc4);
  float acc[4][2] = {{0}};
  for (int kt = 0; kt < 72; ++kt){
    __syncthreads();
    As[kq*4+0][ln]=pav.x; As[kq*4+1][ln]=pav.y; As[kq*4+2][ln]=pav.z; As[kq*4+3][ln]=pav.w;
    if (tid < 128) *(float4*)&Bs[bkr][bc4] = pbv;
    __syncthreads();
    if (kt < 71){
      int k2 = (kt + 1) * 16;
      pav = *(const float4*)(P + (size_t)(n0+ln)*1152 + k2 + kq*4);
      if (tid < 128) pbv = *(const float4*)(wT + (size_t)(k2 + bkr)*256 + d0 + bc4);
    }
#pragma unroll
    for (int k = 0; k < 16; ++k){
      float ar[4];
      *(float4*)ar = *(const float4*)&As[k][ty*4];
      float b0 = Bs[k][tx*2], b1 = Bs[k][tx*2+1];
#pragma unroll
      for (int r = 0; r < 4; ++r){ acc[r][0] += ar[r]*b0; acc[r][1] += ar[r]*b1; }
    }
  }
  float c0 = cb[d0 + tx*2], c1 = cb[d0 + tx*2 + 1];
#pragma unroll
  for (int r = 0; r < 4; ++r){
    float2 o; o.x = acc[r][0] + c0; o.y = acc[r][1] + c1;
    *(float2*)(ymap + (size_t)(n0 + ty*4 + r)*DOUT + d0 + tx*2) = o;
  }
}

// xt = x @ skip_w.T using transposed weights (coalesced); c ascending -> bit-identical
__global__ __launch_bounds__(256) void skip_kernel(const float* __restrict__ x,
                                                   const float* __restrict__ swT,
                                                   float* __restrict__ xt){
  int rowbase = blockIdx.x * 8;
  int d = threadIdx.x;
  __shared__ float xr[8*128];
  ((float4*)xr)[d] = ((const float4*)(x + (size_t)rowbase*CI))[d];
  __syncthreads();
  float acc[8] = {0,0,0,0,0,0,0,0};
  for (int c = 0; c < 128; ++c){
    float w = swT[c*256 + d];
#pragma unroll
    for (int r = 0; r < 8; ++r) acc[r] += w * xr[r*128 + c];
  }
  for (int r = 0; r < 8; ++r) xt[(size_t)(rowbase + r)*DOUT + d] = acc[r];
}

__global__ __launch_bounds__(256) void m2t_scatter(const float* __restrict__ ymap,
                                                   const float* __restrict__ loc,
                                                   const int* __restrict__ idx_agg,
                                                   const float* __restrict__ aggw,
                                                   const float* __restrict__ tot,
                                                   float* __restrict__ xt){
  int bn = blockIdx.x;
  int d = threadIdx.x;
  int b = bn >> 12;
  float lx = loc[(size_t)bn*2 + 0];
  float ly = loc[(size_t)bn*2 + 1];
  int cell = grid_cell(lx, ly, 32);
  int ia = idx_agg[bn];
  float w = aggw[bn] / (tot[b*NT + ia] + EPS_F);
  float val = ymap[((size_t)(b*HWO + cell))*DOUT + d] * w;
  atomicAdd(&xt[((size_t)(b*NT + ia))*DOUT + d], val);
}

__global__ __launch_bounds__(256) void ln_kernel(float* __restrict__ xt,
                                                 const float* __restrict__ g,
                                                 const float* __restrict__ bta,
                                                 const float* __restrict__ cw,
                                                 const float* __restrict__ cb,
                                                 float* __restrict__ sq, float* __restrict__ wt){
  __shared__ float red[4];
  int row = blockIdx.x;
  int d = threadIdx.x;
  float v = xt[(size_t)row*DOUT + d];
  float mu = blockSum256(v, red) * (1.0f/256.0f);
  float xc = v - mu;
  float var = blockSum256(xc*xc, red) * (1.0f/256.0f);
  float rn = 1.0f / sqrtf(var + 1e-5f);
  float y = xc * rn * g[d] + bta[d];
  xt[(size_t)row*DOUT + d] = y;
  float s2 = blockSum256(y*y, red);
  float cf = blockSum256(y*cw[d], red);
  if (d == 0){ sq[row] = s2; wt[row] = expf(cf + cb[0]); }
}

// ---------------- clustering ----------------
// gram: 64x64 lower-triangle tiles (2080/batch), BK=16, prefetch.
// LDS union: As[16][64]@0, Bs[16][64]@1024, T[64][65] aliases (16.6 KB).
__global__ __launch_bounds__(256) void gram64(const float* __restrict__ xt, float* __restrict__ G,
                                              int b_base, size_t gstride){
  __shared__ float smem[4160];
  int b = b_base + blockIdx.y;
  const float* A = xt + (size_t)b*NT*DOUT;
  float* Gb = G + (size_t)blockIdx.y*gstride;
  int t = blockIdx.x;
  int ti = 0, accu = 0;
  while (accu + ti + 1 <= t){ accu += ti + 1; ++ti; }
  int tj = t - accu;
  int i0 = ti * 64, j0 = tj * 64;
  int tid = threadIdx.x;
  int li = tid & 63, kq = tid >> 6;
  int tx = tid & 15, ty = tid >> 4;
  float4 av = *(const float4*)(A + (size_t)(i0+li)*DOUT + kq*4);
  float4 bv = *(const float4*)(A + (size_t)(j0+li)*DOUT + kq*4);
  float acc[4][4] = {{0}};
  for (int kt = 0; kt < 256; kt += 16){
    __syncthreads();
    smem[(kq*4+0)*64 + li]=av.x; smem[(kq*4+1)*64 + li]=av.y;
    smem[(kq*4+2)*64 + li]=av.z; smem[(kq*4+3)*64 + li]=av.w;
    smem[1024 + (kq*4+0)*64 + li]=bv.x; smem[1024 + (kq*4+1)*64 + li]=bv.y;
    smem[1024 + (kq*4+2)*64 + li]=bv.z; smem[1024 + (kq*4+3)*64 + li]=bv.w;
    __syncthreads();
    if (kt < 240){
      av = *(const float4*)(A + (size_t)(i0+li)*DOUT + kt + 16 + kq*4);
      bv = *(const float4*)(A + (size_t)(j0+li)*DOUT + kt + 16 + kq*4);
    }
#pragma unroll
    for (int k = 0; k < 16; ++k){
      float ar[4], br[4];
      *(float4*)ar = *(const float4*)&smem[k*64 + ty*4];
      *(float4*)br = *(const float4*)&smem[1024 + k*64 + tx*4];
#pragma unroll
      for (int r = 0; r < 4; ++r)
#pragma unroll
        for (int s = 0; s < 4; ++s) acc[r][s] += ar[r]*br[s];
    }
  }
#pragma unroll
  for (int r = 0; r < 4; ++r)
    *(float4*)(Gb + (size_t)(i0 + ty*4 + r)*NT + j0 + tx*4) = *(float4*)&acc[r][0];
  if (ti != tj){
    __syncthreads();
#pragma unroll
    for (int r = 0; r < 4; ++r)
#pragma unroll
      for (int s = 0; s < 4; ++s) smem[(ty*4+r)*65 + tx*4+s] = acc[r][s];
    __syncthreads();
#pragma unroll
    for (int r = 0; r < 4; ++r){
      float4 o;
      o.x = smem[(tx*4+0)*65 + ty*4+r]; o.y = smem[(tx*4+1)*65 + ty*4+r];
      o.z = smem[(tx*4+2)*65 + ty*4+r]; o.w = smem[(tx*4+3)*65 + ty*4+r];
      *(float4*)(Gb + (size_t)(j0 + ty*4 + r)*NT + i0 + tx*4) = o;
    }
  }
}

__global__ __launch_bounds__(256) void density_all(const float* __restrict__ G, size_t gstride,
                                                   const float* __restrict__ sq,
                                                   float* __restrict__ density, int* __restrict__ vmax,
                                                   int b_base){
  int b = b_base + blockIdx.y;
  const float* Gb = G + (size_t)blockIdx.y*gstride;
  int i = blockIdx.x;
  int tid = threadIdx.x;
  const float* sqb = sq + b*NT;
  float sqi = sqb[i];
  const float* row = Gb + (size_t)i*NT;
  float t0=INFINITY,t1=INFINITY,t2=INFINITY,t3=INFINITY,t4=INFINITY;
  float vmx = 0.f;
  for (int j = tid*4; j < NT; j += 1024){
    float4 g4 = *(const float4*)(row + j);
    float4 s4 = *(const float4*)(sqb + j);
    float v0 = fmaxf(sqi + s4.x - 2.0f*g4.x, 0.0f);
    float v1 = fmaxf(sqi + s4.y - 2.0f*g4.y, 0.0f);
    float v2 = fmaxf(sqi + s4.z - 2.0f*g4.z, 0.0f);
    float v3 = fmaxf(sqi + s4.w - 2.0f*g4.w, 0.0f);
    vmx = fmaxf(fmaxf(vmx, fmaxf(v0,v1)), fmaxf(v2,v3));
    ins5(v0,t0,t1,t2,t3,t4); ins5(v1,t0,t1,t2,t3,t4);
    ins5(v2,t0,t1,t2,t3,t4); ins5(v3,t0,t1,t2,t3,t4);
  }
#pragma unroll
  for (int m = 1; m < 64; m <<= 1){
    float b0=__shfl_xor(t0,m,64), b1=__shfl_xor(t1,m,64), b2=__shfl_xor(t2,m,64),
          b3=__shfl_xor(t3,m,64), b4=__shfl_xor(t4,m,64);
    merge5(t0,t1,t2,t3,t4,b0,b1,b2,b3,b4);
    vmx = fmaxf(vmx, __shfl_xor(vmx,m,64));
  }
  __shared__ float w5[4][5];
  __shared__ float wm[4];
  int lane = tid & 63, wid = tid >> 6;
  if (lane == 0){ w5[wid][0]=t0; w5[wid][1]=t1; w5[wid][2]=t2; w5[wid][3]=t3; w5[wid][4]=t4; wm[wid]=vmx; }
  __syncthreads();
  if (tid == 0){
    float a0=w5[0][0],a1=w5[0][1],a2=w5[0][2],a3=w5[0][3],a4=w5[0][4];
    for (int w = 1; w < 4; ++w) merge5(a0,a1,a2,a3,a4, w5[w][0],w5[w][1],w5[w][2],w5[w][3],w5[w][4]);
    float d0=sqrtf(a0)*0.0625f, d1=sqrtf(a1)*0.0625f, d2=sqrtf(a2)*0.0625f,
          d3=sqrtf(a3)*0.0625f, d4=sqrtf(a4)*0.0625f;
    float s = d0*d0; s += d1*d1; s += d2*d2; s += d3*d3; s += d4*d4;
    density[b*NT + i] = expf(-(s / 5.0f));
    float vm = fmaxf(fmaxf(wm[0],wm[1]), fmaxf(wm[2],wm[3]));
    atomicMax(vmax + b, __float_as_int(vm));
  }
}

__global__ __launch_bounds__(256) void parent_all(const float* __restrict__ G, size_t gstride,
                                                  const float* __restrict__ sq,
                                                  const float* __restrict__ density, const int* __restrict__ vmax,
                                                  float* __restrict__ score, int b_base){
  int b = b_base + blockIdx.y;
  const float* Gb = G + (size_t)blockIdx.y*gstride;
  int i = blockIdx.x;
  int tid = threadIdx.x;
  const float* sqb = sq + b*NT;
  const float* den = density + b*NT;
  float sqi = sqb[i];
  float di = den[i];
  const float* row = Gb + (size_t)i*NT;
  float minv = INFINITY;
  for (int j = tid*4; j < NT; j += 1024){
    float4 g4 = *(const float4*)(row + j);
    float4 s4 = *(const float4*)(sqb + j);
    float4 d4 = *(const float4*)(den + j);
    float v0 = fmaxf(sqi + s4.x - 2.0f*g4.x, 0.0f);
    float v1 = fmaxf(sqi + s4.y - 2.0f*g4.y, 0.0f);
    float v2 = fmaxf(sqi + s4.z - 2.0f*g4.z, 0.0f);
    float v3 = fmaxf(sqi + s4.w - 2.0f*g4.w, 0.0f);
    minv = fminf(minv, (d4.x > di) ? v0 : INFINITY);
    minv = fminf(minv, (d4.y > di) ? v1 : INFINITY);
    minv = fminf(minv, (d4.z > di) ? v2 : INFINITY);
    minv = fminf(minv, (d4.w > di) ? v3 : INFINITY);
  }
#pragma unroll
  for (int m = 1; m < 64; m <<= 1) minv = fminf(minv, __shfl_xor(minv,m,64));
  __shared__ float wmn[4];
  int lane = tid & 63, wid = tid >> 6;
  if (lane == 0) wmn[wid] = minv;
  __syncthreads();
  if (tid == 0){
    float mv = fminf(fminf(wmn[0],wmn[1]), fminf(wmn[2],wmn[3]));
    float dmax = sqrtf(__int_as_float(vmax[b])) * 0.0625f;
    float dp = isinf(mv) ? dmax : sqrtf(mv) * 0.0625f;
    score[b*NT + i] = dp * di;
  }
}

__global__ __launch_bounds__(1024) void topk_all(const float* __restrict__ score, int* __restrict__ idx_down,
                                                 int* __restrict__ inv, int b_base){
  __shared__ float ss[4096];
  __shared__ int ii[4096];
  int b = b_base + blockIdx.x;
  int tid = threadIdx.x;
  for (int t = tid; t < 4096; t += 1024){ ss[t] = score[b*NT + t]; ii[t] = t; inv[b*NT + t] = -1; }
  for (int k = 2; k <= 4096; k <<= 1){
    for (int j = k >> 1; j > 0; j >>= 1){
      __syncthreads();
#pragma unroll
      for (int vv = 0; vv < 2; ++vv){
        int v = tid + vv*1024;
        int i1 = 2*v - (v & (j-1));
        int i2 = i1 + j;
        float s1 = ss[i1], s2 = ss[i2];
        int a1 = ii[i1], a2 = ii[i2];
        bool lt = (s1 > s2) || (s1 == s2 && a1 < a2);
        bool up = ((i1 & k) == 0);
        if (up ? !lt : lt){ ss[i1]=s2; ss[i2]=s1; ii[i1]=a2; ii[i2]=a1; }
      }
    }
  }
  __syncthreads();
  if (tid < MC){
    int tok = ii[tid];
    idx_down[b*MC + tid] = tok;
    inv[b*NT + tok] = tid;
  }
}

// assign: block = 16 j x 16 m-chunks (64 m each, ascending); grid 256 x gy.
__global__ __launch_bounds__(256) void assign_all(const float* __restrict__ G, size_t gstride,
                                                  const float* __restrict__ sq,
                                                  const int* __restrict__ idx_down, const int* __restrict__ inv,
                                                  const float* __restrict__ wt,
                                                  int* __restrict__ idx_cluster, float* __restrict__ allw,
                                                  int b_base){
  int b = b_base + blockIdx.y;
  const float* Gb = G + (size_t)blockIdx.y*gstride;
  int jl = threadIdx.x & 15, mq = threadIdx.x >> 4;
  int j = blockIdx.x * 16 + jl;
  const float* sqb = sq + b*NT;
  float sqj = sqb[j];
  const int* idb = idx_down + b*MC;
  float bestd = INFINITY; int bestm = 0x7fffffff;
  for (int m = mq*64; m < mq*64 + 64; ++m){
    int im = idb[m];
    float g = Gb[(size_t)im*NT + j];
    float v = fmaxf(sqb[im] + sqj - 2.0f*g, 0.0f);
    float d = sqrtf(v) * 0.0625f;
    if (d < bestd){ bestd = d; bestm = m; }
  }
  __shared__ float ld[16][17];
  __shared__ int lm[16][17];
  ld[mq][jl] = bestd; lm[mq][jl] = bestm;
  __syncthreads();
  if (mq == 0){
    for (int q = 1; q < 16; ++q){
      float d2 = ld[q][jl]; int m2 = lm[q][jl];
      if (d2 < bestd || (d2 == bestd && m2 < bestm)){ bestd = d2; bestm = m2; }
    }
    int iv = inv[b*NT + j];
    int final_m = (iv >= 0) ? iv : bestm;
    idx_cluster[b*NT + j] = final_m;
    atomicAdd(&allw[b*MC + final_m], wt[b*NT + j]);
  }
}

// ---------------- merge + outputs ----------------
__global__ __launch_bounds__(256) void xdown_kernel(const int* __restrict__ idx_cluster,
                                                    const float* __restrict__ wt, const float* __restrict__ allw,
                                                    const float* __restrict__ xt, float* __restrict__ out0){
  int bn = blockIdx.x;
  int d = threadIdx.x;
  int b = bn >> 12;
  int ic = idx_cluster[bn];
  float nw = wt[bn] / (allw[b*MC + ic] + EPS_F);
  float v = xt[(size_t)bn*DOUT + d] * nw;
  atomicAdd(&out0[((size_t)(b*MC + ic))*DOUT + d], v);
}
__global__ __launch_bounds__(256) void out12a_kernel(const int* __restrict__ idx_agg, const int* __restrict__ idx_cluster,
                                                     const float* __restrict__ aggw,
                                                     const float* __restrict__ wt, const float* __restrict__ allw,
                                                     float* __restrict__ awd, int* __restrict__ awdmax,
                                                     float* __restrict__ out1){
  __shared__ float red[4];
  int lin = blockIdx.x * 256 + threadIdx.x;
  int b = lin >> 12;
  int ia = idx_agg[lin];
  int ic = idx_cluster[b*NT + ia];
  out1[lin] = (float)ic;
  float nw = wt[b*NT + ia] / (allw[b*MC + ic] + EPS_F);
  float v = aggw[lin] * nw;
  awd[lin] = v;
  float wv = v;
#pragma unroll
  for (int m = 1; m < 64; m <<= 1) wv = fmaxf(wv, __shfl_xor(wv, m, 64));
  int lane = threadIdx.x & 63, wid = threadIdx.x >> 6;
  if (lane == 0) red[wid] = wv;
  __syncthreads();
  if (threadIdx.x == 0){
    float bm = fmaxf(fmaxf(red[0], red[1]), fmaxf(red[2], red[3]));
    atomicMax(&awdmax[b], __float_as_int(bm));
  }
}
__global__ __launch_bounds__(256) void out2_kernel(const float* __restrict__ awd, const int* __restrict__ awdmax,
                                                   float* __restrict__ out2){
  int lin = blockIdx.x * 256 + threadIdx.x;
  int b = lin >> 12;
  out2[lin] = awd[lin] / __int_as_float(awdmax[b]);
}

extern "C" void kernel_launch(void* const* d_in, const int* in_sizes, int n_in,
                              void* d_out, int out_size, void* d_ws, size_t ws_size,
                              hipStream_t stream) {
  const float* x      = (const float*)d_in[0];
  const float* loc    = (const float*)d_in[1];
  const int*   idxagg = (const int*)d_in[2];
  const float* aggw   = (const float*)d_in[3];
  const float* convw  = (const float*)d_in[7];
  const float* convb  = (const float*)d_in[8];
  const float* skipw  = (const float*)d_in[9];
  const float* lng    = (const float*)d_in[10];
  const float* lnb    = (const float*)d_in[11];
  const float* confw  = (const float*)d_in[12];
  const float* confb  = (const float*)d_in[13];

  char* ws = (char*)d_ws;
  float* w_xmap  = (float*)(ws + OFF_XMAP);
  float* w_cnt   = (float*)(ws + OFF_CNT);
  float* w_tot   = (float*)(ws + OFF_TOT);
  float* w_allw  = (float*)(ws + OFF_ALLW);
  int*   w_vmax  = (int*)  (ws + OFF_VMAX);
  int*   w_awdm  = (int*)  (ws + OFF_AWDM);
  float* w_ymap  = (float*)(ws + OFF_YMAP);
  float* w_xt    = (float*)(ws + OFF_XT);
  float* w_sq    = (float*)(ws + OFF_SQ);
  float* w_den   = (float*)(ws + OFF_DEN);
  float* w_score = (float*)(ws + OFF_SCORE);
  float* w_wt    = (float*)(ws + OFF_WT);
  float* w_awd   = (float*)(ws + OFF_AWD);
  int*   w_idxd  = (int*)  (ws + OFF_IDXD);
  int*   w_idxc  = (int*)  (ws + OFF_IDXC);
  int*   w_inv   = (int*)  (ws + OFF_INV);
  float* w_wtr   = (float*)(ws + OFF_WTR);
  float* w_swt   = (float*)(ws + OFF_SWT);
  float* w_p     = (float*)(ws + OFF_P);
  float* w_g     = (float*)(ws + OFF_G);

  int gcount = 1;
  for (int k = 4; k >= 1; --k){
    if (OFF_G + (size_t)k*GSZB <= ws_size){ gcount = k; break; }
  }

  float* out0 = (float*)d_out;
  float* out1 = out0 + NB*MC*DOUT;
  float* out2 = out1 + NB*NT;

  hipMemsetAsync(ws, 0, ZERO_BYTES, stream);
  hipMemsetAsync(out0, 0, (size_t)NB*MC*DOUT*sizeof(float), stream);

  t2m_scatter<<<NB*NT*CI/256, 256, 0, stream>>>(x, loc, idxagg, aggw, w_xmap, w_cnt, w_tot);
  wprep_kernel<<<1280, 256, 0, stream>>>(convw, skipw, w_wtr, w_swt);
  im2col_kernel<<<2048, 256, 0, stream>>>(w_xmap, w_cnt, w_p);
  conv_gemm<<<dim3(8, 64), 256, 0, stream>>>(w_p, w_wtr, convb, w_ymap);
  skip_kernel<<<NB*NT/8, 256, 0, stream>>>(x, w_swt, w_xt);
  m2t_scatter<<<NB*NT, 256, 0, stream>>>(w_ymap, loc, idxagg, aggw, w_tot, w_xt);
  ln_kernel<<<NB*NT, 256, 0, stream>>>(w_xt, lng, lnb, confw, confb, w_sq, w_wt);

  for (int g0 = 0; g0 < NB; g0 += gcount){
    int gy = (NB - g0 < gcount) ? (NB - g0) : gcount;
    gram64     <<<dim3(2080, gy), 256, 0, stream>>>(w_xt, w_g, g0, GSZ);
    density_all<<<dim3(NT, gy), 256, 0, stream>>>(w_g, GSZ, w_sq, w_den, w_vmax, g0);
    parent_all <<<dim3(NT, gy), 256, 0, stream>>>(w_g, GSZ, w_sq, w_den, w_vmax, w_score, g0);
    topk_all   <<<gy, 1024, 0, stream>>>(w_score, w_idxd, w_inv, g0);
    assign_all <<<dim3(256, gy), 256, 0, stream>>>(w_g, GSZ, w_sq, w_idxd, w_inv, w_wt, w_idxc, w_allw, g0);
  }

  xdown_kernel<<<NB*NT, 256, 0, stream>>>(w_idxc, w_wt, w_allw, w_xt, out0);
  out12a_kernel<<<NB*NT/256, 256, 0, stream>>>(idxagg, w_idxc, aggw, w_wt, w_allw, w_awd, w_awdm, out1);
  out2_kernel<<<NB*NT/256, 256, 0, stream>>>(w_awd, w_awdm, out2);

  (void)in_sizes; (void)n_in; (void)out_size;
}